// Round 1
// baseline (4661.962 us; speedup 1.0000x reference)
//
#include <hip/hip_runtime.h>

#define N_NODES 50000
#define N_EDGES 800000
#define NODE_F  388
#define EDGE_F  385
#define HC      64

// ---- workspace layout (float offsets) ----
#define O_XL      0L         // N*64
#define O_XR      3200000L   // N*64
#define O_EESUM   6400000L   // N*64  (zeroed)
#define O_AGGR    9600000L   // N*64  (zeroed)
#define O_CNT     12800000L  // N     (zeroed)
#define O_SSUM    12850000L  // N*2   (zeroed)
#define O_HA      12950000L  // N*64
#define O_HB      16150000L  // N*64
#define O_EXSELF  19350000L  // N*2
#define O_EXE     19450000L  // E*2
#define O_QW      21050000L  // E*64 bf16 (ushort) from here; total ws = 186.6 MB

static __device__ __forceinline__ unsigned short f2bf(float f) {
    unsigned u = __float_as_uint(f);
    u += 0x7FFFu + ((u >> 16) & 1u);   // RNE
    return (unsigned short)(u >> 16);
}
static __device__ __forceinline__ float bf2f(unsigned short h) {
    return __uint_as_float(((unsigned)h) << 16);
}

// K1: xl = x@lin_l_w + bl ; xr = x@lin_r_w + br.  One wave per node, lane = output col.
__global__ __launch_bounds__(256) void k_node_lin(
    const float* __restrict__ x, const float* __restrict__ wl, const float* __restrict__ bl,
    const float* __restrict__ wr, const float* __restrict__ br,
    float* __restrict__ xl, float* __restrict__ xr)
{
    const int lane = threadIdx.x & 63;
    const int n = blockIdx.x * 4 + (threadIdx.x >> 6);
    if (n >= N_NODES) return;
    const float* xrow = x + (long)n * NODE_F;
    float accL = 0.f, accR = 0.f;
    for (int k0 = 0; k0 < NODE_F; k0 += 64) {
        float xv = (k0 + lane < NODE_F) ? xrow[k0 + lane] : 0.f;
        int kmax = NODE_F - k0; if (kmax > 64) kmax = 64;
        for (int j = 0; j < kmax; ++j) {
            float xb = __shfl(xv, j);
            accL = fmaf(xb, wl[(k0 + j) * HC + lane], accL);
            accR = fmaf(xb, wr[(k0 + j) * HC + lane], accR);
        }
    }
    xl[(long)n * HC + lane] = accL + bl[lane];
    xr[(long)n * HC + lane] = accR + br[lane];
}

// K2: per 64-edge tile: [ee | qW] = edge_attr @ [lin_e_w | W1c]; fused attention score,
// exp, ssum/cnt/eesum atomics, bf16 qW store.  256 thr: tx(col grp of 8) x ty(edge grp of 4).
__global__ __launch_bounds__(256) void k_edge_main(
    const float* __restrict__ ea, const int* __restrict__ ei,
    const float* __restrict__ we, const float* __restrict__ w1,
    const float* __restrict__ xl, const float* __restrict__ xr,
    const float* __restrict__ att,
    float* __restrict__ eesum, float* __restrict__ ssum, float* __restrict__ cnt,
    float* __restrict__ exE, unsigned short* __restrict__ qW)
{
    __shared__ float a_s[64][65];    // 64 edges x 64 k, +1 pad (conflict-free)
    __shared__ float w_s[64][132];   // 64 k x 128 cols, pad 132
    const int t  = threadIdx.x;
    const int tx = t & 15;
    const int ty = t >> 4;
    const long e0 = (long)blockIdx.x * 64;

    float acc[4][8];
#pragma unroll
    for (int i = 0; i < 4; ++i)
#pragma unroll
        for (int j = 0; j < 8; ++j) acc[i][j] = 0.f;

    for (int k0 = 0; k0 < EDGE_F; k0 += 64) {
        __syncthreads();
        for (int idx = t; idx < 64 * 64; idx += 256) {
            int row = idx >> 6, kk = idx & 63;
            int kg = k0 + kk;
            a_s[row][kk] = (kg < EDGE_F) ? ea[(e0 + row) * (long)EDGE_F + kg] : 0.f;
        }
        for (int idx = t; idx < 64 * 128; idx += 256) {
            int kk = idx >> 7, c = idx & 127;
            int kg = k0 + kk;
            float v = 0.f;
            if (c < 64) { if (kg < EDGE_F)     v = we[(long)kg * HC + c]; }
            else        { if (kg < EDGE_F - 1) v = w1[(long)(128 + kg) * HC + (c - 64)]; }
            w_s[kk][c] = v;
        }
        __syncthreads();
#pragma unroll 4
        for (int kk = 0; kk < 64; ++kk) {
            float4 w0 = *(const float4*)&w_s[kk][tx * 8];
            float4 w4 = *(const float4*)&w_s[kk][tx * 8 + 4];
#pragma unroll
            for (int i = 0; i < 4; ++i) {
                float av = a_s[ty * 4 + i][kk];
                acc[i][0] = fmaf(av, w0.x, acc[i][0]);
                acc[i][1] = fmaf(av, w0.y, acc[i][1]);
                acc[i][2] = fmaf(av, w0.z, acc[i][2]);
                acc[i][3] = fmaf(av, w0.w, acc[i][3]);
                acc[i][4] = fmaf(av, w4.x, acc[i][4]);
                acc[i][5] = fmaf(av, w4.y, acc[i][5]);
                acc[i][6] = fmaf(av, w4.z, acc[i][6]);
                acc[i][7] = fmaf(av, w4.w, acc[i][7]);
            }
        }
    }

    float attr[8];
#pragma unroll
    for (int j = 0; j < 8; ++j) attr[j] = att[(tx & 7) * 8 + j];

#pragma unroll
    for (int i = 0; i < 4; ++i) {
        long e = e0 + ty * 4 + i;
        int s = ei[e];
        int g = ei[N_EDGES + e];
        if (tx < 8) {                       // ee cols 0..63
            int c = tx * 8;
#pragma unroll
            for (int j = 0; j < 8; ++j)
                atomicAdd(&eesum[(long)g * HC + c + j], acc[i][j]);
            const float4 xa = *(const float4*)&xl[(long)s * HC + c];
            const float4 xb = *(const float4*)&xl[(long)s * HC + c + 4];
            const float4 ra = *(const float4*)&xr[(long)g * HC + c];
            const float4 rb = *(const float4*)&xr[(long)g * HC + c + 4];
            float sums[8] = { xa.x + ra.x, xa.y + ra.y, xa.z + ra.z, xa.w + ra.w,
                              xb.x + rb.x, xb.y + rb.y, xb.z + rb.z, xb.w + rb.w };
            float partial = 0.f;
#pragma unroll
            for (int j = 0; j < 8; ++j) {
                float v  = acc[i][j] + sums[j];
                float lv = v > 0.f ? v : 0.2f * v;
                partial  = fmaf(lv, attr[j], partial);
            }
            partial += __shfl_xor(partial, 1);   // reduce over 4-lane col groups
            partial += __shfl_xor(partial, 2);   // (head = c/32 -> tx 0..3 h0, 4..7 h1)
            if ((tx & 3) == 0) {
                int h = tx >> 2;
                float ex = __expf(partial);      // no segment-max: shift-invariant
                exE[e * 2 + h] = ex;
                atomicAdd(&ssum[(long)g * 2 + h], ex);
                if (h == 0) atomicAdd(&cnt[g], 1.0f);
            }
        } else {                            // qW cols 0..63 -> bf16 store
            int c = (tx - 8) * 8;
            uint4 pk;
            pk.x = (unsigned)f2bf(acc[i][0]) | ((unsigned)f2bf(acc[i][1]) << 16);
            pk.y = (unsigned)f2bf(acc[i][2]) | ((unsigned)f2bf(acc[i][3]) << 16);
            pk.z = (unsigned)f2bf(acc[i][4]) | ((unsigned)f2bf(acc[i][5]) << 16);
            pk.w = (unsigned)f2bf(acc[i][6]) | ((unsigned)f2bf(acc[i][7]) << 16);
            *(uint4*)&qW[e * HC + c] = pk;
        }
    }
}

// K3: self-loop edge per node: ee_self = eesum/cnt (linearity of segsum through matmul)
__global__ __launch_bounds__(256) void k_self(
    const float* __restrict__ xl, const float* __restrict__ xr,
    const float* __restrict__ eesum, const float* __restrict__ cnt,
    const float* __restrict__ att,
    float* __restrict__ ssum, float* __restrict__ exSelf)
{
    const int lane = threadIdx.x & 63;
    const int n = blockIdx.x * 4 + (threadIdx.x >> 6);
    if (n >= N_NODES) return;
    float dc = fmaxf(cnt[n], 1.0f);
    float eeS = eesum[(long)n * HC + lane] / dc;
    float v = xl[(long)n * HC + lane] + xr[(long)n * HC + lane] + eeS;
    float lv = v > 0.f ? v : 0.2f * v;
    float partial = lv * att[lane];
    partial += __shfl_xor(partial, 1);
    partial += __shfl_xor(partial, 2);
    partial += __shfl_xor(partial, 4);
    partial += __shfl_xor(partial, 8);
    partial += __shfl_xor(partial, 16);
    if ((lane & 31) == 0) {
        int h = lane >> 5;
        float ex = __expf(partial);
        exSelf[(long)n * 2 + h] = ex;
        ssum[(long)n * 2 + h] += ex;   // single writer per node; after K2
    }
}

// K4: out[tgt] += alpha * xl[src]  (16 edges/block, 16 threads/edge, 4 cols each)
__global__ __launch_bounds__(256) void k_aggr(
    const int* __restrict__ ei, const float* __restrict__ xl,
    const float* __restrict__ exE, const float* __restrict__ ssum,
    float* __restrict__ aggr)
{
    const int t = threadIdx.x;
    const int sub = t & 15;
    const long e = (long)blockIdx.x * 16 + (t >> 4);
    int s = ei[e], g = ei[N_EDGES + e];
    int h = (sub < 8) ? 0 : 1;
    float alpha = exE[e * 2 + h] / (ssum[(long)g * 2 + h] + 1e-16f);
    const float4 xv = *(const float4*)&xl[(long)s * HC + sub * 4];
    float* dst = &aggr[(long)g * HC + sub * 4];
    atomicAdd(dst + 0, alpha * xv.x);
    atomicAdd(dst + 1, alpha * xv.y);
    atomicAdd(dst + 2, alpha * xv.z);
    atomicAdd(dst + 3, alpha * xv.w);
}

// K5: h = relu(aggr + alpha_self*xl + conv_b); hA = h@W1a, hB = h@W1b
__global__ __launch_bounds__(256) void k_node_fin(
    const float* __restrict__ xl, const float* __restrict__ aggr,
    const float* __restrict__ exSelf, const float* __restrict__ ssum,
    const float* __restrict__ convb, const float* __restrict__ w1,
    float* __restrict__ hA, float* __restrict__ hB)
{
    const int lane = threadIdx.x & 63;
    const int n = blockIdx.x * 4 + (threadIdx.x >> 6);
    if (n >= N_NODES) return;
    int h = lane >> 5;
    float alphaS = exSelf[(long)n * 2 + h] / (ssum[(long)n * 2 + h] + 1e-16f);
    float val = aggr[(long)n * HC + lane] + alphaS * xl[(long)n * HC + lane];
    float hv = fmaxf(val + convb[lane], 0.f);
    float accA = 0.f, accB = 0.f;
    for (int k = 0; k < 64; ++k) {
        float hb = __shfl(hv, k);
        accA = fmaf(hb, w1[k * HC + lane], accA);
        accB = fmaf(hb, w1[(64 + k) * HC + lane], accB);
    }
    hA[(long)n * HC + lane] = accA;
    hB[(long)n * HC + lane] = accB;
}

// K6: trust[e] from m = relu(hA[src]+hB[tgt]+qW[e]+b1); logits = m@W2+b2; softmax
__global__ __launch_bounds__(256) void k_trust(
    const int* __restrict__ ei, const float* __restrict__ hA, const float* __restrict__ hB,
    const unsigned short* __restrict__ qW, const float* __restrict__ b1,
    const float* __restrict__ w2, const float* __restrict__ b2,
    float* __restrict__ out)
{
    const int lane = threadIdx.x & 63;
    const long e = (long)blockIdx.x * 4 + (threadIdx.x >> 6);
    if (e >= N_EDGES) return;
    int s = ei[e], g = ei[N_EDGES + e];
    float m = hA[(long)s * HC + lane] + hB[(long)g * HC + lane]
            + bf2f(qW[e * HC + lane]) + b1[lane];
    m = fmaxf(m, 0.f);
    float p0 = m * w2[lane * 3 + 0];
    float p1 = m * w2[lane * 3 + 1];
    float p2 = m * w2[lane * 3 + 2];
    for (int msk = 1; msk < 64; msk <<= 1) {
        p0 += __shfl_xor(p0, msk);
        p1 += __shfl_xor(p1, msk);
        p2 += __shfl_xor(p2, msk);
    }
    if (lane == 0) {
        float l0 = p0 + b2[0], l1 = p1 + b2[1], l2 = p2 + b2[2];
        float mx = fmaxf(l0, fmaxf(l1, l2));
        float e0 = __expf(l0 - mx), e1 = __expf(l1 - mx), e2 = __expf(l2 - mx);
        out[e] = (0.5f * e1 + e2) / (e0 + e1 + e2);
    }
}

extern "C" void kernel_launch(void* const* d_in, const int* in_sizes, int n_in,
                              void* d_out, int out_size, void* d_ws, size_t ws_size,
                              hipStream_t stream)
{
    (void)in_sizes; (void)n_in; (void)out_size; (void)ws_size;
    const float* x     = (const float*)d_in[0];
    const int*   ei    = (const int*)  d_in[1];
    const float* ea    = (const float*)d_in[2];
    const float* wl    = (const float*)d_in[3];
    const float* bl    = (const float*)d_in[4];
    const float* wr    = (const float*)d_in[5];
    const float* br    = (const float*)d_in[6];
    const float* we    = (const float*)d_in[7];
    const float* att   = (const float*)d_in[8];
    const float* convb = (const float*)d_in[9];
    const float* w1    = (const float*)d_in[10];
    const float* b1    = (const float*)d_in[11];
    const float* w2    = (const float*)d_in[12];
    const float* b2    = (const float*)d_in[13];

    float* ws = (float*)d_ws;
    float* xl     = ws + O_XL;
    float* xr     = ws + O_XR;
    float* eesum  = ws + O_EESUM;
    float* aggr   = ws + O_AGGR;
    float* cnt    = ws + O_CNT;
    float* ssum   = ws + O_SSUM;
    float* hA     = ws + O_HA;
    float* hB     = ws + O_HB;
    float* exSelf = ws + O_EXSELF;
    float* exE    = ws + O_EXE;
    unsigned short* qW = (unsigned short*)(ws + O_QW);
    float* out = (float*)d_out;

    // zero accumulators (eesum, aggr, cnt, ssum are contiguous)
    hipMemsetAsync(ws + O_EESUM, 0, (size_t)(O_HA - O_EESUM) * sizeof(float), stream);

    k_node_lin<<<N_NODES / 4, 256, 0, stream>>>(x, wl, bl, wr, br, xl, xr);
    k_edge_main<<<N_EDGES / 64, 256, 0, stream>>>(ea, ei, we, w1, xl, xr, att,
                                                  eesum, ssum, cnt, exE, qW);
    k_self<<<N_NODES / 4, 256, 0, stream>>>(xl, xr, eesum, cnt, att, ssum, exSelf);
    k_aggr<<<N_EDGES / 16, 256, 0, stream>>>(ei, xl, exE, ssum, aggr);
    k_node_fin<<<N_NODES / 4, 256, 0, stream>>>(xl, aggr, exSelf, ssum, convb, w1, hA, hB);
    k_trust<<<N_EDGES / 4, 256, 0, stream>>>(ei, hA, hB, qW, b1, w2, b2, out);
}

// Round 2
// 2992.658 us; speedup vs baseline: 1.5578x; 1.5578x over previous
//
#include <hip/hip_runtime.h>

#define N_NODES 50000
#define N_EDGES 800000
#define NODE_F  388
#define EDGE_F  385
#define HC      64
#define KPAD    448   // 7 K-tiles of 64
#define NKT     7

// ---- workspace layout (float offsets) ----
#define O_XL      0L         // N*64
#define O_XR      3200000L   // N*64
#define O_EESUM   6400000L   // N*64  (zeroed)
#define O_AGGR    9600000L   // N*64  (zeroed)
#define O_CNT     12800000L  // N     (zeroed)
#define O_SSUM    12850000L  // N*2   (zeroed)
#define O_HA      12950000L  // N*64
#define O_HB      16150000L  // N*64
#define O_EXSELF  19350000L  // N*2
#define O_EXE     19450000L  // E*2
#define O_QW      21050000L  // E*64 bf16 (ushort)
#define O_WT      46650000L  // 128*448 bf16 transposed weights (ushort)

typedef __attribute__((ext_vector_type(8))) short bf8;   // 8 bf16 (4 VGPRs)
typedef __attribute__((ext_vector_type(4))) float f4;

static __device__ __forceinline__ unsigned short f2bf(float f) {
    unsigned u = __float_as_uint(f);
    u += 0x7FFFu + ((u >> 16) & 1u);   // RNE
    return (unsigned short)(u >> 16);
}
static __device__ __forceinline__ float bf2f(unsigned short h) {
    return __uint_as_float(((unsigned)h) << 16);
}

// K0: one-time build of Wt[col][k] bf16, col 0..127, k 0..447 (zero-padded).
// cols 0..63 = lin_e_w (k<385); cols 64..127 = mlp1_w rows 128.. (k<384).
__global__ __launch_bounds__(256) void k_prep(
    const float* __restrict__ we, const float* __restrict__ w1,
    unsigned short* __restrict__ wt)
{
    int gid = blockIdx.x * 256 + threadIdx.x;     // 0..28671 = 128 cols * 224 k-pairs
    int c  = gid / 224;
    int kp = gid - c * 224;
    int k  = 2 * kp;
    float f0, f1;
    if (c < HC) {
        f0 = (k     < EDGE_F) ? we[(long)k * HC + c] : 0.f;
        f1 = (k + 1 < EDGE_F) ? we[(long)(k + 1) * HC + c] : 0.f;
    } else {
        f0 = (k     < EDGE_F - 1) ? w1[(long)(128 + k) * HC + (c - HC)] : 0.f;
        f1 = (k + 1 < EDGE_F - 1) ? w1[(long)(128 + k + 1) * HC + (c - HC)] : 0.f;
    }
    unsigned pk = (unsigned)f2bf(f0) | ((unsigned)f2bf(f1) << 16);
    *(unsigned*)(wt + (long)c * KPAD + k) = pk;
}

// K1: xl = x@lin_l_w + bl ; xr = x@lin_r_w + br.  One wave per node, lane = output col.
__global__ __launch_bounds__(256) void k_node_lin(
    const float* __restrict__ x, const float* __restrict__ wl, const float* __restrict__ bl,
    const float* __restrict__ wr, const float* __restrict__ br,
    float* __restrict__ xl, float* __restrict__ xr)
{
    const int lane = threadIdx.x & 63;
    const int n = blockIdx.x * 4 + (threadIdx.x >> 6);
    if (n >= N_NODES) return;
    const float* xrow = x + (long)n * NODE_F;
    float accL = 0.f, accR = 0.f;
    for (int k0 = 0; k0 < NODE_F; k0 += 64) {
        float xv = (k0 + lane < NODE_F) ? xrow[k0 + lane] : 0.f;
        int kmax = NODE_F - k0; if (kmax > 64) kmax = 64;
        for (int j = 0; j < kmax; ++j) {
            float xb = __shfl(xv, j);
            accL = fmaf(xb, wl[(k0 + j) * HC + lane], accL);
            accR = fmaf(xb, wr[(k0 + j) * HC + lane], accR);
        }
    }
    xl[(long)n * HC + lane] = accL + bl[lane];
    xr[(long)n * HC + lane] = accR + br[lane];
}

// K2: MFMA edge GEMM [64 edges x 128 cols] = ea(bf16) @ Wt; fused attention epilogue.
// 4 waves: wave w -> rows (w&1)*32..+31, cols (w>>1)*64..+63.
__global__ __launch_bounds__(256) void k_edge_main(
    const float* __restrict__ ea, const int* __restrict__ ei,
    const unsigned short* __restrict__ wt,
    const float* __restrict__ xl, const float* __restrict__ xr,
    const float* __restrict__ att,
    float* __restrict__ eesum, float* __restrict__ ssum, float* __restrict__ cnt,
    float* __restrict__ exE, unsigned short* __restrict__ qW)
{
    __shared__ __align__(16) char lds[64 * 132 * 4];   // 33792 B; c_s phase is largest
    char* A_s = lds;               // [64 rows][128 B]  bf16, XOR-swizzled
    char* W_s = lds + 8192;        // [128 cols][128 B] bf16, XOR-swizzled
    float (*c_s)[132] = (float(*)[132])lds;

    const int t = threadIdx.x;
    const int l = t & 63;
    const int w = t >> 6;
    const long e0 = (long)blockIdx.x * 64;

    const int rb = (w & 1) * 32;
    const int cb = (w >> 1) * 64;
    const int lr = l & 15;
    const int lk = l >> 4;
    const int sw = (lr & 7) << 4;          // swizzle term for compute-phase reads

    f4 acc[2][4];
#pragma unroll
    for (int rg = 0; rg < 2; ++rg)
#pragma unroll
        for (int cg = 0; cg < 4; ++cg) acc[rg][cg] = (f4)(0.f);

    for (int kt = 0; kt < NKT; ++kt) {
        const int k0 = kt * 64;
        __syncthreads();
        // stage A: 64 rows x 64 k (f32 -> bf16), dword loads (rows only 4B-aligned)
#pragma unroll
        for (int i = 0; i < 8; ++i) {
            int idx = t + i * 256;         // 0..2047
            int row = idx >> 5;
            int cp  = idx & 31;
            int g0 = k0 + 2 * cp;
            const float* rp = ea + (e0 + row) * (long)EDGE_F;
            float f0 = (g0     < EDGE_F) ? rp[g0]     : 0.f;
            float f1 = (g0 + 1 < EDGE_F) ? rp[g0 + 1] : 0.f;
            unsigned pk = (unsigned)f2bf(f0) | ((unsigned)f2bf(f1) << 16);
            *(unsigned*)(A_s + row * 128 + ((4 * cp) ^ ((row & 7) << 4))) = pk;
        }
        // stage Wt tile: 128 cols x 64 k bf16, b128 copies
#pragma unroll
        for (int i = 0; i < 4; ++i) {
            int idx  = t + i * 256;        // 0..1023
            int c    = idx >> 3;
            int slot = idx & 7;
            uint4 v = *(const uint4*)(wt + (long)c * KPAD + k0 + slot * 8);
            *(uint4*)(W_s + c * 128 + ((slot * 16) ^ ((c & 7) << 4))) = v;
        }
        __syncthreads();
        // compute: 2 k-substeps of 32, 2 row-groups, 4 col-groups
#pragma unroll
        for (int ks = 0; ks < 2; ++ks) {
            const int kb = ks * 64 + lk * 16;
            bf8 a0 = *(bf8*)(A_s + (rb + lr) * 128      + (kb ^ sw));
            bf8 a1 = *(bf8*)(A_s + (rb + 16 + lr) * 128 + (kb ^ sw));
#pragma unroll
            for (int cg = 0; cg < 4; ++cg) {
                bf8 b = *(bf8*)(W_s + (cb + cg * 16 + lr) * 128 + (kb ^ sw));
                acc[0][cg] = __builtin_amdgcn_mfma_f32_16x16x32_bf16(a0, b, acc[0][cg], 0, 0, 0);
                acc[1][cg] = __builtin_amdgcn_mfma_f32_16x16x32_bf16(a1, b, acc[1][cg], 0, 0, 0);
            }
        }
    }

    __syncthreads();
    // dump acc to c_s: C/D layout col=lane&15, row=(lane>>4)*4+reg
#pragma unroll
    for (int rg = 0; rg < 2; ++rg)
#pragma unroll
        for (int cg = 0; cg < 4; ++cg)
#pragma unroll
            for (int r = 0; r < 4; ++r)
                c_s[rb + rg * 16 + lk * 4 + r][cb + cg * 16 + lr] = acc[rg][cg][r];
    __syncthreads();

    // epilogue (identical math to round-1, acc read from c_s)
    const int tx = t & 15;
    const int ty = t >> 4;
    float attr[8];
#pragma unroll
    for (int j = 0; j < 8; ++j) attr[j] = att[(tx & 7) * 8 + j];

#pragma unroll
    for (int i = 0; i < 4; ++i) {
        const int row = ty * 4 + i;
        const long e = e0 + row;
        int s = ei[e];
        int g = ei[N_EDGES + e];
        float a[8];
        *(float4*)&a[0] = *(const float4*)&c_s[row][tx * 8];
        *(float4*)&a[4] = *(const float4*)&c_s[row][tx * 8 + 4];
        if (tx < 8) {                       // ee cols 0..63
            int c = tx * 8;
#pragma unroll
            for (int j = 0; j < 8; ++j)
                atomicAdd(&eesum[(long)g * HC + c + j], a[j]);
            const float4 xa = *(const float4*)&xl[(long)s * HC + c];
            const float4 xb = *(const float4*)&xl[(long)s * HC + c + 4];
            const float4 ra = *(const float4*)&xr[(long)g * HC + c];
            const float4 rb2 = *(const float4*)&xr[(long)g * HC + c + 4];
            float sums[8] = { xa.x + ra.x, xa.y + ra.y, xa.z + ra.z, xa.w + ra.w,
                              xb.x + rb2.x, xb.y + rb2.y, xb.z + rb2.z, xb.w + rb2.w };
            float partial = 0.f;
#pragma unroll
            for (int j = 0; j < 8; ++j) {
                float v  = a[j] + sums[j];
                float lv = v > 0.f ? v : 0.2f * v;
                partial  = fmaf(lv, attr[j], partial);
            }
            partial += __shfl_xor(partial, 1);   // reduce 4-lane col groups
            partial += __shfl_xor(partial, 2);
            if ((tx & 3) == 0) {
                int h = tx >> 2;
                float ex = __expf(partial);      // no segment-max: shift-invariant
                exE[e * 2 + h] = ex;
                atomicAdd(&ssum[(long)g * 2 + h], ex);
                if (h == 0) atomicAdd(&cnt[g], 1.0f);
            }
        } else {                            // qW cols 64..127 -> bf16 store
            int c = (tx - 8) * 8;
            uint4 pk;
            pk.x = (unsigned)f2bf(a[0]) | ((unsigned)f2bf(a[1]) << 16);
            pk.y = (unsigned)f2bf(a[2]) | ((unsigned)f2bf(a[3]) << 16);
            pk.z = (unsigned)f2bf(a[4]) | ((unsigned)f2bf(a[5]) << 16);
            pk.w = (unsigned)f2bf(a[6]) | ((unsigned)f2bf(a[7]) << 16);
            *(uint4*)&qW[e * HC + c] = pk;
        }
    }
}

// K3: self-loop edge per node: ee_self = eesum/cnt (linearity of segsum through matmul)
__global__ __launch_bounds__(256) void k_self(
    const float* __restrict__ xl, const float* __restrict__ xr,
    const float* __restrict__ eesum, const float* __restrict__ cnt,
    const float* __restrict__ att,
    float* __restrict__ ssum, float* __restrict__ exSelf)
{
    const int lane = threadIdx.x & 63;
    const int n = blockIdx.x * 4 + (threadIdx.x >> 6);
    if (n >= N_NODES) return;
    float dc = fmaxf(cnt[n], 1.0f);
    float eeS = eesum[(long)n * HC + lane] / dc;
    float v = xl[(long)n * HC + lane] + xr[(long)n * HC + lane] + eeS;
    float lv = v > 0.f ? v : 0.2f * v;
    float partial = lv * att[lane];
    partial += __shfl_xor(partial, 1);
    partial += __shfl_xor(partial, 2);
    partial += __shfl_xor(partial, 4);
    partial += __shfl_xor(partial, 8);
    partial += __shfl_xor(partial, 16);
    if ((lane & 31) == 0) {
        int h = lane >> 5;
        float ex = __expf(partial);
        exSelf[(long)n * 2 + h] = ex;
        ssum[(long)n * 2 + h] += ex;   // single writer per node; after K2
    }
}

// K4: aggr[tgt] += alpha * xl[src]
__global__ __launch_bounds__(256) void k_aggr(
    const int* __restrict__ ei, const float* __restrict__ xl,
    const float* __restrict__ exE, const float* __restrict__ ssum,
    float* __restrict__ aggr)
{
    const int t = threadIdx.x;
    const int sub = t & 15;
    const long e = (long)blockIdx.x * 16 + (t >> 4);
    int s = ei[e], g = ei[N_EDGES + e];
    int h = (sub < 8) ? 0 : 1;
    float alpha = exE[e * 2 + h] / (ssum[(long)g * 2 + h] + 1e-16f);
    const float4 xv = *(const float4*)&xl[(long)s * HC + sub * 4];
    float* dst = &aggr[(long)g * HC + sub * 4];
    atomicAdd(dst + 0, alpha * xv.x);
    atomicAdd(dst + 1, alpha * xv.y);
    atomicAdd(dst + 2, alpha * xv.z);
    atomicAdd(dst + 3, alpha * xv.w);
}

// K5: h = relu(aggr + alpha_self*xl + conv_b); hA = h@W1a, hB = h@W1b
__global__ __launch_bounds__(256) void k_node_fin(
    const float* __restrict__ xl, const float* __restrict__ aggr,
    const float* __restrict__ exSelf, const float* __restrict__ ssum,
    const float* __restrict__ convb, const float* __restrict__ w1,
    float* __restrict__ hA, float* __restrict__ hB)
{
    const int lane = threadIdx.x & 63;
    const int n = blockIdx.x * 4 + (threadIdx.x >> 6);
    if (n >= N_NODES) return;
    int h = lane >> 5;
    float alphaS = exSelf[(long)n * 2 + h] / (ssum[(long)n * 2 + h] + 1e-16f);
    float val = aggr[(long)n * HC + lane] + alphaS * xl[(long)n * HC + lane];
    float hv = fmaxf(val + convb[lane], 0.f);
    float accA = 0.f, accB = 0.f;
    for (int k = 0; k < 64; ++k) {
        float hb = __shfl(hv, k);
        accA = fmaf(hb, w1[k * HC + lane], accA);
        accB = fmaf(hb, w1[(64 + k) * HC + lane], accB);
    }
    hA[(long)n * HC + lane] = accA;
    hB[(long)n * HC + lane] = accB;
}

// K6: trust per edge
__global__ __launch_bounds__(256) void k_trust(
    const int* __restrict__ ei, const float* __restrict__ hA, const float* __restrict__ hB,
    const unsigned short* __restrict__ qW, const float* __restrict__ b1,
    const float* __restrict__ w2, const float* __restrict__ b2,
    float* __restrict__ out)
{
    const int lane = threadIdx.x & 63;
    const long e = (long)blockIdx.x * 4 + (threadIdx.x >> 6);
    if (e >= N_EDGES) return;
    int s = ei[e], g = ei[N_EDGES + e];
    float m = hA[(long)s * HC + lane] + hB[(long)g * HC + lane]
            + bf2f(qW[e * HC + lane]) + b1[lane];
    m = fmaxf(m, 0.f);
    float p0 = m * w2[lane * 3 + 0];
    float p1 = m * w2[lane * 3 + 1];
    float p2 = m * w2[lane * 3 + 2];
    for (int msk = 1; msk < 64; msk <<= 1) {
        p0 += __shfl_xor(p0, msk);
        p1 += __shfl_xor(p1, msk);
        p2 += __shfl_xor(p2, msk);
    }
    if (lane == 0) {
        float l0 = p0 + b2[0], l1 = p1 + b2[1], l2 = p2 + b2[2];
        float mx = fmaxf(l0, fmaxf(l1, l2));
        float e0 = __expf(l0 - mx), e1 = __expf(l1 - mx), e2 = __expf(l2 - mx);
        out[e] = (0.5f * e1 + e2) / (e0 + e1 + e2);
    }
}

extern "C" void kernel_launch(void* const* d_in, const int* in_sizes, int n_in,
                              void* d_out, int out_size, void* d_ws, size_t ws_size,
                              hipStream_t stream)
{
    (void)in_sizes; (void)n_in; (void)out_size; (void)ws_size;
    const float* x     = (const float*)d_in[0];
    const int*   ei    = (const int*)  d_in[1];
    const float* ea    = (const float*)d_in[2];
    const float* wl    = (const float*)d_in[3];
    const float* bl    = (const float*)d_in[4];
    const float* wr    = (const float*)d_in[5];
    const float* br    = (const float*)d_in[6];
    const float* we    = (const float*)d_in[7];
    const float* att   = (const float*)d_in[8];
    const float* convb = (const float*)d_in[9];
    const float* w1    = (const float*)d_in[10];
    const float* b1    = (const float*)d_in[11];
    const float* w2    = (const float*)d_in[12];
    const float* b2    = (const float*)d_in[13];

    float* ws = (float*)d_ws;
    float* xl     = ws + O_XL;
    float* xr     = ws + O_XR;
    float* eesum  = ws + O_EESUM;
    float* aggr   = ws + O_AGGR;
    float* cnt    = ws + O_CNT;
    float* ssum   = ws + O_SSUM;
    float* hA     = ws + O_HA;
    float* hB     = ws + O_HB;
    float* exSelf = ws + O_EXSELF;
    float* exE    = ws + O_EXE;
    unsigned short* qW = (unsigned short*)(ws + O_QW);
    unsigned short* wt = (unsigned short*)(ws + O_WT);
    float* out = (float*)d_out;

    hipMemsetAsync(ws + O_EESUM, 0, (size_t)(O_HA - O_EESUM) * sizeof(float), stream);

    k_prep<<<112, 256, 0, stream>>>(we, w1, wt);
    k_node_lin<<<N_NODES / 4, 256, 0, stream>>>(x, wl, bl, wr, br, xl, xr);
    k_edge_main<<<N_EDGES / 64, 256, 0, stream>>>(ea, ei, wt, xl, xr, att,
                                                  eesum, ssum, cnt, exE, qW);
    k_self<<<N_NODES / 4, 256, 0, stream>>>(xl, xr, eesum, cnt, att, ssum, exSelf);
    k_aggr<<<N_EDGES / 16, 256, 0, stream>>>(ei, xl, exE, ssum, aggr);
    k_node_fin<<<N_NODES / 4, 256, 0, stream>>>(xl, aggr, exSelf, ssum, convb, w1, hA, hB);
    k_trust<<<N_EDGES / 4, 256, 0, stream>>>(ei, hA, hB, qW, b1, w2, b2, out);
}

// Round 3
// 1914.965 us; speedup vs baseline: 2.4345x; 1.5628x over previous
//
#include <hip/hip_runtime.h>

#define N_NODES 50000
#define N_EDGES 800000
#define NODE_F  388
#define EDGE_F  385
#define HC      64
#define KRED    384   // 6 K-tiles of 64; k=384 handled as rank-1 in epilogue
#define NKT     6

// ---- workspace layout (float offsets) ----
#define O_XL      0L         // N*64
#define O_XR      3200000L   // N*64
#define O_EESUM   6400000L   // N*64  (zeroed)
#define O_AGGR    9600000L   // N*64  (zeroed)
#define O_CNT     12800000L  // N     (zeroed)
#define O_SSUM    12850000L  // N*2   (zeroed)
#define O_HA      12950000L  // N*64
#define O_HB      16150000L  // N*64
#define O_EXSELF  19350000L  // N*2
#define O_EXE     19450000L  // E*2
#define O_QW      21050000L  // E*64 bf16 (ushort)
#define O_WT      46650000L  // 128 cols x 384 k bf16 transposed weights

typedef __attribute__((ext_vector_type(8))) short bf8;   // 8 bf16 (4 VGPRs)
typedef __attribute__((ext_vector_type(4))) float f4;

typedef __attribute__((address_space(1))) const unsigned char ga_u8;
typedef __attribute__((address_space(3))) unsigned char lds_u8;

static __device__ __forceinline__ void gload_lds16(const void* g, void* l) {
    __builtin_amdgcn_global_load_lds((ga_u8*)g, (lds_u8*)l, 16, 0, 0);
}

static __device__ __forceinline__ unsigned short f2bf(float f) {
    unsigned u = __float_as_uint(f);
    u += 0x7FFFu + ((u >> 16) & 1u);   // RNE
    return (unsigned short)(u >> 16);
}
static __device__ __forceinline__ float bf2f(unsigned short h) {
    return __uint_as_float(((unsigned)h) << 16);
}
static __device__ __forceinline__ unsigned cvtpk(float lo, float hi) {
    unsigned r;
    asm("v_cvt_pk_bf16_f32 %0, %1, %2" : "=v"(r) : "v"(lo), "v"(hi));
    return r;
}

// K0: wt[c][k] bf16, c 0..127, k 0..383. c<64: lin_e_w col c; c>=64: mlp1_w row 128+k col c-64.
__global__ __launch_bounds__(256) void k_prep(
    const float* __restrict__ we, const float* __restrict__ w1,
    unsigned short* __restrict__ wt)
{
    int gid = blockIdx.x * 256 + threadIdx.x;     // 24576 = 128 cols * 192 k-pairs
    int c  = gid / 192;
    int k  = 2 * (gid - c * 192);
    float f0, f1;
    if (c < HC) {
        f0 = we[(long)k * HC + c];
        f1 = we[(long)(k + 1) * HC + c];
    } else {
        f0 = w1[(long)(128 + k) * HC + (c - HC)];
        f1 = w1[(long)(128 + k + 1) * HC + (c - HC)];
    }
    unsigned pk = (unsigned)f2bf(f0) | ((unsigned)f2bf(f1) << 16);
    *(unsigned*)(wt + (long)c * KRED + k) = pk;
}

// K1: xl = x@lin_l_w + bl ; xr = x@lin_r_w + br.
__global__ __launch_bounds__(256) void k_node_lin(
    const float* __restrict__ x, const float* __restrict__ wl, const float* __restrict__ bl,
    const float* __restrict__ wr, const float* __restrict__ br,
    float* __restrict__ xl, float* __restrict__ xr)
{
    const int lane = threadIdx.x & 63;
    const int n = blockIdx.x * 4 + (threadIdx.x >> 6);
    if (n >= N_NODES) return;
    const float* xrow = x + (long)n * NODE_F;
    float accL = 0.f, accR = 0.f;
    for (int k0 = 0; k0 < NODE_F; k0 += 64) {
        float xv = (k0 + lane < NODE_F) ? xrow[k0 + lane] : 0.f;
        int kmax = NODE_F - k0; if (kmax > 64) kmax = 64;
        for (int j = 0; j < kmax; ++j) {
            float xb = __shfl(xv, j);
            accL = fmaf(xb, wl[(k0 + j) * HC + lane], accL);
            accR = fmaf(xb, wr[(k0 + j) * HC + lane], accR);
        }
    }
    xl[(long)n * HC + lane] = accL + bl[lane];
    xr[(long)n * HC + lane] = accR + br[lane];
}

// K2: 64-edge x 128-col MFMA tile; A direct-to-reg from ea(f32), W dbl-buffered LDS via
// global_load_lds; epilogue from fragments. 4 waves: rb=(w&1)*32 rows, cb=(w>>1)*64 cols.
__global__ __launch_bounds__(256, 4) void k_edge_main(
    const float* __restrict__ ea, const int* __restrict__ ei,
    const unsigned short* __restrict__ wt, const float* __restrict__ we,
    const float* __restrict__ xl, const float* __restrict__ xr,
    const float* __restrict__ att,
    float* __restrict__ eesum, float* __restrict__ ssum, float* __restrict__ cnt,
    float* __restrict__ exE, unsigned short* __restrict__ qW)
{
    __shared__ __align__(16) char W_s[2][16384];   // [c 0..127][64 k bf16], XOR-swizzled
    const int t = threadIdx.x;
    const int l = t & 63;
    const int w = t >> 6;
    const long e0 = (long)blockIdx.x * 64;
    const int rb = (w & 1) * 32;
    const int cb = (w >> 1) * 64;
    const int lr = l & 15;
    const int lk = l >> 4;

    // per-lane W source offsets (bytes into wt): dest c = w*32+i*8+(l>>3), kb0=(l&7)*16,
    // read-swizzle ^((c&7)<<4) with c&7 == l>>3  -> pre-swizzle the SOURCE (rule #21)
    int wsrc[4];
#pragma unroll
    for (int i = 0; i < 4; ++i) {
        int c = w * 32 + i * 8 + (l >> 3);
        wsrc[i] = c * (KRED * 2) + ((((l & 7) * 16)) ^ ((l >> 3) << 4));
    }
    const char* wtb = (const char*)wt;

    // A row bases (elements): rows rb+rg*16+lr
    unsigned rowb[2];
#pragma unroll
    for (int rg = 0; rg < 2; ++rg)
        rowb[rg] = (unsigned)((e0 + rb + rg * 16 + lr) * EDGE_F);

    float af[2][16];
    bf8 fa[2][2];
    f4 acc[2][4];
#pragma unroll
    for (int rg = 0; rg < 2; ++rg)
#pragma unroll
        for (int cg = 0; cg < 4; ++cg) acc[rg][cg] = (f4)(0.f);

#define STAGE_W(kt, buf)                                                         \
    {                                                                            \
        _Pragma("unroll")                                                        \
        for (int i = 0; i < 4; ++i)                                              \
            gload_lds16(wtb + wsrc[i] + (kt) * 128, &W_s[buf][w * 4096 + i * 1024]); \
    }

#define ISSUE_A(kt)                                                              \
    {                                                                            \
        _Pragma("unroll")                                                        \
        for (int rg = 0; rg < 2; ++rg) {                                         \
            const float* rp = ea + rowb[rg] + (kt) * 64 + lk * 8;                \
            _Pragma("unroll")                                                    \
            for (int q = 0; q < 16; ++q)                                         \
                af[rg][q] = rp[(q >> 3) * 32 + (q & 7)];                         \
        }                                                                        \
    }

#define CVT_A()                                                                  \
    {                                                                            \
        _Pragma("unroll")                                                        \
        for (int rg = 0; rg < 2; ++rg)                                           \
            _Pragma("unroll")                                                    \
            for (int ks = 0; ks < 2; ++ks) {                                     \
                union { bf8 v; unsigned u[4]; } tu;                              \
                _Pragma("unroll")                                                \
                for (int p = 0; p < 4; ++p)                                      \
                    tu.u[p] = cvtpk(af[rg][ks * 8 + 2 * p], af[rg][ks * 8 + 2 * p + 1]); \
                fa[rg][ks] = tu.v;                                               \
            }                                                                    \
    }

    STAGE_W(0, 0);
    ISSUE_A(0);
    __syncthreads();       // drains vmcnt: W0 in LDS, af loaded
    CVT_A();

    for (int kt = 0; kt < NKT; ++kt) {
        const int buf = kt & 1;
        if (kt < NKT - 1) { STAGE_W(kt + 1, buf ^ 1); ISSUE_A(kt + 1); }
#pragma unroll
        for (int ks = 0; ks < 2; ++ks) {
            const int kb = ks * 64 + lk * 16;
#pragma unroll
            for (int cg = 0; cg < 4; ++cg) {
                const int c = cb + cg * 16 + lr;
                bf8 b = *(bf8*)(&W_s[buf][c * 128 + (kb ^ ((c & 7) << 4))]);
                acc[0][cg] = __builtin_amdgcn_mfma_f32_16x16x32_bf16(fa[0][ks], b, acc[0][cg], 0, 0, 0);
                acc[1][cg] = __builtin_amdgcn_mfma_f32_16x16x32_bf16(fa[1][ks], b, acc[1][cg], 0, 0, 0);
            }
        }
        __syncthreads();   // readers done with buf; drains prefetch (W kt+1, af kt+1)
        if (kt < NKT - 1) CVT_A();
    }

    // ---- epilogue from fragments: C row = rb+rg*16+lk*4+r, col = cb+cg*16+lr ----
    if (cb == 0) {
        float attv[4], w384[4];
#pragma unroll
        for (int cg = 0; cg < 4; ++cg) {
            attv[cg] = att[cg * 16 + lr];
            w384[cg] = we[(long)(EDGE_F - 1) * HC + cg * 16 + lr];
        }
#pragma unroll
        for (int rg = 0; rg < 2; ++rg)
#pragma unroll
        for (int r = 0; r < 4; ++r) {
            const long e = e0 + rb + rg * 16 + lk * 4 + r;
            const int s = ei[e];
            const int g = ei[N_EDGES + e];
            const float a384 = ea[e * EDGE_F + (EDGE_F - 1)];
            float sc0 = 0.f, sc1 = 0.f;
#pragma unroll
            for (int cg = 0; cg < 4; ++cg) {
                const int c = cg * 16 + lr;
                float eev = fmaf(a384, w384[cg], acc[rg][cg][r]);
                atomicAdd(&eesum[(long)g * HC + c], eev);
                float m = eev + xl[(long)s * HC + c] + xr[(long)g * HC + c];
                float lv = m > 0.f ? m : 0.2f * m;
                float tm = lv * attv[cg];
                if (cg < 2) sc0 += tm; else sc1 += tm;
            }
            sc0 += __shfl_xor(sc0, 1); sc0 += __shfl_xor(sc0, 2);
            sc0 += __shfl_xor(sc0, 4); sc0 += __shfl_xor(sc0, 8);
            sc1 += __shfl_xor(sc1, 1); sc1 += __shfl_xor(sc1, 2);
            sc1 += __shfl_xor(sc1, 4); sc1 += __shfl_xor(sc1, 8);
            if (lr == 0) {
                float ex = __expf(sc0);            // no segment-max: shift-invariant
                exE[e * 2 + 0] = ex;
                atomicAdd(&ssum[(long)g * 2 + 0], ex);
                atomicAdd(&cnt[g], 1.0f);
            } else if (lr == 1) {
                float ex = __expf(sc1);
                exE[e * 2 + 1] = ex;
                atomicAdd(&ssum[(long)g * 2 + 1], ex);
            }
        }
    } else {
#pragma unroll
        for (int rg = 0; rg < 2; ++rg)
#pragma unroll
        for (int r = 0; r < 4; ++r) {
            const long e = e0 + rb + rg * 16 + lk * 4 + r;
#pragma unroll
            for (int cg = 0; cg < 4; ++cg) {
                float v = acc[rg][cg][r];
                float nb = __shfl_xor(v, 1);
                if (!(lr & 1)) {
                    unsigned pk = cvtpk(v, nb);
                    *(unsigned*)&qW[e * HC + cg * 16 + lr] = pk;
                }
            }
        }
    }
#undef STAGE_W
#undef ISSUE_A
#undef CVT_A
}

// K3: self-loop edge per node: ee_self = eesum/cnt (linearity of segsum through matmul)
__global__ __launch_bounds__(256) void k_self(
    const float* __restrict__ xl, const float* __restrict__ xr,
    const float* __restrict__ eesum, const float* __restrict__ cnt,
    const float* __restrict__ att,
    float* __restrict__ ssum, float* __restrict__ exSelf)
{
    const int lane = threadIdx.x & 63;
    const int n = blockIdx.x * 4 + (threadIdx.x >> 6);
    if (n >= N_NODES) return;
    float dc = fmaxf(cnt[n], 1.0f);
    float eeS = eesum[(long)n * HC + lane] / dc;
    float v = xl[(long)n * HC + lane] + xr[(long)n * HC + lane] + eeS;
    float lv = v > 0.f ? v : 0.2f * v;
    float partial = lv * att[lane];
    partial += __shfl_xor(partial, 1);
    partial += __shfl_xor(partial, 2);
    partial += __shfl_xor(partial, 4);
    partial += __shfl_xor(partial, 8);
    partial += __shfl_xor(partial, 16);
    if ((lane & 31) == 0) {
        int h = lane >> 5;
        float ex = __expf(partial);
        exSelf[(long)n * 2 + h] = ex;
        ssum[(long)n * 2 + h] += ex;   // single writer per node; after K2
    }
}

// K4: aggr[tgt] += alpha * xl[src]
__global__ __launch_bounds__(256) void k_aggr(
    const int* __restrict__ ei, const float* __restrict__ xl,
    const float* __restrict__ exE, const float* __restrict__ ssum,
    float* __restrict__ aggr)
{
    const int t = threadIdx.x;
    const int sub = t & 15;
    const long e = (long)blockIdx.x * 16 + (t >> 4);
    int s = ei[e], g = ei[N_EDGES + e];
    int h = (sub < 8) ? 0 : 1;
    float alpha = exE[e * 2 + h] / (ssum[(long)g * 2 + h] + 1e-16f);
    const float4 xv = *(const float4*)&xl[(long)s * HC + sub * 4];
    float* dst = &aggr[(long)g * HC + sub * 4];
    atomicAdd(dst + 0, alpha * xv.x);
    atomicAdd(dst + 1, alpha * xv.y);
    atomicAdd(dst + 2, alpha * xv.z);
    atomicAdd(dst + 3, alpha * xv.w);
}

// K5: h = relu(aggr + alpha_self*xl + conv_b); hA = h@W1a, hB = h@W1b
__global__ __launch_bounds__(256) void k_node_fin(
    const float* __restrict__ xl, const float* __restrict__ aggr,
    const float* __restrict__ exSelf, const float* __restrict__ ssum,
    const float* __restrict__ convb, const float* __restrict__ w1,
    float* __restrict__ hA, float* __restrict__ hB)
{
    const int lane = threadIdx.x & 63;
    const int n = blockIdx.x * 4 + (threadIdx.x >> 6);
    if (n >= N_NODES) return;
    int h = lane >> 5;
    float alphaS = exSelf[(long)n * 2 + h] / (ssum[(long)n * 2 + h] + 1e-16f);
    float val = aggr[(long)n * HC + lane] + alphaS * xl[(long)n * HC + lane];
    float hv = fmaxf(val + convb[lane], 0.f);
    float accA = 0.f, accB = 0.f;
    for (int k = 0; k < 64; ++k) {
        float hb = __shfl(hv, k);
        accA = fmaf(hb, w1[k * HC + lane], accA);
        accB = fmaf(hb, w1[(64 + k) * HC + lane], accB);
    }
    hA[(long)n * HC + lane] = accA;
    hB[(long)n * HC + lane] = accB;
}

// K6: trust per edge
__global__ __launch_bounds__(256) void k_trust(
    const int* __restrict__ ei, const float* __restrict__ hA, const float* __restrict__ hB,
    const unsigned short* __restrict__ qW, const float* __restrict__ b1,
    const float* __restrict__ w2, const float* __restrict__ b2,
    float* __restrict__ out)
{
    const int lane = threadIdx.x & 63;
    const long e = (long)blockIdx.x * 4 + (threadIdx.x >> 6);
    if (e >= N_EDGES) return;
    int s = ei[e], g = ei[N_EDGES + e];
    float m = hA[(long)s * HC + lane] + hB[(long)g * HC + lane]
            + bf2f(qW[e * HC + lane]) + b1[lane];
    m = fmaxf(m, 0.f);
    float p0 = m * w2[lane * 3 + 0];
    float p1 = m * w2[lane * 3 + 1];
    float p2 = m * w2[lane * 3 + 2];
    for (int msk = 1; msk < 64; msk <<= 1) {
        p0 += __shfl_xor(p0, msk);
        p1 += __shfl_xor(p1, msk);
        p2 += __shfl_xor(p2, msk);
    }
    if (lane == 0) {
        float l0 = p0 + b2[0], l1 = p1 + b2[1], l2 = p2 + b2[2];
        float mx = fmaxf(l0, fmaxf(l1, l2));
        float e0 = __expf(l0 - mx), e1 = __expf(l1 - mx), e2 = __expf(l2 - mx);
        out[e] = (0.5f * e1 + e2) / (e0 + e1 + e2);
    }
}

extern "C" void kernel_launch(void* const* d_in, const int* in_sizes, int n_in,
                              void* d_out, int out_size, void* d_ws, size_t ws_size,
                              hipStream_t stream)
{
    (void)in_sizes; (void)n_in; (void)out_size; (void)ws_size;
    const float* x     = (const float*)d_in[0];
    const int*   ei    = (const int*)  d_in[1];
    const float* ea    = (const float*)d_in[2];
    const float* wl    = (const float*)d_in[3];
    const float* bl    = (const float*)d_in[4];
    const float* wr    = (const float*)d_in[5];
    const float* br    = (const float*)d_in[6];
    const float* we    = (const float*)d_in[7];
    const float* att   = (const float*)d_in[8];
    const float* convb = (const float*)d_in[9];
    const float* w1    = (const float*)d_in[10];
    const float* b1    = (const float*)d_in[11];
    const float* w2    = (const float*)d_in[12];
    const float* b2    = (const float*)d_in[13];

    float* ws = (float*)d_ws;
    float* xl     = ws + O_XL;
    float* xr     = ws + O_XR;
    float* eesum  = ws + O_EESUM;
    float* aggr   = ws + O_AGGR;
    float* cnt    = ws + O_CNT;
    float* ssum   = ws + O_SSUM;
    float* hA     = ws + O_HA;
    float* hB     = ws + O_HB;
    float* exSelf = ws + O_EXSELF;
    float* exE    = ws + O_EXE;
    unsigned short* qW = (unsigned short*)(ws + O_QW);
    unsigned short* wt = (unsigned short*)(ws + O_WT);
    float* out = (float*)d_out;

    hipMemsetAsync(ws + O_EESUM, 0, (size_t)(O_HA - O_EESUM) * sizeof(float), stream);

    k_prep<<<96, 256, 0, stream>>>(we, w1, wt);
    k_node_lin<<<N_NODES / 4, 256, 0, stream>>>(x, wl, bl, wr, br, xl, xr);
    k_edge_main<<<N_EDGES / 64, 256, 0, stream>>>(ea, ei, wt, we, xl, xr, att,
                                                  eesum, ssum, cnt, exE, qW);
    k_self<<<N_NODES / 4, 256, 0, stream>>>(xl, xr, eesum, cnt, att, ssum, exSelf);
    k_aggr<<<N_EDGES / 16, 256, 0, stream>>>(ei, xl, exE, ssum, aggr);
    k_node_fin<<<N_NODES / 4, 256, 0, stream>>>(xl, aggr, exSelf, ssum, convb, w1, hA, hB);
    k_trust<<<N_EDGES / 4, 256, 0, stream>>>(ei, hA, hB, qW, b1, w2, b2, out);
}

// Round 5
// 1337.883 us; speedup vs baseline: 3.4846x; 1.4313x over previous
//
#include <hip/hip_runtime.h>

#define N_NODES 50000
#define N_EDGES 800000
#define NODE_F  388
#define EDGE_F  385
#define HC      64
#define KRED    384   // 6 K-tiles of 64; k=384 handled as rank-1 in epilogue
#define NKT     6
#define NB      196   // scan blocks: 196*256 >= 50000

// ---- workspace layout (float offsets) ----  [start, end) in floats
#define O_XL      0L          // N*64          [0,        3,200,000)
#define O_XR      3200000L    // N*64          [3.2M,     6,400,000)
#define O_HA      6400000L    // N*64          [6.4M,     9,600,000)
#define O_HB      9600000L    // N*64          [9.6M,    12,800,000)
#define O_EXE     12800000L   // E*2           [12.8M,   14,400,000)
#define O_WT      14400000L   // 24,576 f      [14.4M,   14,424,576)
#define O_DEG     14430000L   // N int         [14.43M,  14,480,000)
#define O_CURSOR  14480000L   // N int         [14.48M,  14,530,000)  contiguous w/ DEG
#define O_ROWPTR  14530000L   // N+1 int       [14.53M,  14,580,001)
#define O_BSUM    14590000L   // NB int        [14.59M,  14,590,196)
#define O_CSRE    14600000L   // E int         [14.6M,   15,400,000)
#define O_CSRS    15400000L   // E int         [15.4M,   16,200,000)
#define O_QW      16200000L   // E*64 bf16 = 25.6M f  [16.2M, 41,800,000)
#define O_EE      42000000L   // E*64 f32      [42M,     93,200,000) = 373 MB total

typedef __attribute__((ext_vector_type(8))) short bf8;   // 8 bf16 (4 VGPRs)
typedef __attribute__((ext_vector_type(4))) float f4;

typedef __attribute__((address_space(1))) const unsigned char ga_u8;
typedef __attribute__((address_space(3))) unsigned char lds_u8;

static __device__ __forceinline__ void gload_lds16(const void* g, void* l) {
    __builtin_amdgcn_global_load_lds((ga_u8*)g, (lds_u8*)l, 16, 0, 0);
}

static __device__ __forceinline__ unsigned short f2bf(float f) {
    unsigned u = __float_as_uint(f);
    u += 0x7FFFu + ((u >> 16) & 1u);   // RNE
    return (unsigned short)(u >> 16);
}
static __device__ __forceinline__ float bf2f(unsigned short h) {
    return __uint_as_float(((unsigned)h) << 16);
}
static __device__ __forceinline__ unsigned cvtpk(float lo, float hi) {
    unsigned r;
    asm("v_cvt_pk_bf16_f32 %0, %1, %2" : "=v"(r) : "v"(lo), "v"(hi));
    return r;
}

// K0: wt[c][k] bf16, c 0..127, k 0..383. c<64: lin_e_w col c; c>=64: mlp1_w row 128+k col c-64.
__global__ __launch_bounds__(256) void k_prep(
    const float* __restrict__ we, const float* __restrict__ w1,
    unsigned short* __restrict__ wt)
{
    int gid = blockIdx.x * 256 + threadIdx.x;     // 24576 = 128 cols * 192 k-pairs
    int c  = gid / 192;
    int k  = 2 * (gid - c * 192);
    float f0, f1;
    if (c < HC) {
        f0 = we[(long)k * HC + c];
        f1 = we[(long)(k + 1) * HC + c];
    } else {
        f0 = w1[(long)(128 + k) * HC + (c - HC)];
        f1 = w1[(long)(128 + k + 1) * HC + (c - HC)];
    }
    unsigned pk = (unsigned)f2bf(f0) | ((unsigned)f2bf(f1) << 16);
    *(unsigned*)(wt + (long)c * KRED + k) = pk;
}

// K1: xl = x@lin_l_w + bl ; xr = x@lin_r_w + br.
__global__ __launch_bounds__(256) void k_node_lin(
    const float* __restrict__ x, const float* __restrict__ wl, const float* __restrict__ bl,
    const float* __restrict__ wr, const float* __restrict__ br,
    float* __restrict__ xl, float* __restrict__ xr)
{
    const int lane = threadIdx.x & 63;
    const int n = blockIdx.x * 4 + (threadIdx.x >> 6);
    if (n >= N_NODES) return;
    const float* xrow = x + (long)n * NODE_F;
    float accL = 0.f, accR = 0.f;
    for (int k0 = 0; k0 < NODE_F; k0 += 64) {
        float xv = (k0 + lane < NODE_F) ? xrow[k0 + lane] : 0.f;
        int kmax = NODE_F - k0; if (kmax > 64) kmax = 64;
        for (int j = 0; j < kmax; ++j) {
            float xb = __shfl(xv, j);
            accL = fmaf(xb, wl[(k0 + j) * HC + lane], accL);
            accR = fmaf(xb, wr[(k0 + j) * HC + lane], accR);
        }
    }
    xl[(long)n * HC + lane] = accL + bl[lane];
    xr[(long)n * HC + lane] = accR + br[lane];
}

// ---- CSR build ----
__global__ __launch_bounds__(256) void k_hist(const int* __restrict__ ei, int* __restrict__ deg)
{
    int e = blockIdx.x * 256 + threadIdx.x;
    if (e < N_EDGES) atomicAdd(&deg[ei[N_EDGES + e]], 1);
}

__global__ __launch_bounds__(256) void k_scan_bsum(const int* __restrict__ deg, int* __restrict__ bsum)
{
    __shared__ int red[4];
    int i = blockIdx.x * 256 + threadIdx.x;
    int v = (i < N_NODES) ? deg[i] : 0;
    for (int m = 1; m < 64; m <<= 1) v += __shfl_xor(v, m);
    if ((threadIdx.x & 63) == 0) red[threadIdx.x >> 6] = v;
    __syncthreads();
    if (threadIdx.x == 0) bsum[blockIdx.x] = red[0] + red[1] + red[2] + red[3];
}

__global__ void k_scan_boff(int* bsum)   // 1 thread: serial exclusive scan of NB values
{
    int run = 0;
    for (int i = 0; i < NB; ++i) { int t = bsum[i]; bsum[i] = run; run += t; }
}

__global__ __launch_bounds__(256) void k_scan_row(const int* __restrict__ deg,
                                                  const int* __restrict__ bsum,
                                                  int* __restrict__ rowptr)
{
    __shared__ int sc[256];
    int t = threadIdx.x;
    int i = blockIdx.x * 256 + t;
    int v = (i < N_NODES) ? deg[i] : 0;
    sc[t] = v; __syncthreads();
    for (int off = 1; off < 256; off <<= 1) {
        int tv = (t >= off) ? sc[t - off] : 0;
        __syncthreads();
        sc[t] += tv;
        __syncthreads();
    }
    if (i < N_NODES) rowptr[i] = bsum[blockIdx.x] + sc[t] - v;   // exclusive
    if (i == N_NODES - 1) rowptr[N_NODES] = N_EDGES;
}

__global__ __launch_bounds__(256) void k_scatter(const int* __restrict__ ei,
                                                 const int* __restrict__ rowptr,
                                                 int* __restrict__ cursor,
                                                 int* __restrict__ csr_e, int* __restrict__ csr_s)
{
    int e = blockIdx.x * 256 + threadIdx.x;
    if (e >= N_EDGES) return;
    int g = ei[N_EDGES + e];
    int pos = rowptr[g] + atomicAdd(&cursor[g], 1);
    csr_e[pos] = e;
    csr_s[pos] = ei[e];
}

// K2: 64-edge x 128-col MFMA tile; A direct-to-reg from ea(f32), W dbl-buffered LDS via
// global_load_lds; epilogue: ee coalesced store + score/exp (no atomics).
__global__ __launch_bounds__(256, 4) void k_edge_main(
    const float* __restrict__ ea, const int* __restrict__ ei,
    const unsigned short* __restrict__ wt, const float* __restrict__ we,
    const float* __restrict__ xl, const float* __restrict__ xr,
    const float* __restrict__ att,
    float* __restrict__ ee, float* __restrict__ exE, unsigned short* __restrict__ qW)
{
    __shared__ __align__(16) char W_s[2][16384];   // [c 0..127][64 k bf16], XOR-swizzled
    const int t = threadIdx.x;
    const int l = t & 63;
    const int w = t >> 6;
    const long e0 = (long)blockIdx.x * 64;
    const int rb = (w & 1) * 32;
    const int cb = (w >> 1) * 64;
    const int lr = l & 15;
    const int lk = l >> 4;

    int wsrc[4];
#pragma unroll
    for (int i = 0; i < 4; ++i) {
        int c = w * 32 + i * 8 + (l >> 3);
        wsrc[i] = c * (KRED * 2) + ((((l & 7) * 16)) ^ ((l >> 3) << 4));
    }
    const char* wtb = (const char*)wt;

    unsigned rowb[2];
#pragma unroll
    for (int rg = 0; rg < 2; ++rg)
        rowb[rg] = (unsigned)((e0 + rb + rg * 16 + lr) * EDGE_F);

    float af[2][16];
    bf8 fa[2][2];
    f4 acc[2][4];
#pragma unroll
    for (int rg = 0; rg < 2; ++rg)
#pragma unroll
        for (int cg = 0; cg < 4; ++cg) acc[rg][cg] = (f4)(0.f);

#define STAGE_W(kt, buf)                                                         \
    {                                                                            \
        _Pragma("unroll")                                                        \
        for (int i = 0; i < 4; ++i)                                              \
            gload_lds16(wtb + wsrc[i] + (kt) * 128, &W_s[buf][w * 4096 + i * 1024]); \
    }

#define ISSUE_A(kt)                                                              \
    {                                                                            \
        _Pragma("unroll")                                                        \
        for (int rg = 0; rg < 2; ++rg) {                                         \
            const float* rp = ea + rowb[rg] + (kt) * 64 + lk * 8;                \
            _Pragma("unroll")                                                    \
            for (int q = 0; q < 16; ++q)                                         \
                af[rg][q] = rp[(q >> 3) * 32 + (q & 7)];                         \
        }                                                                        \
    }

#define CVT_A()                                                                  \
    {                                                                            \
        _Pragma("unroll")                                                        \
        for (int rg = 0; rg < 2; ++rg)                                           \
            _Pragma("unroll")                                                    \
            for (int ks = 0; ks < 2; ++ks) {                                     \
                union { bf8 v; unsigned u[4]; } tu;                              \
                _Pragma("unroll")                                                \
                for (int p = 0; p < 4; ++p)                                      \
                    tu.u[p] = cvtpk(af[rg][ks * 8 + 2 * p], af[rg][ks * 8 + 2 * p + 1]); \
                fa[rg][ks] = tu.v;                                               \
            }                                                                    \
    }

    STAGE_W(0, 0);
    ISSUE_A(0);
    __syncthreads();       // drains vmcnt: W0 in LDS, af loaded
    CVT_A();

    for (int kt = 0; kt < NKT; ++kt) {
        const int buf = kt & 1;
        if (kt < NKT - 1) { STAGE_W(kt + 1, buf ^ 1); ISSUE_A(kt + 1); }
#pragma unroll
        for (int ks = 0; ks < 2; ++ks) {
            const int kb = ks * 64 + lk * 16;
#pragma unroll
            for (int cg = 0; cg < 4; ++cg) {
                const int c = cb + cg * 16 + lr;
                bf8 b = *(bf8*)(&W_s[buf][c * 128 + (kb ^ ((c & 7) << 4))]);
                acc[0][cg] = __builtin_amdgcn_mfma_f32_16x16x32_bf16(fa[0][ks], b, acc[0][cg], 0, 0, 0);
                acc[1][cg] = __builtin_amdgcn_mfma_f32_16x16x32_bf16(fa[1][ks], b, acc[1][cg], 0, 0, 0);
            }
        }
        __syncthreads();   // readers done with buf; drains prefetch (W kt+1, af kt+1)
        if (kt < NKT - 1) CVT_A();
    }

    // ---- epilogue from fragments: C row = rb+rg*16+lk*4+r, col = cb+cg*16+lr ----
    if (cb == 0) {
        float attv[4], w384[4];
#pragma unroll
        for (int cg = 0; cg < 4; ++cg) {
            attv[cg] = att[cg * 16 + lr];
            w384[cg] = we[(long)(EDGE_F - 1) * HC + cg * 16 + lr];
        }
#pragma unroll
        for (int rg = 0; rg < 2; ++rg)
#pragma unroll
        for (int r = 0; r < 4; ++r) {
            const long e = e0 + rb + rg * 16 + lk * 4 + r;
            const int s = ei[e];
            const int g = ei[N_EDGES + e];
            const float a384 = ea[e * EDGE_F + (EDGE_F - 1)];
            float sc0 = 0.f, sc1 = 0.f;
#pragma unroll
            for (int cg = 0; cg < 4; ++cg) {
                const int c = cg * 16 + lr;
                float eev = fmaf(a384, w384[cg], acc[rg][cg][r]);
                ee[e * (long)HC + c] = eev;
                float m = eev + xl[(long)s * HC + c] + xr[(long)g * HC + c];
                float lv = m > 0.f ? m : 0.2f * m;
                float tm = lv * attv[cg];
                if (cg < 2) sc0 += tm; else sc1 += tm;
            }
            sc0 += __shfl_xor(sc0, 1); sc0 += __shfl_xor(sc0, 2);
            sc0 += __shfl_xor(sc0, 4); sc0 += __shfl_xor(sc0, 8);
            sc1 += __shfl_xor(sc1, 1); sc1 += __shfl_xor(sc1, 2);
            sc1 += __shfl_xor(sc1, 4); sc1 += __shfl_xor(sc1, 8);
            if (lr == 0) exE[e * 2 + 0] = __expf(sc0);   // no segment-max: shift-invariant
            else if (lr == 1) exE[e * 2 + 1] = __expf(sc1);
        }
    } else {
#pragma unroll
        for (int rg = 0; rg < 2; ++rg)
#pragma unroll
        for (int r = 0; r < 4; ++r) {
            const long e = e0 + rb + rg * 16 + lk * 4 + r;
#pragma unroll
            for (int cg = 0; cg < 4; ++cg) {
                float v = acc[rg][cg][r];
                float nb = __shfl_xor(v, 1);
                if (!(lr & 1)) {
                    unsigned pk = cvtpk(v, nb);
                    *(unsigned*)&qW[e * HC + cg * 16 + lr] = pk;
                }
            }
        }
    }
#undef STAGE_W
#undef ISSUE_A
#undef CVT_A
}

// K3: per-node CSR aggregation (replaces k_self + k_aggr + k_node_fin; no atomics).
__global__ __launch_bounds__(256) void k_node_agg(
    const int* __restrict__ rowptr, const int* __restrict__ csr_e, const int* __restrict__ csr_s,
    const float* __restrict__ ee, const float* __restrict__ exE,
    const float* __restrict__ xl, const float* __restrict__ xr,
    const float* __restrict__ att, const float* __restrict__ convb,
    const float* __restrict__ w1,
    float* __restrict__ hA, float* __restrict__ hB)
{
    const int lane = threadIdx.x & 63;
    const int n = blockIdx.x * 4 + (threadIdx.x >> 6);
    if (n >= N_NODES) return;
    const int p0 = rowptr[n], p1 = rowptr[n + 1];
    const int h = lane >> 5;
    float eeS = 0.f, sex = 0.f;
#pragma unroll 2
    for (int p = p0; p < p1; ++p) {
        int e = csr_e[p];
        eeS += ee[(long)e * HC + lane];
        sex += exE[e * 2 + h];
    }
    int deg = p1 - p0;
    eeS /= (deg > 0 ? (float)deg : 1.f);
    float v = xl[(long)n * HC + lane] + xr[(long)n * HC + lane] + eeS;
    float lv = v > 0.f ? v : 0.2f * v;
    float partial = lv * att[lane];
    partial += __shfl_xor(partial, 1);
    partial += __shfl_xor(partial, 2);
    partial += __shfl_xor(partial, 4);
    partial += __shfl_xor(partial, 8);
    partial += __shfl_xor(partial, 16);    // each 32-lane half holds its head's score
    float exSelf = __expf(partial);
    float inv = 1.f / (sex + exSelf + 1e-16f);
    float aggr = exSelf * inv * xl[(long)n * HC + lane];
#pragma unroll 2
    for (int p = p0; p < p1; ++p) {
        int e = csr_e[p];
        int s = csr_s[p];
        float alpha = exE[e * 2 + h] * inv;
        aggr = fmaf(alpha, xl[(long)s * HC + lane], aggr);
    }
    float hv = fmaxf(aggr + convb[lane], 0.f);
    float accA = 0.f, accB = 0.f;
    for (int k = 0; k < 64; ++k) {
        float hb = __shfl(hv, k);
        accA = fmaf(hb, w1[k * HC + lane], accA);
        accB = fmaf(hb, w1[(64 + k) * HC + lane], accB);
    }
    hA[(long)n * HC + lane] = accA;
    hB[(long)n * HC + lane] = accB;
}

// K6: trust per edge
__global__ __launch_bounds__(256) void k_trust(
    const int* __restrict__ ei, const float* __restrict__ hA, const float* __restrict__ hB,
    const unsigned short* __restrict__ qW, const float* __restrict__ b1,
    const float* __restrict__ w2, const float* __restrict__ b2,
    float* __restrict__ out)
{
    const int lane = threadIdx.x & 63;
    const long e = (long)blockIdx.x * 4 + (threadIdx.x >> 6);
    if (e >= N_EDGES) return;
    int s = ei[e], g = ei[N_EDGES + e];
    float m = hA[(long)s * HC + lane] + hB[(long)g * HC + lane]
            + bf2f(qW[e * HC + lane]) + b1[lane];
    m = fmaxf(m, 0.f);
    float p0 = m * w2[lane * 3 + 0];
    float p1 = m * w2[lane * 3 + 1];
    float p2 = m * w2[lane * 3 + 2];
    for (int msk = 1; msk < 64; msk <<= 1) {
        p0 += __shfl_xor(p0, msk);
        p1 += __shfl_xor(p1, msk);
        p2 += __shfl_xor(p2, msk);
    }
    if (lane == 0) {
        float l0 = p0 + b2[0], l1 = p1 + b2[1], l2 = p2 + b2[2];
        float mx = fmaxf(l0, fmaxf(l1, l2));
        float e0 = __expf(l0 - mx), e1 = __expf(l1 - mx), e2 = __expf(l2 - mx);
        out[e] = (0.5f * e1 + e2) / (e0 + e1 + e2);
    }
}

extern "C" void kernel_launch(void* const* d_in, const int* in_sizes, int n_in,
                              void* d_out, int out_size, void* d_ws, size_t ws_size,
                              hipStream_t stream)
{
    (void)in_sizes; (void)n_in; (void)out_size; (void)ws_size;
    const float* x     = (const float*)d_in[0];
    const int*   ei    = (const int*)  d_in[1];
    const float* ea    = (const float*)d_in[2];
    const float* wl    = (const float*)d_in[3];
    const float* bl    = (const float*)d_in[4];
    const float* wr    = (const float*)d_in[5];
    const float* br    = (const float*)d_in[6];
    const float* we    = (const float*)d_in[7];
    const float* att   = (const float*)d_in[8];
    const float* convb = (const float*)d_in[9];
    const float* w1    = (const float*)d_in[10];
    const float* b1    = (const float*)d_in[11];
    const float* w2    = (const float*)d_in[12];
    const float* b2    = (const float*)d_in[13];

    float* ws = (float*)d_ws;
    float* xl     = ws + O_XL;
    float* xr     = ws + O_XR;
    float* hA     = ws + O_HA;
    float* hB     = ws + O_HB;
    float* exE    = ws + O_EXE;
    unsigned short* wt = (unsigned short*)(ws + O_WT);
    int* deg    = (int*)(ws + O_DEG);
    int* cursor = (int*)(ws + O_CURSOR);
    int* rowptr = (int*)(ws + O_ROWPTR);
    int* bsum   = (int*)(ws + O_BSUM);
    int* csr_e  = (int*)(ws + O_CSRE);
    int* csr_s  = (int*)(ws + O_CSRS);
    unsigned short* qW = (unsigned short*)(ws + O_QW);
    float* ee   = ws + O_EE;
    float* out  = (float*)d_out;

    hipMemsetAsync(deg, 0, 100000 * sizeof(int), stream);   // deg + cursor (contiguous)

    k_prep<<<96, 256, 0, stream>>>(we, w1, wt);
    k_node_lin<<<N_NODES / 4, 256, 0, stream>>>(x, wl, bl, wr, br, xl, xr);
    k_hist<<<3125, 256, 0, stream>>>(ei, deg);
    k_scan_bsum<<<NB, 256, 0, stream>>>(deg, bsum);
    k_scan_boff<<<1, 1, 0, stream>>>(bsum);
    k_scan_row<<<NB, 256, 0, stream>>>(deg, bsum, rowptr);
    k_scatter<<<3125, 256, 0, stream>>>(ei, rowptr, cursor, csr_e, csr_s);
    k_edge_main<<<N_EDGES / 64, 256, 0, stream>>>(ea, ei, wt, we, xl, xr, att, ee, exE, qW);
    k_node_agg<<<N_NODES / 4, 256, 0, stream>>>(rowptr, csr_e, csr_s, ee, exE,
                                                xl, xr, att, convb, w1, hA, hB);
    k_trust<<<N_EDGES / 4, 256, 0, stream>>>(ei, hA, hB, qW, b1, w2, b2, out);
}

// Round 6
// 1099.987 us; speedup vs baseline: 4.2382x; 1.2163x over previous
//
#include <hip/hip_runtime.h>

#define N_NODES 50000
#define N_EDGES 800000
#define NODE_F  388
#define EDGE_F  385
#define HC      64
#define KRED    384   // edge GEMM: 6 K-tiles of 64; k=384 is rank-1 in epilogue
#define NKT     6
#define KPAD2   448   // node GEMM: 7 K-tiles of 64, zero-padded
#define NKT2    7
#define XBROWS  50048 // 782*64
#define NB      196   // scan blocks: 196*256 >= 50000

// ---- workspace layout (float offsets) ----  [start, end) in floats
#define O_XL      0L          // N*64                  [0,          3,200,000)
#define O_XR      3200000L    //                       [3.2M,       6,400,000)
#define O_HA      6400000L    //                       [6.4M,       9,600,000)
#define O_HB      9600000L    //                       [9.6M,      12,800,000)
#define O_EXE     12800000L   // E*2                   [12.8M,     14,400,000)
#define O_WT      14400000L   // 128*384 bf16=24576f   [14.4M,     14,424,576)
#define O_WT2     14430000L   // 128*448 bf16=28672f   [14.43M,    14,458,672)
#define O_XB      14460000L   // 50048*448 bf16=11,210,752f [14.46M, 25,670,752)
#define O_DEG     25680000L   // N int                 [25.68M,    25,730,000)
#define O_CURSOR  25730000L   // N int (contig w/ DEG) [25.73M,    25,780,000)
#define O_ROWPTR  25790000L   // N+1 int               [25.79M,    25,840,001)
#define O_BSUM    25850000L   // NB int                [25.85M,    25,850,196)
#define O_CSRE    25860000L   // E int                 [25.86M,    26,660,000)
#define O_CSRS    26660000L   // E int                 [26.66M,    27,460,000)
#define O_QW      27500000L   // E*64 bf16 = 25.6M f   [27.5M,     53,100,000)
#define O_EE      53200000L   // E*64 f32              [53.2M,    104,400,000) = 418 MB

typedef __attribute__((ext_vector_type(8))) short bf8;   // 8 bf16 (4 VGPRs)
typedef __attribute__((ext_vector_type(4))) float f4;

typedef __attribute__((address_space(1))) const unsigned char ga_u8;
typedef __attribute__((address_space(3))) unsigned char lds_u8;

static __device__ __forceinline__ void gload_lds16(const void* g, void* l) {
    __builtin_amdgcn_global_load_lds((ga_u8*)g, (lds_u8*)l, 16, 0, 0);
}

static __device__ __forceinline__ unsigned short f2bf(float f) {
    unsigned u = __float_as_uint(f);
    u += 0x7FFFu + ((u >> 16) & 1u);   // RNE
    return (unsigned short)(u >> 16);
}
static __device__ __forceinline__ float bf2f(unsigned short h) {
    return __uint_as_float(((unsigned)h) << 16);
}
static __device__ __forceinline__ unsigned cvtpk(float lo, float hi) {
    unsigned r;
    asm("v_cvt_pk_bf16_f32 %0, %1, %2" : "=v"(r) : "v"(lo), "v"(hi));
    return r;
}

// K0a: edge weights wt[c][k] bf16, c0..63=lin_e_w, c64..127=mlp1_w[128+k], k<384
__global__ __launch_bounds__(256) void k_prep(
    const float* __restrict__ we, const float* __restrict__ w1,
    unsigned short* __restrict__ wt)
{
    int gid = blockIdx.x * 256 + threadIdx.x;     // 24576 = 128 * 192
    int c  = gid / 192;
    int k  = 2 * (gid - c * 192);
    float f0, f1;
    if (c < HC) {
        f0 = we[(long)k * HC + c];
        f1 = we[(long)(k + 1) * HC + c];
    } else {
        f0 = w1[(long)(128 + k) * HC + (c - HC)];
        f1 = w1[(long)(128 + k + 1) * HC + (c - HC)];
    }
    *(unsigned*)(wt + (long)c * KRED + k) =
        (unsigned)f2bf(f0) | ((unsigned)f2bf(f1) << 16);
}

// K0b: node weights wt2[c][k] bf16, c0..63=lin_l_w, c64..127=lin_r_w, k<388 else 0
__global__ __launch_bounds__(256) void k_prep2(
    const float* __restrict__ wl, const float* __restrict__ wr,
    unsigned short* __restrict__ wt2)
{
    int gid = blockIdx.x * 256 + threadIdx.x;     // 28672 = 128 * 224
    int c  = gid / 224;
    int k  = 2 * (gid - c * 224);
    const float* w = (c < HC) ? wl : wr;
    int cc = (c < HC) ? c : c - HC;
    float f0 = (k     < NODE_F) ? w[(long)k * HC + cc] : 0.f;
    float f1 = (k + 1 < NODE_F) ? w[(long)(k + 1) * HC + cc] : 0.f;
    *(unsigned*)(wt2 + (long)c * KPAD2 + k) =
        (unsigned)f2bf(f0) | ((unsigned)f2bf(f1) << 16);
}

// K0c: x (f32 [50000][388]) -> xb (bf16 [50048][448], zero-padded)
__global__ __launch_bounds__(256) void k_cvt_x(
    const float* __restrict__ x, unsigned short* __restrict__ xb)
{
    long gid = (long)blockIdx.x * 256 + threadIdx.x;   // 50048*224 u32 slots
    int row = (int)(gid / 224);
    int k   = 2 * (int)(gid - (long)row * 224);
    float f0 = 0.f, f1 = 0.f;
    if (row < N_NODES) {
        const float* rp = x + (long)row * NODE_F;
        if (k     < NODE_F) f0 = rp[k];
        if (k + 1 < NODE_F) f1 = rp[k + 1];
    }
    *(unsigned*)(xb + (long)row * KPAD2 + k) =
        (unsigned)f2bf(f0) | ((unsigned)f2bf(f1) << 16);
}

// K1: [xl|xr] = xb @ wt2 + bias via MFMA.  64 rows x 128 cols per block.
__global__ __launch_bounds__(256, 5) void k_node_lin(
    const unsigned short* __restrict__ xb, const unsigned short* __restrict__ wt2,
    const float* __restrict__ bl, const float* __restrict__ br,
    float* __restrict__ xl, float* __restrict__ xr)
{
    __shared__ __align__(16) char W_s[2][16384];
    const int t = threadIdx.x;
    const int l = t & 63;
    const int w = t >> 6;
    const int n0 = blockIdx.x * 64;
    const int rb = (w & 1) * 32;
    const int cb = (w >> 1) * 64;
    const int lr = l & 15;
    const int lk = l >> 4;

    int wsrc[4];
#pragma unroll
    for (int i = 0; i < 4; ++i) {
        int c = w * 32 + i * 8 + (l >> 3);
        wsrc[i] = c * (KPAD2 * 2) + ((((l & 7) * 16)) ^ ((l >> 3) << 4));
    }
    const char* wtb = (const char*)wt2;

    const unsigned short* arow0 = xb + (long)(n0 + rb + lr) * KPAD2 + lk * 8;
    const unsigned short* arow1 = arow0 + 16 * KPAD2;

    bf8 fa[2][2], fb[2][2];
    f4 acc[2][4];
#pragma unroll
    for (int rg = 0; rg < 2; ++rg)
#pragma unroll
        for (int cg = 0; cg < 4; ++cg) acc[rg][cg] = (f4)(0.f);

#define STAGE_W2(kt, buf)                                                        \
    {                                                                            \
        _Pragma("unroll")                                                        \
        for (int i = 0; i < 4; ++i)                                              \
            gload_lds16(wtb + wsrc[i] + (kt) * 128, &W_s[buf][w * 4096 + i * 1024]); \
    }
#define LOAD_A2(dst, kt)                                                         \
    {                                                                            \
        _Pragma("unroll")                                                        \
        for (int ks = 0; ks < 2; ++ks) {                                         \
            dst[0][ks] = *(const bf8*)(arow0 + (kt) * 64 + ks * 32);             \
            dst[1][ks] = *(const bf8*)(arow1 + (kt) * 64 + ks * 32);             \
        }                                                                        \
    }

    STAGE_W2(0, 0);
    LOAD_A2(fa, 0);
    __syncthreads();

    for (int kt = 0; kt < NKT2; ++kt) {
        const int buf = kt & 1;
        if (kt < NKT2 - 1) {
            STAGE_W2(kt + 1, buf ^ 1);
            if (buf) LOAD_A2(fa, kt + 1) else LOAD_A2(fb, kt + 1);
        }
        __builtin_amdgcn_s_setprio(1);
#pragma unroll
        for (int ks = 0; ks < 2; ++ks) {
            const int kb = ks * 64 + lk * 16;
#pragma unroll
            for (int cg = 0; cg < 4; ++cg) {
                const int c = cb + cg * 16 + lr;
                bf8 b = *(bf8*)(&W_s[buf][c * 128 + (kb ^ ((c & 7) << 4))]);
                bf8 a0 = buf ? fb[0][ks] : fa[0][ks];
                bf8 a1 = buf ? fb[1][ks] : fa[1][ks];
                acc[0][cg] = __builtin_amdgcn_mfma_f32_16x16x32_bf16(a0, b, acc[0][cg], 0, 0, 0);
                acc[1][cg] = __builtin_amdgcn_mfma_f32_16x16x32_bf16(a1, b, acc[1][cg], 0, 0, 0);
            }
        }
        __builtin_amdgcn_s_setprio(0);
        __syncthreads();
    }

    float bias[4];
#pragma unroll
    for (int cg = 0; cg < 4; ++cg)
        bias[cg] = (cb == 0) ? bl[cg * 16 + lr] : br[cg * 16 + lr];
    float* dst = (cb == 0) ? xl : xr;
#pragma unroll
    for (int rg = 0; rg < 2; ++rg)
#pragma unroll
    for (int r = 0; r < 4; ++r) {
        const int n = n0 + rb + rg * 16 + lk * 4 + r;
        if (n < N_NODES) {
#pragma unroll
            for (int cg = 0; cg < 4; ++cg)
                dst[(long)n * HC + cg * 16 + lr] = acc[rg][cg][r] + bias[cg];
        }
    }
#undef STAGE_W2
#undef LOAD_A2
}

// ---- CSR build ----
__global__ __launch_bounds__(256) void k_hist(const int* __restrict__ ei, int* __restrict__ deg)
{
    int e = blockIdx.x * 256 + threadIdx.x;
    if (e < N_EDGES) atomicAdd(&deg[ei[N_EDGES + e]], 1);
}

__global__ __launch_bounds__(256) void k_scan_bsum(const int* __restrict__ deg, int* __restrict__ bsum)
{
    __shared__ int red[4];
    int i = blockIdx.x * 256 + threadIdx.x;
    int v = (i < N_NODES) ? deg[i] : 0;
    for (int m = 1; m < 64; m <<= 1) v += __shfl_xor(v, m);
    if ((threadIdx.x & 63) == 0) red[threadIdx.x >> 6] = v;
    __syncthreads();
    if (threadIdx.x == 0) bsum[blockIdx.x] = red[0] + red[1] + red[2] + red[3];
}

__global__ __launch_bounds__(256) void k_scan_boff(int* bsum)   // 1 block, parallel
{
    __shared__ int sc[256];
    int t = threadIdx.x;
    int v = (t < NB) ? bsum[t] : 0;
    sc[t] = v; __syncthreads();
    for (int off = 1; off < 256; off <<= 1) {
        int tv = (t >= off) ? sc[t - off] : 0;
        __syncthreads();
        sc[t] += tv;
        __syncthreads();
    }
    if (t < NB) bsum[t] = sc[t] - v;   // exclusive
}

__global__ __launch_bounds__(256) void k_scan_row(const int* __restrict__ deg,
                                                  const int* __restrict__ bsum,
                                                  int* __restrict__ rowptr)
{
    __shared__ int sc[256];
    int t = threadIdx.x;
    int i = blockIdx.x * 256 + t;
    int v = (i < N_NODES) ? deg[i] : 0;
    sc[t] = v; __syncthreads();
    for (int off = 1; off < 256; off <<= 1) {
        int tv = (t >= off) ? sc[t - off] : 0;
        __syncthreads();
        sc[t] += tv;
        __syncthreads();
    }
    if (i < N_NODES) rowptr[i] = bsum[blockIdx.x] + sc[t] - v;   // exclusive
    if (i == N_NODES - 1) rowptr[N_NODES] = N_EDGES;
}

__global__ __launch_bounds__(256) void k_scatter(const int* __restrict__ ei,
                                                 const int* __restrict__ rowptr,
                                                 int* __restrict__ cursor,
                                                 int* __restrict__ csr_e, int* __restrict__ csr_s)
{
    int e = blockIdx.x * 256 + threadIdx.x;
    if (e >= N_EDGES) return;
    int g = ei[N_EDGES + e];
    int pos = rowptr[g] + atomicAdd(&cursor[g], 1);
    csr_e[pos] = e;
    csr_s[pos] = ei[e];
}

// K2: 64-edge x 128-col MFMA tile; A direct-to-reg from ea(f32), W dbuf LDS via
// global_load_lds; epilogue: ee coalesced store + score/exp (no atomics).
__global__ __launch_bounds__(256, 5) void k_edge_main(
    const float* __restrict__ ea, const int* __restrict__ ei,
    const unsigned short* __restrict__ wt, const float* __restrict__ we,
    const float* __restrict__ xl, const float* __restrict__ xr,
    const float* __restrict__ att,
    float* __restrict__ ee, float* __restrict__ exE, unsigned short* __restrict__ qW)
{
    __shared__ __align__(16) char W_s[2][16384];   // [c 0..127][64 k bf16], XOR-swizzled
    const int t = threadIdx.x;
    const int l = t & 63;
    const int w = t >> 6;
    const long e0 = (long)blockIdx.x * 64;
    const int rb = (w & 1) * 32;
    const int cb = (w >> 1) * 64;
    const int lr = l & 15;
    const int lk = l >> 4;

    int wsrc[4];
#pragma unroll
    for (int i = 0; i < 4; ++i) {
        int c = w * 32 + i * 8 + (l >> 3);
        wsrc[i] = c * (KRED * 2) + ((((l & 7) * 16)) ^ ((l >> 3) << 4));
    }
    const char* wtb = (const char*)wt;

    unsigned rowb[2];
#pragma unroll
    for (int rg = 0; rg < 2; ++rg)
        rowb[rg] = (unsigned)((e0 + rb + rg * 16 + lr) * EDGE_F);

    float af[2][16];
    bf8 fa[2][2];
    f4 acc[2][4];
#pragma unroll
    for (int rg = 0; rg < 2; ++rg)
#pragma unroll
        for (int cg = 0; cg < 4; ++cg) acc[rg][cg] = (f4)(0.f);

#define STAGE_W(kt, buf)                                                         \
    {                                                                            \
        _Pragma("unroll")                                                        \
        for (int i = 0; i < 4; ++i)                                              \
            gload_lds16(wtb + wsrc[i] + (kt) * 128, &W_s[buf][w * 4096 + i * 1024]); \
    }

#define ISSUE_A(kt)                                                              \
    {                                                                            \
        _Pragma("unroll")                                                        \
        for (int rg = 0; rg < 2; ++rg) {                                         \
            const float* rp = ea + rowb[rg] + (kt) * 64 + lk * 8;                \
            _Pragma("unroll")                                                    \
            for (int q = 0; q < 16; ++q)                                         \
                af[rg][q] = rp[(q >> 3) * 32 + (q & 7)];                         \
        }                                                                        \
    }

#define CVT_A()                                                                  \
    {                                                                            \
        _Pragma("unroll")                                                        \
        for (int rg = 0; rg < 2; ++rg)                                           \
            _Pragma("unroll")                                                    \
            for (int ks = 0; ks < 2; ++ks) {                                     \
                union { bf8 v; unsigned u[4]; } tu;                              \
                _Pragma("unroll")                                                \
                for (int p = 0; p < 4; ++p)                                      \
                    tu.u[p] = cvtpk(af[rg][ks * 8 + 2 * p], af[rg][ks * 8 + 2 * p + 1]); \
                fa[rg][ks] = tu.v;                                               \
            }                                                                    \
    }

    STAGE_W(0, 0);
    ISSUE_A(0);
    __syncthreads();       // drains vmcnt: W0 in LDS, af loaded
    CVT_A();

    for (int kt = 0; kt < NKT; ++kt) {
        const int buf = kt & 1;
        if (kt < NKT - 1) { STAGE_W(kt + 1, buf ^ 1); ISSUE_A(kt + 1); }
        __builtin_amdgcn_s_setprio(1);
#pragma unroll
        for (int ks = 0; ks < 2; ++ks) {
            const int kb = ks * 64 + lk * 16;
#pragma unroll
            for (int cg = 0; cg < 4; ++cg) {
                const int c = cb + cg * 16 + lr;
                bf8 b = *(bf8*)(&W_s[buf][c * 128 + (kb ^ ((c & 7) << 4))]);
                acc[0][cg] = __builtin_amdgcn_mfma_f32_16x16x32_bf16(fa[0][ks], b, acc[0][cg], 0, 0, 0);
                acc[1][cg] = __builtin_amdgcn_mfma_f32_16x16x32_bf16(fa[1][ks], b, acc[1][cg], 0, 0, 0);
            }
        }
        __builtin_amdgcn_s_setprio(0);
        __syncthreads();   // readers done with buf; drains prefetch (W kt+1, af kt+1)
        if (kt < NKT - 1) CVT_A();
    }

    // ---- epilogue from fragments: C row = rb+rg*16+lk*4+r, col = cb+cg*16+lr ----
    if (cb == 0) {
        float attv[4], w384[4];
#pragma unroll
        for (int cg = 0; cg < 4; ++cg) {
            attv[cg] = att[cg * 16 + lr];
            w384[cg] = we[(long)(EDGE_F - 1) * HC + cg * 16 + lr];
        }
#pragma unroll
        for (int rg = 0; rg < 2; ++rg)
#pragma unroll
        for (int r = 0; r < 4; ++r) {
            const long e = e0 + rb + rg * 16 + lk * 4 + r;
            const int s = ei[e];
            const int g = ei[N_EDGES + e];
            const float a384 = ea[e * EDGE_F + (EDGE_F - 1)];
            float sc0 = 0.f, sc1 = 0.f;
#pragma unroll
            for (int cg = 0; cg < 4; ++cg) {
                const int c = cg * 16 + lr;
                float eev = fmaf(a384, w384[cg], acc[rg][cg][r]);
                ee[e * (long)HC + c] = eev;
                float m = eev + xl[(long)s * HC + c] + xr[(long)g * HC + c];
                float lv = m > 0.f ? m : 0.2f * m;
                float tm = lv * attv[cg];
                if (cg < 2) sc0 += tm; else sc1 += tm;
            }
            sc0 += __shfl_xor(sc0, 1); sc0 += __shfl_xor(sc0, 2);
            sc0 += __shfl_xor(sc0, 4); sc0 += __shfl_xor(sc0, 8);
            sc1 += __shfl_xor(sc1, 1); sc1 += __shfl_xor(sc1, 2);
            sc1 += __shfl_xor(sc1, 4); sc1 += __shfl_xor(sc1, 8);
            if (lr == 0) exE[e * 2 + 0] = __expf(sc0);   // no segment-max: shift-invariant
            else if (lr == 1) exE[e * 2 + 1] = __expf(sc1);
        }
    } else {
#pragma unroll
        for (int rg = 0; rg < 2; ++rg)
#pragma unroll
        for (int r = 0; r < 4; ++r) {
            const long e = e0 + rb + rg * 16 + lk * 4 + r;
#pragma unroll
            for (int cg = 0; cg < 4; ++cg) {
                float v = acc[rg][cg][r];
                float nb = __shfl_xor(v, 1);
                if (!(lr & 1)) {
                    unsigned pk = cvtpk(v, nb);
                    *(unsigned*)&qW[e * HC + cg * 16 + lr] = pk;
                }
            }
        }
    }
#undef STAGE_W
#undef ISSUE_A
#undef CVT_A
}

// K3: per-node CSR aggregation; chunked register-cached csr lists, no dependent chains.
__global__ __launch_bounds__(256) void k_node_agg(
    const int* __restrict__ rowptr, const int* __restrict__ csr_e, const int* __restrict__ csr_s,
    const float* __restrict__ ee, const float* __restrict__ exE,
    const float* __restrict__ xl, const float* __restrict__ xr,
    const float* __restrict__ att, const float* __restrict__ convb,
    const float* __restrict__ w1,
    float* __restrict__ hA, float* __restrict__ hB)
{
    const int lane = threadIdx.x & 63;
    const int n = blockIdx.x * 4 + (threadIdx.x >> 6);
    if (n >= N_NODES) return;
    const int p0 = rowptr[n], p1 = rowptr[n + 1];
    const int h = lane >> 5;

    float eeS = 0.f, s0 = 0.f, s1 = 0.f;
    for (int base = p0; base < p1; base += 64) {
        int m = p1 - base; if (m > 64) m = 64;
        int ew = (lane < m) ? csr_e[base + lane] : 0;
        if (lane < m) {
            float2 ex2 = *(const float2*)&exE[(long)ew * 2];
            s0 += ex2.x; s1 += ex2.y;
        }
        for (int j = 0; j < m; ++j) {
            int e = __shfl(ew, j);
            eeS += ee[(long)e * HC + lane];
        }
    }
    for (int msk = 1; msk < 64; msk <<= 1) {
        s0 += __shfl_xor(s0, msk);
        s1 += __shfl_xor(s1, msk);
    }
    float sex = h ? s1 : s0;

    int deg = p1 - p0;
    eeS /= (deg > 0 ? (float)deg : 1.f);
    float v = xl[(long)n * HC + lane] + xr[(long)n * HC + lane] + eeS;
    float lv = v > 0.f ? v : 0.2f * v;
    float partial = lv * att[lane];
    partial += __shfl_xor(partial, 1);
    partial += __shfl_xor(partial, 2);
    partial += __shfl_xor(partial, 4);
    partial += __shfl_xor(partial, 8);
    partial += __shfl_xor(partial, 16);    // each 32-lane half holds its head's score
    float exSelf = __expf(partial);
    float inv = 1.f / (sex + exSelf + 1e-16f);
    float aggr = exSelf * inv * xl[(long)n * HC + lane];

    for (int base = p0; base < p1; base += 64) {
        int m = p1 - base; if (m > 64) m = 64;
        int ew  = (lane < m) ? csr_e[base + lane] : 0;
        int sw_ = (lane < m) ? csr_s[base + lane] : 0;
        float a0 = 0.f, a1 = 0.f;
        if (lane < m) {
            float2 ex2 = *(const float2*)&exE[(long)ew * 2];
            a0 = ex2.x; a1 = ex2.y;
        }
        for (int j = 0; j < m; ++j) {
            int s = __shfl(sw_, j);
            float t0 = __shfl(a0, j), t1 = __shfl(a1, j);
            float alpha = (h ? t1 : t0) * inv;
            aggr = fmaf(alpha, xl[(long)s * HC + lane], aggr);
        }
    }

    float hv = fmaxf(aggr + convb[lane], 0.f);
    float accA = 0.f, accB = 0.f;
    for (int k = 0; k < 64; ++k) {
        float hb = __shfl(hv, k);
        accA = fmaf(hb, w1[k * HC + lane], accA);
        accB = fmaf(hb, w1[(64 + k) * HC + lane], accB);
    }
    hA[(long)n * HC + lane] = accA;
    hB[(long)n * HC + lane] = accB;
}

// K6: trust per edge
__global__ __launch_bounds__(256) void k_trust(
    const int* __restrict__ ei, const float* __restrict__ hA, const float* __restrict__ hB,
    const unsigned short* __restrict__ qW, const float* __restrict__ b1,
    const float* __restrict__ w2, const float* __restrict__ b2,
    float* __restrict__ out)
{
    const int lane = threadIdx.x & 63;
    const long e = (long)blockIdx.x * 4 + (threadIdx.x >> 6);
    if (e >= N_EDGES) return;
    int s = ei[e], g = ei[N_EDGES + e];
    float m = hA[(long)s * HC + lane] + hB[(long)g * HC + lane]
            + bf2f(qW[e * HC + lane]) + b1[lane];
    m = fmaxf(m, 0.f);
    float p0 = m * w2[lane * 3 + 0];
    float p1 = m * w2[lane * 3 + 1];
    float p2 = m * w2[lane * 3 + 2];
    for (int msk = 1; msk < 64; msk <<= 1) {
        p0 += __shfl_xor(p0, msk);
        p1 += __shfl_xor(p1, msk);
        p2 += __shfl_xor(p2, msk);
    }
    if (lane == 0) {
        float l0 = p0 + b2[0], l1 = p1 + b2[1], l2 = p2 + b2[2];
        float mx = fmaxf(l0, fmaxf(l1, l2));
        float e0 = __expf(l0 - mx), e1 = __expf(l1 - mx), e2 = __expf(l2 - mx);
        out[e] = (0.5f * e1 + e2) / (e0 + e1 + e2);
    }
}

extern "C" void kernel_launch(void* const* d_in, const int* in_sizes, int n_in,
                              void* d_out, int out_size, void* d_ws, size_t ws_size,
                              hipStream_t stream)
{
    (void)in_sizes; (void)n_in; (void)out_size; (void)ws_size;
    const float* x     = (const float*)d_in[0];
    const int*   ei    = (const int*)  d_in[1];
    const float* ea    = (const float*)d_in[2];
    const float* wl    = (const float*)d_in[3];
    const float* bl    = (const float*)d_in[4];
    const float* wr    = (const float*)d_in[5];
    const float* br    = (const float*)d_in[6];
    const float* we    = (const float*)d_in[7];
    const float* att   = (const float*)d_in[8];
    const float* convb = (const float*)d_in[9];
    const float* w1    = (const float*)d_in[10];
    const float* b1    = (const float*)d_in[11];
    const float* w2    = (const float*)d_in[12];
    const float* b2    = (const float*)d_in[13];

    float* ws = (float*)d_ws;
    float* xl     = ws + O_XL;
    float* xr     = ws + O_XR;
    float* hA     = ws + O_HA;
    float* hB     = ws + O_HB;
    float* exE    = ws + O_EXE;
    unsigned short* wt  = (unsigned short*)(ws + O_WT);
    unsigned short* wt2 = (unsigned short*)(ws + O_WT2);
    unsigned short* xb  = (unsigned short*)(ws + O_XB);
    int* deg    = (int*)(ws + O_DEG);
    int* cursor = (int*)(ws + O_CURSOR);
    int* rowptr = (int*)(ws + O_ROWPTR);
    int* bsum   = (int*)(ws + O_BSUM);
    int* csr_e  = (int*)(ws + O_CSRE);
    int* csr_s  = (int*)(ws + O_CSRS);
    unsigned short* qW = (unsigned short*)(ws + O_QW);
    float* ee   = ws + O_EE;
    float* out  = (float*)d_out;

    hipMemsetAsync(deg, 0, 100000 * sizeof(int), stream);   // deg + cursor (contiguous)

    k_prep<<<96, 256, 0, stream>>>(we, w1, wt);
    k_prep2<<<112, 256, 0, stream>>>(wl, wr, wt2);
    k_cvt_x<<<43792, 256, 0, stream>>>(x, xb);
    k_hist<<<3125, 256, 0, stream>>>(ei, deg);
    k_scan_bsum<<<NB, 256, 0, stream>>>(deg, bsum);
    k_scan_boff<<<1, 256, 0, stream>>>(bsum);
    k_scan_row<<<NB, 256, 0, stream>>>(deg, bsum, rowptr);
    k_scatter<<<3125, 256, 0, stream>>>(ei, rowptr, cursor, csr_e, csr_s);
    k_node_lin<<<XBROWS / 64, 256, 0, stream>>>(xb, wt2, bl, br, xl, xr);
    k_edge_main<<<N_EDGES / 64, 256, 0, stream>>>(ea, ei, wt, we, xl, xr, att, ee, exE, qW);
    k_node_agg<<<N_NODES / 4, 256, 0, stream>>>(rowptr, csr_e, csr_s, ee, exE,
                                                xl, xr, att, convb, w1, hA, hB);
    k_trust<<<N_EDGES / 4, 256, 0, stream>>>(ei, hA, hB, qW, b1, w2, b2, out);
}

// Round 7
// 1028.471 us; speedup vs baseline: 4.5329x; 1.0695x over previous
//
#include <hip/hip_runtime.h>

#define N_NODES 50000
#define N_EDGES 800000
#define NODE_F  388
#define EDGE_F  385
#define HC      64
#define KRED    384   // both GEMMs: 6 K-tiles of 64; k>=384 handled in epilogue
#define NKT     6
#define NB      196   // scan blocks: 196*256 >= 50000

// ---- workspace layout (float offsets) ----  [start, end) in floats
#define O_XLB     0L          // N*64 bf16 = 1.6M f    [0,          1,600,000)
#define O_XRB     1600000L    //                       [1.6M,       3,200,000)
#define O_HAB     3200000L    //                       [3.2M,       4,800,000)
#define O_HBB     4800000L    //                       [4.8M,       6,400,000)
#define O_EXE     6400000L    // E*2 f32               [6.4M,       8,000,000)
#define O_WT      8000000L    // 128*384 bf16=24576f   [8.0M,       8,024,576)
#define O_WT2     8030000L    // 128*384 bf16=24576f   [8.03M,      8,054,576)
#define O_DEG     8060000L    // N int                 [8.06M,      8,110,000)
#define O_CURSOR  8110000L    // N int (contig w/ DEG) [8.11M,      8,160,000)
#define O_ROWPTR  8160000L    // N+1 int               [8.16M,      8,210,001)
#define O_BSUM    8211000L    // NB int                [8.211M,     8,211,196)
#define O_CSRE    8220000L    // E int                 [8.22M,      9,020,000)
#define O_CSRS    9020000L    // E int                 [9.02M,      9,820,000)
#define O_QW      9820000L    // E*64 bf16 = 25.6M f   [9.82M,     35,420,000)
#define O_EEB     35420000L   // E*64 bf16 = 25.6M f   [35.42M,    61,020,000) = 244 MB

typedef __attribute__((ext_vector_type(8))) short bf8;   // 8 bf16 (4 VGPRs)
typedef __attribute__((ext_vector_type(4))) float f4;

typedef __attribute__((address_space(1))) const unsigned char ga_u8;
typedef __attribute__((address_space(3))) unsigned char lds_u8;

static __device__ __forceinline__ void gload_lds16(const void* g, void* l) {
    __builtin_amdgcn_global_load_lds((ga_u8*)g, (lds_u8*)l, 16, 0, 0);
}

static __device__ __forceinline__ unsigned short f2bf(float f) {
    unsigned u = __float_as_uint(f);
    u += 0x7FFFu + ((u >> 16) & 1u);   // RNE
    return (unsigned short)(u >> 16);
}
static __device__ __forceinline__ float bf2f(unsigned short h) {
    return __uint_as_float(((unsigned)h) << 16);
}
static __device__ __forceinline__ unsigned cvtpk(float lo, float hi) {
    unsigned r;
    asm("v_cvt_pk_bf16_f32 %0, %1, %2" : "=v"(r) : "v"(lo), "v"(hi));
    return r;
}

// K0a: edge weights wt[c][k] bf16, c0..63=lin_e_w, c64..127=mlp1_w[128+k], k<384
__global__ __launch_bounds__(256) void k_prep(
    const float* __restrict__ we, const float* __restrict__ w1,
    unsigned short* __restrict__ wt)
{
    int gid = blockIdx.x * 256 + threadIdx.x;     // 24576 = 128 * 192
    int c  = gid / 192;
    int k  = 2 * (gid - c * 192);
    float f0, f1;
    if (c < HC) {
        f0 = we[(long)k * HC + c];
        f1 = we[(long)(k + 1) * HC + c];
    } else {
        f0 = w1[(long)(128 + k) * HC + (c - HC)];
        f1 = w1[(long)(128 + k + 1) * HC + (c - HC)];
    }
    *(unsigned*)(wt + (long)c * KRED + k) =
        (unsigned)f2bf(f0) | ((unsigned)f2bf(f1) << 16);
}

// K0b: node weights wt2[c][k] bf16, c0..63=lin_l_w col c, c64..127=lin_r_w col c-64, k<384
__global__ __launch_bounds__(256) void k_prep2(
    const float* __restrict__ wl, const float* __restrict__ wr,
    unsigned short* __restrict__ wt2)
{
    int gid = blockIdx.x * 256 + threadIdx.x;     // 24576 = 128 * 192
    int c  = gid / 192;
    int k  = 2 * (gid - c * 192);
    const float* w = (c < HC) ? wl : wr;
    int cc = (c < HC) ? c : c - HC;
    float f0 = w[(long)k * HC + cc];
    float f1 = w[(long)(k + 1) * HC + cc];
    *(unsigned*)(wt2 + (long)c * KRED + k) =
        (unsigned)f2bf(f0) | ((unsigned)f2bf(f1) << 16);
}

// K1: [xl|xr] = x @ [wl|wr] + bias via MFMA; A direct-to-reg f32->bf16 (x rows 16B-aligned),
// k=384..387 rank-4 in epilogue; bf16 output.
__global__ __launch_bounds__(256, 5) void k_node_lin(
    const float* __restrict__ x, const unsigned short* __restrict__ wt2,
    const float* __restrict__ wl, const float* __restrict__ wr,
    const float* __restrict__ bl, const float* __restrict__ br,
    unsigned short* __restrict__ xlb, unsigned short* __restrict__ xrb)
{
    __shared__ __align__(16) char W_s[2][16384];
    const int t = threadIdx.x;
    const int l = t & 63;
    const int w = t >> 6;
    const int n0 = blockIdx.x * 64;
    const int rb = (w & 1) * 32;
    const int cb = (w >> 1) * 64;
    const int lr = l & 15;
    const int lk = l >> 4;

    int wsrc[4];
#pragma unroll
    for (int i = 0; i < 4; ++i) {
        int c = w * 32 + i * 8 + (l >> 3);
        wsrc[i] = c * (KRED * 2) + ((((l & 7) * 16)) ^ ((l >> 3) << 4));
    }
    const char* wtb = (const char*)wt2;

    long rowx[2];
#pragma unroll
    for (int rg = 0; rg < 2; ++rg) {
        int n = n0 + rb + rg * 16 + lr;
        if (n >= N_NODES) n = N_NODES - 1;        // clamp loads; stores guarded
        rowx[rg] = (long)n * NODE_F;
    }

    float af[2][16];
    bf8 fa[2][2];
    f4 acc[2][4];
#pragma unroll
    for (int rg = 0; rg < 2; ++rg)
#pragma unroll
        for (int cg = 0; cg < 4; ++cg) acc[rg][cg] = (f4)(0.f);

#define STAGE_W(kt, buf)                                                         \
    {                                                                            \
        _Pragma("unroll")                                                        \
        for (int i = 0; i < 4; ++i)                                              \
            gload_lds16(wtb + wsrc[i] + (kt) * 128, &W_s[buf][w * 4096 + i * 1024]); \
    }
#define ISSUE_AX(kt)                                                             \
    {                                                                            \
        _Pragma("unroll")                                                        \
        for (int rg = 0; rg < 2; ++rg) {                                         \
            const float* rp = x + rowx[rg] + (kt) * 64 + lk * 8;                 \
            float4 a0 = *(const float4*)(rp);                                    \
            float4 a1 = *(const float4*)(rp + 4);                                \
            float4 a2 = *(const float4*)(rp + 32);                               \
            float4 a3 = *(const float4*)(rp + 36);                               \
            af[rg][0]=a0.x; af[rg][1]=a0.y; af[rg][2]=a0.z; af[rg][3]=a0.w;      \
            af[rg][4]=a1.x; af[rg][5]=a1.y; af[rg][6]=a1.z; af[rg][7]=a1.w;      \
            af[rg][8]=a2.x; af[rg][9]=a2.y; af[rg][10]=a2.z; af[rg][11]=a2.w;    \
            af[rg][12]=a3.x; af[rg][13]=a3.y; af[rg][14]=a3.z; af[rg][15]=a3.w;  \
        }                                                                        \
    }
#define CVT_A()                                                                  \
    {                                                                            \
        _Pragma("unroll")                                                        \
        for (int rg = 0; rg < 2; ++rg)                                           \
            _Pragma("unroll")                                                    \
            for (int ks = 0; ks < 2; ++ks) {                                     \
                union { bf8 v; unsigned u[4]; } tu;                              \
                _Pragma("unroll")                                                \
                for (int p = 0; p < 4; ++p)                                      \
                    tu.u[p] = cvtpk(af[rg][ks * 8 + 2 * p], af[rg][ks * 8 + 2 * p + 1]); \
                fa[rg][ks] = tu.v;                                               \
            }                                                                    \
    }

    STAGE_W(0, 0);
    ISSUE_AX(0);
    __syncthreads();
    CVT_A();

    for (int kt = 0; kt < NKT; ++kt) {
        const int buf = kt & 1;
        if (kt < NKT - 1) { STAGE_W(kt + 1, buf ^ 1); ISSUE_AX(kt + 1); }
        __builtin_amdgcn_s_setprio(1);
#pragma unroll
        for (int ks = 0; ks < 2; ++ks) {
            const int kb = ks * 64 + lk * 16;
#pragma unroll
            for (int cg = 0; cg < 4; ++cg) {
                const int c = cb + cg * 16 + lr;
                bf8 b = *(bf8*)(&W_s[buf][c * 128 + (kb ^ ((c & 7) << 4))]);
                acc[0][cg] = __builtin_amdgcn_mfma_f32_16x16x32_bf16(fa[0][ks], b, acc[0][cg], 0, 0, 0);
                acc[1][cg] = __builtin_amdgcn_mfma_f32_16x16x32_bf16(fa[1][ks], b, acc[1][cg], 0, 0, 0);
            }
        }
        __builtin_amdgcn_s_setprio(0);
        __syncthreads();
        if (kt < NKT - 1) CVT_A();
    }

    // epilogue: rank-4 tail (k=384..387) + bias + bf16 pack store
    const float* wsf = (cb == 0) ? wl : wr;
    const float* bsf = (cb == 0) ? bl : br;
    unsigned short* dst = (cb == 0) ? xlb : xrb;
    float wtail[4][4], bias[4];
#pragma unroll
    for (int cg = 0; cg < 4; ++cg) {
        int c = cg * 16 + lr;
        bias[cg] = bsf[c];
#pragma unroll
        for (int j = 0; j < 4; ++j)
            wtail[j][cg] = wsf[(long)(KRED + j) * HC + c];
    }
#pragma unroll
    for (int rg = 0; rg < 2; ++rg)
#pragma unroll
    for (int r = 0; r < 4; ++r) {
        const int n = n0 + rb + rg * 16 + lk * 4 + r;
        const int nc = (n < N_NODES) ? n : N_NODES - 1;
        float4 xt = *(const float4*)(x + (long)nc * NODE_F + KRED);
#pragma unroll
        for (int cg = 0; cg < 4; ++cg) {
            float v = acc[rg][cg][r] + bias[cg]
                    + xt.x * wtail[0][cg] + xt.y * wtail[1][cg]
                    + xt.z * wtail[2][cg] + xt.w * wtail[3][cg];
            float nb = __shfl_xor(v, 1);
            if (!(lr & 1) && n < N_NODES)
                *(unsigned*)&dst[(long)n * HC + cg * 16 + lr] = cvtpk(v, nb);
        }
    }
#undef STAGE_W
#undef ISSUE_AX
#undef CVT_A
}

// ---- CSR build ----
__global__ __launch_bounds__(256) void k_hist(const int* __restrict__ ei, int* __restrict__ deg)
{
    int e = blockIdx.x * 256 + threadIdx.x;
    if (e < N_EDGES) atomicAdd(&deg[ei[N_EDGES + e]], 1);
}

__global__ __launch_bounds__(256) void k_scan_bsum(const int* __restrict__ deg, int* __restrict__ bsum)
{
    __shared__ int red[4];
    int i = blockIdx.x * 256 + threadIdx.x;
    int v = (i < N_NODES) ? deg[i] : 0;
    for (int m = 1; m < 64; m <<= 1) v += __shfl_xor(v, m);
    if ((threadIdx.x & 63) == 0) red[threadIdx.x >> 6] = v;
    __syncthreads();
    if (threadIdx.x == 0) bsum[blockIdx.x] = red[0] + red[1] + red[2] + red[3];
}

__global__ __launch_bounds__(256) void k_scan_boff(int* bsum)   // 1 block, parallel
{
    __shared__ int sc[256];
    int t = threadIdx.x;
    int v = (t < NB) ? bsum[t] : 0;
    sc[t] = v; __syncthreads();
    for (int off = 1; off < 256; off <<= 1) {
        int tv = (t >= off) ? sc[t - off] : 0;
        __syncthreads();
        sc[t] += tv;
        __syncthreads();
    }
    if (t < NB) bsum[t] = sc[t] - v;   // exclusive
}

__global__ __launch_bounds__(256) void k_scan_row(const int* __restrict__ deg,
                                                  const int* __restrict__ bsum,
                                                  int* __restrict__ rowptr)
{
    __shared__ int sc[256];
    int t = threadIdx.x;
    int i = blockIdx.x * 256 + t;
    int v = (i < N_NODES) ? deg[i] : 0;
    sc[t] = v; __syncthreads();
    for (int off = 1; off < 256; off <<= 1) {
        int tv = (t >= off) ? sc[t - off] : 0;
        __syncthreads();
        sc[t] += tv;
        __syncthreads();
    }
    if (i < N_NODES) rowptr[i] = bsum[blockIdx.x] + sc[t] - v;   // exclusive
    if (i == N_NODES - 1) rowptr[N_NODES] = N_EDGES;
}

__global__ __launch_bounds__(256) void k_scatter(const int* __restrict__ ei,
                                                 const int* __restrict__ rowptr,
                                                 int* __restrict__ cursor,
                                                 int* __restrict__ csr_e, int* __restrict__ csr_s)
{
    int e = blockIdx.x * 256 + threadIdx.x;
    if (e >= N_EDGES) return;
    int g = ei[N_EDGES + e];
    int pos = rowptr[g] + atomicAdd(&cursor[g], 1);
    csr_e[pos] = e;
    csr_s[pos] = ei[e];
}

// K2: 64-edge x 128-col MFMA tile; A direct-to-reg from ea(f32), W dbuf LDS via
// global_load_lds; epilogue: eeb/qW bf16 stores + score/exp (no atomics).
__global__ __launch_bounds__(256, 5) void k_edge_main(
    const float* __restrict__ ea, const int* __restrict__ ei,
    const unsigned short* __restrict__ wt, const float* __restrict__ we,
    const unsigned short* __restrict__ xlb, const unsigned short* __restrict__ xrb,
    const float* __restrict__ att,
    unsigned short* __restrict__ eeb, float* __restrict__ exE,
    unsigned short* __restrict__ qW)
{
    __shared__ __align__(16) char W_s[2][16384];   // [c 0..127][64 k bf16], XOR-swizzled
    const int t = threadIdx.x;
    const int l = t & 63;
    const int w = t >> 6;
    const long e0 = (long)blockIdx.x * 64;
    const int rb = (w & 1) * 32;
    const int cb = (w >> 1) * 64;
    const int lr = l & 15;
    const int lk = l >> 4;

    int wsrc[4];
#pragma unroll
    for (int i = 0; i < 4; ++i) {
        int c = w * 32 + i * 8 + (l >> 3);
        wsrc[i] = c * (KRED * 2) + ((((l & 7) * 16)) ^ ((l >> 3) << 4));
    }
    const char* wtb = (const char*)wt;

    unsigned rowb[2];
#pragma unroll
    for (int rg = 0; rg < 2; ++rg)
        rowb[rg] = (unsigned)((e0 + rb + rg * 16 + lr) * EDGE_F);

    float af[2][16];
    bf8 fa[2][2];
    f4 acc[2][4];
#pragma unroll
    for (int rg = 0; rg < 2; ++rg)
#pragma unroll
        for (int cg = 0; cg < 4; ++cg) acc[rg][cg] = (f4)(0.f);

#define STAGE_W(kt, buf)                                                         \
    {                                                                            \
        _Pragma("unroll")                                                        \
        for (int i = 0; i < 4; ++i)                                              \
            gload_lds16(wtb + wsrc[i] + (kt) * 128, &W_s[buf][w * 4096 + i * 1024]); \
    }

#define ISSUE_A(kt)                                                              \
    {                                                                            \
        _Pragma("unroll")                                                        \
        for (int rg = 0; rg < 2; ++rg) {                                         \
            const float* rp = ea + rowb[rg] + (kt) * 64 + lk * 8;                \
            _Pragma("unroll")                                                    \
            for (int q = 0; q < 16; ++q)                                         \
                af[rg][q] = rp[(q >> 3) * 32 + (q & 7)];                         \
        }                                                                        \
    }

#define CVT_A()                                                                  \
    {                                                                            \
        _Pragma("unroll")                                                        \
        for (int rg = 0; rg < 2; ++rg)                                           \
            _Pragma("unroll")                                                    \
            for (int ks = 0; ks < 2; ++ks) {                                     \
                union { bf8 v; unsigned u[4]; } tu;                              \
                _Pragma("unroll")                                                \
                for (int p = 0; p < 4; ++p)                                      \
                    tu.u[p] = cvtpk(af[rg][ks * 8 + 2 * p], af[rg][ks * 8 + 2 * p + 1]); \
                fa[rg][ks] = tu.v;                                               \
            }                                                                    \
    }

    STAGE_W(0, 0);
    ISSUE_A(0);
    __syncthreads();       // drains vmcnt: W0 in LDS, af loaded
    CVT_A();

    for (int kt = 0; kt < NKT; ++kt) {
        const int buf = kt & 1;
        if (kt < NKT - 1) { STAGE_W(kt + 1, buf ^ 1); ISSUE_A(kt + 1); }
        __builtin_amdgcn_s_setprio(1);
#pragma unroll
        for (int ks = 0; ks < 2; ++ks) {
            const int kb = ks * 64 + lk * 16;
#pragma unroll
            for (int cg = 0; cg < 4; ++cg) {
                const int c = cb + cg * 16 + lr;
                bf8 b = *(bf8*)(&W_s[buf][c * 128 + (kb ^ ((c & 7) << 4))]);
                acc[0][cg] = __builtin_amdgcn_mfma_f32_16x16x32_bf16(fa[0][ks], b, acc[0][cg], 0, 0, 0);
                acc[1][cg] = __builtin_amdgcn_mfma_f32_16x16x32_bf16(fa[1][ks], b, acc[1][cg], 0, 0, 0);
            }
        }
        __builtin_amdgcn_s_setprio(0);
        __syncthreads();   // readers done with buf; drains prefetch (W kt+1, af kt+1)
        if (kt < NKT - 1) CVT_A();
    }

    // ---- epilogue from fragments: C row = rb+rg*16+lk*4+r, col = cb+cg*16+lr ----
    if (cb == 0) {
        float attv[4], w384[4];
#pragma unroll
        for (int cg = 0; cg < 4; ++cg) {
            attv[cg] = att[cg * 16 + lr];
            w384[cg] = we[(long)(EDGE_F - 1) * HC + cg * 16 + lr];
        }
#pragma unroll
        for (int rg = 0; rg < 2; ++rg)
#pragma unroll
        for (int r = 0; r < 4; ++r) {
            const long e = e0 + rb + rg * 16 + lk * 4 + r;
            const int s = ei[e];
            const int g = ei[N_EDGES + e];
            const float a384 = ea[e * EDGE_F + (EDGE_F - 1)];
            float eev[4];
            float sc0 = 0.f, sc1 = 0.f;
#pragma unroll
            for (int cg = 0; cg < 4; ++cg) {
                const int c = cg * 16 + lr;
                eev[cg] = fmaf(a384, w384[cg], acc[rg][cg][r]);
                float m = eev[cg] + bf2f(xlb[(long)s * HC + c]) + bf2f(xrb[(long)g * HC + c]);
                float lv = m > 0.f ? m : 0.2f * m;
                float tm = lv * attv[cg];
                if (cg < 2) sc0 += tm; else sc1 += tm;
            }
#pragma unroll
            for (int cg = 0; cg < 4; ++cg) {
                float nb = __shfl_xor(eev[cg], 1);
                if (!(lr & 1))
                    *(unsigned*)&eeb[e * HC + cg * 16 + lr] = cvtpk(eev[cg], nb);
            }
            sc0 += __shfl_xor(sc0, 1); sc0 += __shfl_xor(sc0, 2);
            sc0 += __shfl_xor(sc0, 4); sc0 += __shfl_xor(sc0, 8);
            sc1 += __shfl_xor(sc1, 1); sc1 += __shfl_xor(sc1, 2);
            sc1 += __shfl_xor(sc1, 4); sc1 += __shfl_xor(sc1, 8);
            if (lr == 0) exE[e * 2 + 0] = __expf(sc0);   // no segment-max: shift-invariant
            else if (lr == 1) exE[e * 2 + 1] = __expf(sc1);
        }
    } else {
#pragma unroll
        for (int rg = 0; rg < 2; ++rg)
#pragma unroll
        for (int r = 0; r < 4; ++r) {
            const long e = e0 + rb + rg * 16 + lk * 4 + r;
#pragma unroll
            for (int cg = 0; cg < 4; ++cg) {
                float v = acc[rg][cg][r];
                float nb = __shfl_xor(v, 1);
                if (!(lr & 1)) {
                    unsigned pk = cvtpk(v, nb);
                    *(unsigned*)&qW[e * HC + cg * 16 + lr] = pk;
                }
            }
        }
    }
#undef STAGE_W
#undef ISSUE_A
#undef CVT_A
}

// K3: per-node CSR aggregation; chunked register-cached csr lists; bf16 in/out.
__global__ __launch_bounds__(256) void k_node_agg(
    const int* __restrict__ rowptr, const int* __restrict__ csr_e, const int* __restrict__ csr_s,
    const unsigned short* __restrict__ eeb, const float* __restrict__ exE,
    const unsigned short* __restrict__ xlb, const unsigned short* __restrict__ xrb,
    const float* __restrict__ att, const float* __restrict__ convb,
    const float* __restrict__ w1,
    unsigned short* __restrict__ hAb, unsigned short* __restrict__ hBb)
{
    const int lane = threadIdx.x & 63;
    const int n = blockIdx.x * 4 + (threadIdx.x >> 6);
    if (n >= N_NODES) return;
    const int p0 = rowptr[n], p1 = rowptr[n + 1];
    const int h = lane >> 5;

    float eeS = 0.f, s0 = 0.f, s1 = 0.f;
    for (int base = p0; base < p1; base += 64) {
        int m = p1 - base; if (m > 64) m = 64;
        int ew = (lane < m) ? csr_e[base + lane] : 0;
        if (lane < m) {
            float2 ex2 = *(const float2*)&exE[(long)ew * 2];
            s0 += ex2.x; s1 += ex2.y;
        }
        for (int j = 0; j < m; ++j) {
            int e = __shfl(ew, j);
            eeS += bf2f(eeb[(long)e * HC + lane]);
        }
    }
    for (int msk = 1; msk < 64; msk <<= 1) {
        s0 += __shfl_xor(s0, msk);
        s1 += __shfl_xor(s1, msk);
    }
    float sex = h ? s1 : s0;

    int deg = p1 - p0;
    eeS /= (deg > 0 ? (float)deg : 1.f);
    float xlv = bf2f(xlb[(long)n * HC + lane]);
    float v = xlv + bf2f(xrb[(long)n * HC + lane]) + eeS;
    float lv = v > 0.f ? v : 0.2f * v;
    float partial = lv * att[lane];
    partial += __shfl_xor(partial, 1);
    partial += __shfl_xor(partial, 2);
    partial += __shfl_xor(partial, 4);
    partial += __shfl_xor(partial, 8);
    partial += __shfl_xor(partial, 16);    // each 32-lane half holds its head's score
    float exSelf = __expf(partial);
    float inv = 1.f / (sex + exSelf + 1e-16f);
    float aggr = exSelf * inv * xlv;

    for (int base = p0; base < p1; base += 64) {
        int m = p1 - base; if (m > 64) m = 64;
        int ew  = (lane < m) ? csr_e[base + lane] : 0;
        int sw_ = (lane < m) ? csr_s[base + lane] : 0;
        float a0 = 0.f, a1 = 0.f;
        if (lane < m) {
            float2 ex2 = *(const float2*)&exE[(long)ew * 2];
            a0 = ex2.x; a1 = ex2.y;
        }
        for (int j = 0; j < m; ++j) {
            int s = __shfl(sw_, j);
            float t0 = __shfl(a0, j), t1 = __shfl(a1, j);
            float alpha = (h ? t1 : t0) * inv;
            aggr = fmaf(alpha, bf2f(xlb[(long)s * HC + lane]), aggr);
        }
    }

    float hv = fmaxf(aggr + convb[lane], 0.f);
    float accA = 0.f, accB = 0.f;
    for (int k = 0; k < 64; ++k) {
        float hb = __shfl(hv, k);
        accA = fmaf(hb, w1[k * HC + lane], accA);
        accB = fmaf(hb, w1[(64 + k) * HC + lane], accB);
    }
    hAb[(long)n * HC + lane] = f2bf(accA);
    hBb[(long)n * HC + lane] = f2bf(accB);
}

// K6: trust per edge
__global__ __launch_bounds__(256) void k_trust(
    const int* __restrict__ ei,
    const unsigned short* __restrict__ hAb, const unsigned short* __restrict__ hBb,
    const unsigned short* __restrict__ qW, const float* __restrict__ b1,
    const float* __restrict__ w2, const float* __restrict__ b2,
    float* __restrict__ out)
{
    const int lane = threadIdx.x & 63;
    const long e = (long)blockIdx.x * 4 + (threadIdx.x >> 6);
    if (e >= N_EDGES) return;
    int s = ei[e], g = ei[N_EDGES + e];
    float m = bf2f(hAb[(long)s * HC + lane]) + bf2f(hBb[(long)g * HC + lane])
            + bf2f(qW[e * HC + lane]) + b1[lane];
    m = fmaxf(m, 0.f);
    float p0 = m * w2[lane * 3 + 0];
    float p1 = m * w2[lane * 3 + 1];
    float p2 = m * w2[lane * 3 + 2];
    for (int msk = 1; msk < 64; msk <<= 1) {
        p0 += __shfl_xor(p0, msk);
        p1 += __shfl_xor(p1, msk);
        p2 += __shfl_xor(p2, msk);
    }
    if (lane == 0) {
        float l0 = p0 + b2[0], l1 = p1 + b2[1], l2 = p2 + b2[2];
        float mx = fmaxf(l0, fmaxf(l1, l2));
        float e0 = __expf(l0 - mx), e1 = __expf(l1 - mx), e2 = __expf(l2 - mx);
        out[e] = (0.5f * e1 + e2) / (e0 + e1 + e2);
    }
}

extern "C" void kernel_launch(void* const* d_in, const int* in_sizes, int n_in,
                              void* d_out, int out_size, void* d_ws, size_t ws_size,
                              hipStream_t stream)
{
    (void)in_sizes; (void)n_in; (void)out_size; (void)ws_size;
    const float* x     = (const float*)d_in[0];
    const int*   ei    = (const int*)  d_in[1];
    const float* ea    = (const float*)d_in[2];
    const float* wl    = (const float*)d_in[3];
    const float* bl    = (const float*)d_in[4];
    const float* wr    = (const float*)d_in[5];
    const float* br    = (const float*)d_in[6];
    const float* we    = (const float*)d_in[7];
    const float* att   = (const float*)d_in[8];
    const float* convb = (const float*)d_in[9];
    const float* w1    = (const float*)d_in[10];
    const float* b1    = (const float*)d_in[11];
    const float* w2    = (const float*)d_in[12];
    const float* b2    = (const float*)d_in[13];

    float* ws = (float*)d_ws;
    unsigned short* xlb = (unsigned short*)(ws + O_XLB);
    unsigned short* xrb = (unsigned short*)(ws + O_XRB);
    unsigned short* hAb = (unsigned short*)(ws + O_HAB);
    unsigned short* hBb = (unsigned short*)(ws + O_HBB);
    float* exE    = ws + O_EXE;
    unsigned short* wt  = (unsigned short*)(ws + O_WT);
    unsigned short* wt2 = (unsigned short*)(ws + O_WT2);
    int* deg    = (int*)(ws + O_DEG);
    int* cursor = (int*)(ws + O_CURSOR);
    int* rowptr = (int*)(ws + O_ROWPTR);
    int* bsum   = (int*)(ws + O_BSUM);
    int* csr_e  = (int*)(ws + O_CSRE);
    int* csr_s  = (int*)(ws + O_CSRS);
    unsigned short* qW  = (unsigned short*)(ws + O_QW);
    unsigned short* eeb = (unsigned short*)(ws + O_EEB);
    float* out  = (float*)d_out;

    hipMemsetAsync(deg, 0, 100000 * sizeof(int), stream);   // deg + cursor (contiguous)

    k_prep<<<96, 256, 0, stream>>>(we, w1, wt);
    k_prep2<<<96, 256, 0, stream>>>(wl, wr, wt2);
    k_hist<<<3125, 256, 0, stream>>>(ei, deg);
    k_scan_bsum<<<NB, 256, 0, stream>>>(deg, bsum);
    k_scan_boff<<<1, 256, 0, stream>>>(bsum);
    k_scan_row<<<NB, 256, 0, stream>>>(deg, bsum, rowptr);
    k_scatter<<<3125, 256, 0, stream>>>(ei, rowptr, cursor, csr_e, csr_s);
    k_node_lin<<<782, 256, 0, stream>>>(x, wt2, wl, wr, bl, br, xlb, xrb);
    k_edge_main<<<N_EDGES / 64, 256, 0, stream>>>(ea, ei, wt, we, xlb, xrb, att, eeb, exE, qW);
    k_node_agg<<<N_NODES / 4, 256, 0, stream>>>(rowptr, csr_e, csr_s, eeb, exE,
                                                xlb, xrb, att, convb, w1, hAb, hBb);
    k_trust<<<N_EDGES / 4, 256, 0, stream>>>(ei, hAb, hBb, qW, b1, w2, b2, out);
}

// Round 8
// 1009.426 us; speedup vs baseline: 4.6184x; 1.0189x over previous
//
#include <hip/hip_runtime.h>

#define N_NODES 50000
#define N_EDGES 800000
#define NODE_F  388
#define EDGE_F  385
#define HC      64
#define KRED    384   // both GEMMs: 6 K-tiles of 64; k>=384 handled in epilogue
#define NKT     6
#define NB      196   // scan blocks: 196*256 >= 50000

// ---- workspace layout (float offsets) ----  [start, end) in floats
#define O_XLB     0L          // N*64 bf16 = 1.6M f    [0,          1,600,000)
#define O_XRB     1600000L    //                       [1.6M,       3,200,000)
#define O_HAB     3200000L    //                       [3.2M,       4,800,000)
#define O_HBB     4800000L    //                       [4.8M,       6,400,000)
#define O_EXE     6400000L    // E*2 f32               [6.4M,       8,000,000)
#define O_WT      8000000L    // 128*384 bf16=24576f   [8.0M,       8,024,576)
#define O_WT2     8030000L    // 128*384 bf16=24576f   [8.03M,      8,054,576)
#define O_DEG     8060000L    // N int                 [8.06M,      8,110,000)
#define O_CURSOR  8110000L    // N int (contig w/ DEG) [8.11M,      8,160,000)
#define O_ROWPTR  8160000L    // N+1 int               [8.16M,      8,210,001)
#define O_BSUM    8211000L    // NB int                [8.211M,     8,211,196)
#define O_CSRE    8220000L    // E int                 [8.22M,      9,020,000)
#define O_CSRS    9020000L    // E int                 [9.02M,      9,820,000)
#define O_QW      9820000L    // E*64 bf16 = 25.6M f   [9.82M,     35,420,000)
#define O_EEB     35420000L   // E*64 bf16 = 25.6M f   [35.42M,    61,020,000) = 244 MB

typedef __attribute__((ext_vector_type(8))) short bf8;   // 8 bf16 (4 VGPRs)
typedef __attribute__((ext_vector_type(4))) float f4;

typedef __attribute__((address_space(1))) const unsigned char ga_u8;
typedef __attribute__((address_space(3))) unsigned char lds_u8;

static __device__ __forceinline__ void gload_lds16(const void* g, void* l) {
    __builtin_amdgcn_global_load_lds((ga_u8*)g, (lds_u8*)l, 16, 0, 0);
}

static __device__ __forceinline__ unsigned short f2bf(float f) {
    unsigned u = __float_as_uint(f);
    u += 0x7FFFu + ((u >> 16) & 1u);   // RNE
    return (unsigned short)(u >> 16);
}
static __device__ __forceinline__ float bf2f(unsigned short h) {
    return __uint_as_float(((unsigned)h) << 16);
}
static __device__ __forceinline__ unsigned cvtpk(float lo, float hi) {
    unsigned r;
    asm("v_cvt_pk_bf16_f32 %0, %1, %2" : "=v"(r) : "v"(lo), "v"(hi));
    return r;
}
// raw workgroup barrier, no vmcnt drain; sched_barrier pins instruction order
static __device__ __forceinline__ void raw_barrier() {
    __builtin_amdgcn_sched_barrier(0);
    __builtin_amdgcn_s_barrier();
    __builtin_amdgcn_sched_barrier(0);
}

// K0a: edge weights wt[c][k] bf16, c0..63=lin_e_w, c64..127=mlp1_w[128+k], k<384
__global__ __launch_bounds__(256) void k_prep(
    const float* __restrict__ we, const float* __restrict__ w1,
    unsigned short* __restrict__ wt)
{
    int gid = blockIdx.x * 256 + threadIdx.x;     // 24576 = 128 * 192
    int c  = gid / 192;
    int k  = 2 * (gid - c * 192);
    float f0, f1;
    if (c < HC) {
        f0 = we[(long)k * HC + c];
        f1 = we[(long)(k + 1) * HC + c];
    } else {
        f0 = w1[(long)(128 + k) * HC + (c - HC)];
        f1 = w1[(long)(128 + k + 1) * HC + (c - HC)];
    }
    *(unsigned*)(wt + (long)c * KRED + k) =
        (unsigned)f2bf(f0) | ((unsigned)f2bf(f1) << 16);
}

// K0b: node weights wt2[c][k] bf16, c0..63=lin_l_w col c, c64..127=lin_r_w col c-64, k<384
__global__ __launch_bounds__(256) void k_prep2(
    const float* __restrict__ wl, const float* __restrict__ wr,
    unsigned short* __restrict__ wt2)
{
    int gid = blockIdx.x * 256 + threadIdx.x;     // 24576 = 128 * 192
    int c  = gid / 192;
    int k  = 2 * (gid - c * 192);
    const float* w = (c < HC) ? wl : wr;
    int cc = (c < HC) ? c : c - HC;
    float f0 = w[(long)k * HC + cc];
    float f1 = w[(long)(k + 1) * HC + cc];
    *(unsigned*)(wt2 + (long)c * KRED + k) =
        (unsigned)f2bf(f0) | ((unsigned)f2bf(f1) << 16);
}

// K1: [xl|xr] = x @ [wl|wr] + bias via MFMA; A direct-to-reg f32->bf16,
// k=384..387 rank-4 in epilogue; bf16 output.  Counted-wait pipeline (no vmcnt(0) drain).
__global__ __launch_bounds__(256, 5) void k_node_lin(
    const float* __restrict__ x, const unsigned short* __restrict__ wt2,
    const float* __restrict__ wl, const float* __restrict__ wr,
    const float* __restrict__ bl, const float* __restrict__ br,
    unsigned short* __restrict__ xlb, unsigned short* __restrict__ xrb)
{
    __shared__ __align__(16) char W_s[2][16384];
    const int t = threadIdx.x;
    const int l = t & 63;
    const int w = t >> 6;
    const int n0 = blockIdx.x * 64;
    const int rb = (w & 1) * 32;
    const int cb = (w >> 1) * 64;
    const int lr = l & 15;
    const int lk = l >> 4;

    int wsrc[4];
#pragma unroll
    for (int i = 0; i < 4; ++i) {
        int c = w * 32 + i * 8 + (l >> 3);
        wsrc[i] = c * (KRED * 2) + ((((l & 7) * 16)) ^ ((l >> 3) << 4));
    }
    const char* wtb = (const char*)wt2;

    long rowx[2];
#pragma unroll
    for (int rg = 0; rg < 2; ++rg) {
        int n = n0 + rb + rg * 16 + lr;
        if (n >= N_NODES) n = N_NODES - 1;        // clamp loads; stores guarded
        rowx[rg] = (long)n * NODE_F;
    }

    float af[2][16];
    bf8 fa[2][2];
    f4 acc[2][4];
#pragma unroll
    for (int rg = 0; rg < 2; ++rg)
#pragma unroll
        for (int cg = 0; cg < 4; ++cg) acc[rg][cg] = (f4)(0.f);

#define STAGE_W(kt, buf)                                                         \
    {                                                                            \
        _Pragma("unroll")                                                        \
        for (int i = 0; i < 4; ++i)                                              \
            gload_lds16(wtb + wsrc[i] + (kt) * 128, &W_s[buf][w * 4096 + i * 1024]); \
    }
#define ISSUE_AX(kt)                                                             \
    {                                                                            \
        _Pragma("unroll")                                                        \
        for (int rg = 0; rg < 2; ++rg) {                                         \
            const float* rp = x + rowx[rg] + (kt) * 64 + lk * 8;                 \
            float4 a0 = *(const float4*)(rp);                                    \
            float4 a1 = *(const float4*)(rp + 4);                                \
            float4 a2 = *(const float4*)(rp + 32);                               \
            float4 a3 = *(const float4*)(rp + 36);                               \
            af[rg][0]=a0.x; af[rg][1]=a0.y; af[rg][2]=a0.z; af[rg][3]=a0.w;      \
            af[rg][4]=a1.x; af[rg][5]=a1.y; af[rg][6]=a1.z; af[rg][7]=a1.w;      \
            af[rg][8]=a2.x; af[rg][9]=a2.y; af[rg][10]=a2.z; af[rg][11]=a2.w;    \
            af[rg][12]=a3.x; af[rg][13]=a3.y; af[rg][14]=a3.z; af[rg][15]=a3.w;  \
        }                                                                        \
    }
#define CVT_A()                                                                  \
    {                                                                            \
        _Pragma("unroll")                                                        \
        for (int rg = 0; rg < 2; ++rg)                                           \
            _Pragma("unroll")                                                    \
            for (int ks = 0; ks < 2; ++ks) {                                     \
                union { bf8 v; unsigned u[4]; } tu;                              \
                _Pragma("unroll")                                                \
                for (int p = 0; p < 4; ++p)                                      \
                    tu.u[p] = cvtpk(af[rg][ks * 8 + 2 * p], af[rg][ks * 8 + 2 * p + 1]); \
                fa[rg][ks] = tu.v;                                               \
            }                                                                    \
    }

    STAGE_W(0, 0);
    ISSUE_AX(0);

    for (int kt = 0; kt < NKT; ++kt) {
        const int buf = kt & 1;
        CVT_A();                              // waits A(kt)+W(kt) (issued last iter)
        if (kt < NKT - 1) { STAGE_W(kt + 1, buf ^ 1); ISSUE_AX(kt + 1); }
        raw_barrier();                        // W(kt) visible to all waves
        __builtin_amdgcn_s_setprio(1);
#pragma unroll
        for (int ks = 0; ks < 2; ++ks) {
            const int kb = ks * 64 + lk * 16;
#pragma unroll
            for (int cg = 0; cg < 4; ++cg) {
                const int c = cb + cg * 16 + lr;
                bf8 b = *(bf8*)(&W_s[buf][c * 128 + (kb ^ ((c & 7) << 4))]);
                acc[0][cg] = __builtin_amdgcn_mfma_f32_16x16x32_bf16(fa[0][ks], b, acc[0][cg], 0, 0, 0);
                acc[1][cg] = __builtin_amdgcn_mfma_f32_16x16x32_bf16(fa[1][ks], b, acc[1][cg], 0, 0, 0);
            }
        }
        __builtin_amdgcn_s_setprio(0);
        raw_barrier();                        // all readers done before buf reuse
    }

    // epilogue: rank-4 tail (k=384..387) + bias + bf16 pack store
    const float* wsf = (cb == 0) ? wl : wr;
    const float* bsf = (cb == 0) ? bl : br;
    unsigned short* dst = (cb == 0) ? xlb : xrb;
    float wtail[4][4], bias[4];
#pragma unroll
    for (int cg = 0; cg < 4; ++cg) {
        int c = cg * 16 + lr;
        bias[cg] = bsf[c];
#pragma unroll
        for (int j = 0; j < 4; ++j)
            wtail[j][cg] = wsf[(long)(KRED + j) * HC + c];
    }
#pragma unroll
    for (int rg = 0; rg < 2; ++rg)
#pragma unroll
    for (int r = 0; r < 4; ++r) {
        const int n = n0 + rb + rg * 16 + lk * 4 + r;
        const int nc = (n < N_NODES) ? n : N_NODES - 1;
        float4 xt = *(const float4*)(x + (long)nc * NODE_F + KRED);
#pragma unroll
        for (int cg = 0; cg < 4; ++cg) {
            float v = acc[rg][cg][r] + bias[cg]
                    + xt.x * wtail[0][cg] + xt.y * wtail[1][cg]
                    + xt.z * wtail[2][cg] + xt.w * wtail[3][cg];
            float nb = __shfl_xor(v, 1);
            if (!(lr & 1) && n < N_NODES)
                *(unsigned*)&dst[(long)n * HC + cg * 16 + lr] = cvtpk(v, nb);
        }
    }
#undef STAGE_W
#undef ISSUE_AX
#undef CVT_A
}

// ---- CSR build ----
__global__ __launch_bounds__(256) void k_hist(const int* __restrict__ ei, int* __restrict__ deg)
{
    int e = blockIdx.x * 256 + threadIdx.x;
    if (e < N_EDGES) atomicAdd(&deg[ei[N_EDGES + e]], 1);
}

__global__ __launch_bounds__(256) void k_scan_bsum(const int* __restrict__ deg, int* __restrict__ bsum)
{
    __shared__ int red[4];
    int i = blockIdx.x * 256 + threadIdx.x;
    int v = (i < N_NODES) ? deg[i] : 0;
    for (int m = 1; m < 64; m <<= 1) v += __shfl_xor(v, m);
    if ((threadIdx.x & 63) == 0) red[threadIdx.x >> 6] = v;
    __syncthreads();
    if (threadIdx.x == 0) bsum[blockIdx.x] = red[0] + red[1] + red[2] + red[3];
}

__global__ __launch_bounds__(256) void k_scan_boff(int* bsum)   // 1 block, parallel
{
    __shared__ int sc[256];
    int t = threadIdx.x;
    int v = (t < NB) ? bsum[t] : 0;
    sc[t] = v; __syncthreads();
    for (int off = 1; off < 256; off <<= 1) {
        int tv = (t >= off) ? sc[t - off] : 0;
        __syncthreads();
        sc[t] += tv;
        __syncthreads();
    }
    if (t < NB) bsum[t] = sc[t] - v;   // exclusive
}

__global__ __launch_bounds__(256) void k_scan_row(const int* __restrict__ deg,
                                                  const int* __restrict__ bsum,
                                                  int* __restrict__ rowptr)
{
    __shared__ int sc[256];
    int t = threadIdx.x;
    int i = blockIdx.x * 256 + t;
    int v = (i < N_NODES) ? deg[i] : 0;
    sc[t] = v; __syncthreads();
    for (int off = 1; off < 256; off <<= 1) {
        int tv = (t >= off) ? sc[t - off] : 0;
        __syncthreads();
        sc[t] += tv;
        __syncthreads();
    }
    if (i < N_NODES) rowptr[i] = bsum[blockIdx.x] + sc[t] - v;   // exclusive
    if (i == N_NODES - 1) rowptr[N_NODES] = N_EDGES;
}

__global__ __launch_bounds__(256) void k_scatter(const int* __restrict__ ei,
                                                 const int* __restrict__ rowptr,
                                                 int* __restrict__ cursor,
                                                 int* __restrict__ csr_e, int* __restrict__ csr_s)
{
    int e = blockIdx.x * 256 + threadIdx.x;
    if (e >= N_EDGES) return;
    int g = ei[N_EDGES + e];
    int pos = rowptr[g] + atomicAdd(&cursor[g], 1);
    csr_e[pos] = e;
    csr_s[pos] = ei[e];
}

// K2: 64-edge x 128-col MFMA tile; A direct-to-reg from ea(f32), W dbuf LDS via
// global_load_lds; counted-wait pipeline; epilogue: eeb/qW bf16 stores + score/exp.
__global__ __launch_bounds__(256, 5) void k_edge_main(
    const float* __restrict__ ea, const int* __restrict__ ei,
    const unsigned short* __restrict__ wt, const float* __restrict__ we,
    const unsigned short* __restrict__ xlb, const unsigned short* __restrict__ xrb,
    const float* __restrict__ att,
    unsigned short* __restrict__ eeb, float* __restrict__ exE,
    unsigned short* __restrict__ qW)
{
    __shared__ __align__(16) char W_s[2][16384];   // [c 0..127][64 k bf16], XOR-swizzled
    const int t = threadIdx.x;
    const int l = t & 63;
    const int w = t >> 6;
    const long e0 = (long)blockIdx.x * 64;
    const int rb = (w & 1) * 32;
    const int cb = (w >> 1) * 64;
    const int lr = l & 15;
    const int lk = l >> 4;

    int wsrc[4];
#pragma unroll
    for (int i = 0; i < 4; ++i) {
        int c = w * 32 + i * 8 + (l >> 3);
        wsrc[i] = c * (KRED * 2) + ((((l & 7) * 16)) ^ ((l >> 3) << 4));
    }
    const char* wtb = (const char*)wt;

    unsigned rowb[2];
#pragma unroll
    for (int rg = 0; rg < 2; ++rg)
        rowb[rg] = (unsigned)((e0 + rb + rg * 16 + lr) * EDGE_F);

    float af[2][16];
    bf8 fa[2][2];
    f4 acc[2][4];
#pragma unroll
    for (int rg = 0; rg < 2; ++rg)
#pragma unroll
        for (int cg = 0; cg < 4; ++cg) acc[rg][cg] = (f4)(0.f);

#define STAGE_W(kt, buf)                                                         \
    {                                                                            \
        _Pragma("unroll")                                                        \
        for (int i = 0; i < 4; ++i)                                              \
            gload_lds16(wtb + wsrc[i] + (kt) * 128, &W_s[buf][w * 4096 + i * 1024]); \
    }

#define ISSUE_A(kt)                                                              \
    {                                                                            \
        _Pragma("unroll")                                                        \
        for (int rg = 0; rg < 2; ++rg) {                                         \
            const float* rp = ea + rowb[rg] + (kt) * 64 + lk * 8;                \
            _Pragma("unroll")                                                    \
            for (int q = 0; q < 16; ++q)                                         \
                af[rg][q] = rp[(q >> 3) * 32 + (q & 7)];                         \
        }                                                                        \
    }

#define CVT_A()                                                                  \
    {                                                                            \
        _Pragma("unroll")                                                        \
        for (int rg = 0; rg < 2; ++rg)                                           \
            _Pragma("unroll")                                                    \
            for (int ks = 0; ks < 2; ++ks) {                                     \
                union { bf8 v; unsigned u[4]; } tu;                              \
                _Pragma("unroll")                                                \
                for (int p = 0; p < 4; ++p)                                      \
                    tu.u[p] = cvtpk(af[rg][ks * 8 + 2 * p], af[rg][ks * 8 + 2 * p + 1]); \
                fa[rg][ks] = tu.v;                                               \
            }                                                                    \
    }

    STAGE_W(0, 0);
    ISSUE_A(0);

    for (int kt = 0; kt < NKT; ++kt) {
        const int buf = kt & 1;
        CVT_A();                              // waits A(kt)+W(kt) (issued last iter)
        if (kt < NKT - 1) { STAGE_W(kt + 1, buf ^ 1); ISSUE_A(kt + 1); }
        raw_barrier();                        // W(kt) visible to all waves
        __builtin_amdgcn_s_setprio(1);
#pragma unroll
        for (int ks = 0; ks < 2; ++ks) {
            const int kb = ks * 64 + lk * 16;
#pragma unroll
            for (int cg = 0; cg < 4; ++cg) {
                const int c = cb + cg * 16 + lr;
                bf8 b = *(bf8*)(&W_s[buf][c * 128 + (kb ^ ((c & 7) << 4))]);
                acc[0][cg] = __builtin_amdgcn_mfma_f32_16x16x32_bf16(fa[0][ks], b, acc[0][cg], 0, 0, 0);
                acc[1][cg] = __builtin_amdgcn_mfma_f32_16x16x32_bf16(fa[1][ks], b, acc[1][cg], 0, 0, 0);
            }
        }
        __builtin_amdgcn_s_setprio(0);
        raw_barrier();                        // all readers done before buf reuse
    }

    // ---- epilogue from fragments: C row = rb+rg*16+lk*4+r, col = cb+cg*16+lr ----
    if (cb == 0) {
        float attv[4], w384[4];
#pragma unroll
        for (int cg = 0; cg < 4; ++cg) {
            attv[cg] = att[cg * 16 + lr];
            w384[cg] = we[(long)(EDGE_F - 1) * HC + cg * 16 + lr];
        }
#pragma unroll
        for (int rg = 0; rg < 2; ++rg)
#pragma unroll
        for (int r = 0; r < 4; ++r) {
            const long e = e0 + rb + rg * 16 + lk * 4 + r;
            const int s = ei[e];
            const int g = ei[N_EDGES + e];
            const float a384 = ea[e * EDGE_F + (EDGE_F - 1)];
            float eev[4];
            float sc0 = 0.f, sc1 = 0.f;
#pragma unroll
            for (int cg = 0; cg < 4; ++cg) {
                const int c = cg * 16 + lr;
                eev[cg] = fmaf(a384, w384[cg], acc[rg][cg][r]);
                float m = eev[cg] + bf2f(xlb[(long)s * HC + c]) + bf2f(xrb[(long)g * HC + c]);
                float lv = m > 0.f ? m : 0.2f * m;
                float tm = lv * attv[cg];
                if (cg < 2) sc0 += tm; else sc1 += tm;
            }
#pragma unroll
            for (int cg = 0; cg < 4; ++cg) {
                float nb = __shfl_xor(eev[cg], 1);
                if (!(lr & 1))
                    *(unsigned*)&eeb[e * HC + cg * 16 + lr] = cvtpk(eev[cg], nb);
            }
            sc0 += __shfl_xor(sc0, 1); sc0 += __shfl_xor(sc0, 2);
            sc0 += __shfl_xor(sc0, 4); sc0 += __shfl_xor(sc0, 8);
            sc1 += __shfl_xor(sc1, 1); sc1 += __shfl_xor(sc1, 2);
            sc1 += __shfl_xor(sc1, 4); sc1 += __shfl_xor(sc1, 8);
            if (lr == 0) exE[e * 2 + 0] = __expf(sc0);   // no segment-max: shift-invariant
            else if (lr == 1) exE[e * 2 + 1] = __expf(sc1);
        }
    } else {
#pragma unroll
        for (int rg = 0; rg < 2; ++rg)
#pragma unroll
        for (int r = 0; r < 4; ++r) {
            const long e = e0 + rb + rg * 16 + lk * 4 + r;
#pragma unroll
            for (int cg = 0; cg < 4; ++cg) {
                float v = acc[rg][cg][r];
                float nb = __shfl_xor(v, 1);
                if (!(lr & 1)) {
                    unsigned pk = cvtpk(v, nb);
                    *(unsigned*)&qW[e * HC + cg * 16 + lr] = pk;
                }
            }
        }
    }
#undef STAGE_W
#undef ISSUE_A
#undef CVT_A
}

// K3: per-node CSR aggregation; chunked register-cached csr lists; bf16 in/out.
__global__ __launch_bounds__(256) void k_node_agg(
    const int* __restrict__ rowptr, const int* __restrict__ csr_e, const int* __restrict__ csr_s,
    const unsigned short* __restrict__ eeb, const float* __restrict__ exE,
    const unsigned short* __restrict__ xlb, const unsigned short* __restrict__ xrb,
    const float* __restrict__ att, const float* __restrict__ convb,
    const float* __restrict__ w1,
    unsigned short* __restrict__ hAb, unsigned short* __restrict__ hBb)
{
    const int lane = threadIdx.x & 63;
    const int n = blockIdx.x * 4 + (threadIdx.x >> 6);
    if (n >= N_NODES) return;
    const int p0 = rowptr[n], p1 = rowptr[n + 1];
    const int h = lane >> 5;

    float eeS = 0.f, s0 = 0.f, s1 = 0.f;
    for (int base = p0; base < p1; base += 64) {
        int m = p1 - base; if (m > 64) m = 64;
        int ew = (lane < m) ? csr_e[base + lane] : 0;
        if (lane < m) {
            float2 ex2 = *(const float2*)&exE[(long)ew * 2];
            s0 += ex2.x; s1 += ex2.y;
        }
        for (int j = 0; j < m; ++j) {
            int e = __shfl(ew, j);
            eeS += bf2f(eeb[(long)e * HC + lane]);
        }
    }
    for (int msk = 1; msk < 64; msk <<= 1) {
        s0 += __shfl_xor(s0, msk);
        s1 += __shfl_xor(s1, msk);
    }
    float sex = h ? s1 : s0;

    int deg = p1 - p0;
    eeS /= (deg > 0 ? (float)deg : 1.f);
    float xlv = bf2f(xlb[(long)n * HC + lane]);
    float v = xlv + bf2f(xrb[(long)n * HC + lane]) + eeS;
    float lv = v > 0.f ? v : 0.2f * v;
    float partial = lv * att[lane];
    partial += __shfl_xor(partial, 1);
    partial += __shfl_xor(partial, 2);
    partial += __shfl_xor(partial, 4);
    partial += __shfl_xor(partial, 8);
    partial += __shfl_xor(partial, 16);    // each 32-lane half holds its head's score
    float exSelf = __expf(partial);
    float inv = 1.f / (sex + exSelf + 1e-16f);
    float aggr = exSelf * inv * xlv;

    for (int base = p0; base < p1; base += 64) {
        int m = p1 - base; if (m > 64) m = 64;
        int ew  = (lane < m) ? csr_e[base + lane] : 0;
        int sw_ = (lane < m) ? csr_s[base + lane] : 0;
        float a0 = 0.f, a1 = 0.f;
        if (lane < m) {
            float2 ex2 = *(const float2*)&exE[(long)ew * 2];
            a0 = ex2.x; a1 = ex2.y;
        }
        for (int j = 0; j < m; ++j) {
            int s = __shfl(sw_, j);
            float t0 = __shfl(a0, j), t1 = __shfl(a1, j);
            float alpha = (h ? t1 : t0) * inv;
            aggr = fmaf(alpha, bf2f(xlb[(long)s * HC + lane]), aggr);
        }
    }

    float hv = fmaxf(aggr + convb[lane], 0.f);
    float accA = 0.f, accB = 0.f;
    for (int k = 0; k < 64; ++k) {
        float hb = __shfl(hv, k);
        accA = fmaf(hb, w1[k * HC + lane], accA);
        accB = fmaf(hb, w1[(64 + k) * HC + lane], accB);
    }
    hAb[(long)n * HC + lane] = f2bf(accA);
    hBb[(long)n * HC + lane] = f2bf(accB);
}

// K6: trust per edge
__global__ __launch_bounds__(256) void k_trust(
    const int* __restrict__ ei,
    const unsigned short* __restrict__ hAb, const unsigned short* __restrict__ hBb,
    const unsigned short* __restrict__ qW, const float* __restrict__ b1,
    const float* __restrict__ w2, const float* __restrict__ b2,
    float* __restrict__ out)
{
    const int lane = threadIdx.x & 63;
    const long e = (long)blockIdx.x * 4 + (threadIdx.x >> 6);
    if (e >= N_EDGES) return;
    int s = ei[e], g = ei[N_EDGES + e];
    float m = bf2f(hAb[(long)s * HC + lane]) + bf2f(hBb[(long)g * HC + lane])
            + bf2f(qW[e * HC + lane]) + b1[lane];
    m = fmaxf(m, 0.f);
    float p0 = m * w2[lane * 3 + 0];
    float p1 = m * w2[lane * 3 + 1];
    float p2 = m * w2[lane * 3 + 2];
    for (int msk = 1; msk < 64; msk <<= 1) {
        p0 += __shfl_xor(p0, msk);
        p1 += __shfl_xor(p1, msk);
        p2 += __shfl_xor(p2, msk);
    }
    if (lane == 0) {
        float l0 = p0 + b2[0], l1 = p1 + b2[1], l2 = p2 + b2[2];
        float mx = fmaxf(l0, fmaxf(l1, l2));
        float e0 = __expf(l0 - mx), e1 = __expf(l1 - mx), e2 = __expf(l2 - mx);
        out[e] = (0.5f * e1 + e2) / (e0 + e1 + e2);
    }
}

extern "C" void kernel_launch(void* const* d_in, const int* in_sizes, int n_in,
                              void* d_out, int out_size, void* d_ws, size_t ws_size,
                              hipStream_t stream)
{
    (void)in_sizes; (void)n_in; (void)out_size; (void)ws_size;
    const float* x     = (const float*)d_in[0];
    const int*   ei    = (const int*)  d_in[1];
    const float* ea    = (const float*)d_in[2];
    const float* wl    = (const float*)d_in[3];
    const float* bl    = (const float*)d_in[4];
    const float* wr    = (const float*)d_in[5];
    const float* br    = (const float*)d_in[6];
    const float* we    = (const float*)d_in[7];
    const float* att   = (const float*)d_in[8];
    const float* convb = (const float*)d_in[9];
    const float* w1    = (const float*)d_in[10];
    const float* b1    = (const float*)d_in[11];
    const float* w2    = (const float*)d_in[12];
    const float* b2    = (const float*)d_in[13];

    float* ws = (float*)d_ws;
    unsigned short* xlb = (unsigned short*)(ws + O_XLB);
    unsigned short* xrb = (unsigned short*)(ws + O_XRB);
    unsigned short* hAb = (unsigned short*)(ws + O_HAB);
    unsigned short* hBb = (unsigned short*)(ws + O_HBB);
    float* exE    = ws + O_EXE;
    unsigned short* wt  = (unsigned short*)(ws + O_WT);
    unsigned short* wt2 = (unsigned short*)(ws + O_WT2);
    int* deg    = (int*)(ws + O_DEG);
    int* cursor = (int*)(ws + O_CURSOR);
    int* rowptr = (int*)(ws + O_ROWPTR);
    int* bsum   = (int*)(ws + O_BSUM);
    int* csr_e  = (int*)(ws + O_CSRE);
    int* csr_s  = (int*)(ws + O_CSRS);
    unsigned short* qW  = (unsigned short*)(ws + O_QW);
    unsigned short* eeb = (unsigned short*)(ws + O_EEB);
    float* out  = (float*)d_out;

    hipMemsetAsync(deg, 0, 100000 * sizeof(int), stream);   // deg + cursor (contiguous)

    k_prep<<<96, 256, 0, stream>>>(we, w1, wt);
    k_prep2<<<96, 256, 0, stream>>>(wl, wr, wt2);
    k_hist<<<3125, 256, 0, stream>>>(ei, deg);
    k_scan_bsum<<<NB, 256, 0, stream>>>(deg, bsum);
    k_scan_boff<<<1, 256, 0, stream>>>(bsum);
    k_scan_row<<<NB, 256, 0, stream>>>(deg, bsum, rowptr);
    k_scatter<<<3125, 256, 0, stream>>>(ei, rowptr, cursor, csr_e, csr_s);
    k_node_lin<<<782, 256, 0, stream>>>(x, wt2, wl, wr, bl, br, xlb, xrb);
    k_edge_main<<<N_EDGES / 64, 256, 0, stream>>>(ea, ei, wt, we, xlb, xrb, att, eeb, exE, qW);
    k_node_agg<<<N_NODES / 4, 256, 0, stream>>>(rowptr, csr_e, csr_s, eeb, exE,
                                                xlb, xrb, att, convb, w1, hAb, hBb);
    k_trust<<<N_EDGES / 4, 256, 0, stream>>>(ei, hAb, hBb, qW, b1, w2, b2, out);
}

// Round 9
// 1005.300 us; speedup vs baseline: 4.6374x; 1.0041x over previous
//
#include <hip/hip_runtime.h>

#define N_NODES 50000
#define N_EDGES 800000
#define NODE_F  388
#define EDGE_F  385
#define HC      64
#define KRED    384   // both GEMMs: 6 K-tiles of 64; k>=384 handled in epilogue
#define NKT     6
#define NB      196   // scan blocks: 196*256 >= 50000

// ---- workspace layout (float offsets) ----  [start, end) in floats
#define O_XLB     0L          // N*64 bf16 = 1.6M f    [0,          1,600,000)
#define O_XRB     1600000L    //                       [1.6M,       3,200,000)
#define O_HAB     3200000L    //                       [3.2M,       4,800,000)
#define O_HBB     4800000L    //                       [4.8M,       6,400,000)
#define O_EXE     6400000L    // E*2 f32 (p-indexed)   [6.4M,       8,000,000)
#define O_WT      8000000L    // 128*384 bf16=24576f   [8.0M,       8,024,576)
#define O_WT2     8030000L    // 128*384 bf16=24576f   [8.03M,      8,054,576)
#define O_DEG     8060000L    // N int                 [8.06M,      8,110,000)
#define O_CURSOR  8110000L    // N int (contig w/ DEG) [8.11M,      8,160,000)
#define O_ROWPTR  8160000L    // N+1 int               [8.16M,      8,210,001)
#define O_BSUM    8211000L    // NB int                [8.211M,     8,211,196)
#define O_CSRE    8220000L    // E int                 [8.22M,      9,020,000)
#define O_CSRS    9020000L    // E int                 [9.02M,      9,820,000)
#define O_CSRT    9820000L    // E int                 [9.82M,     10,620,000)
#define O_QW      10700000L   // E*64 bf16 (p-idx)     [10.7M,     36,300,000)
#define O_EEB     36400000L   // E*64 bf16 (p-idx)     [36.4M,     62,000,000) = 248 MB

typedef __attribute__((ext_vector_type(8))) short bf8;   // 8 bf16 (4 VGPRs)
typedef __attribute__((ext_vector_type(4))) float f4;

typedef __attribute__((address_space(1))) const unsigned char ga_u8;
typedef __attribute__((address_space(3))) unsigned char lds_u8;

static __device__ __forceinline__ void gload_lds16(const void* g, void* l) {
    __builtin_amdgcn_global_load_lds((ga_u8*)g, (lds_u8*)l, 16, 0, 0);
}

static __device__ __forceinline__ unsigned short f2bf(float f) {
    unsigned u = __float_as_uint(f);
    u += 0x7FFFu + ((u >> 16) & 1u);   // RNE
    return (unsigned short)(u >> 16);
}
static __device__ __forceinline__ float bf2f(unsigned short h) {
    return __uint_as_float(((unsigned)h) << 16);
}
static __device__ __forceinline__ unsigned cvtpk(float lo, float hi) {
    unsigned r;
    asm("v_cvt_pk_bf16_f32 %0, %1, %2" : "=v"(r) : "v"(lo), "v"(hi));
    return r;
}
// raw workgroup barrier, no vmcnt drain; sched_barrier pins instruction order
static __device__ __forceinline__ void raw_barrier() {
    __builtin_amdgcn_sched_barrier(0);
    __builtin_amdgcn_s_barrier();
    __builtin_amdgcn_sched_barrier(0);
}

// K0: weights. blocks 0..95: wt (edge: lin_e_w | mlp1_w[128+k]); 96..191: wt2 (lin_l|lin_r)
__global__ __launch_bounds__(256) void k_prep(
    const float* __restrict__ we, const float* __restrict__ w1,
    const float* __restrict__ wl, const float* __restrict__ wr,
    unsigned short* __restrict__ wt, unsigned short* __restrict__ wt2)
{
    int half = blockIdx.x / 96;
    int gid = (blockIdx.x - half * 96) * 256 + threadIdx.x;   // 24576 = 128 * 192
    int c  = gid / 192;
    int k  = 2 * (gid - c * 192);
    float f0, f1;
    if (half == 0) {
        if (c < HC) {
            f0 = we[(long)k * HC + c];
            f1 = we[(long)(k + 1) * HC + c];
        } else {
            f0 = w1[(long)(128 + k) * HC + (c - HC)];
            f1 = w1[(long)(128 + k + 1) * HC + (c - HC)];
        }
        *(unsigned*)(wt + (long)c * KRED + k) =
            (unsigned)f2bf(f0) | ((unsigned)f2bf(f1) << 16);
    } else {
        const float* w = (c < HC) ? wl : wr;
        int cc = (c < HC) ? c : c - HC;
        f0 = w[(long)k * HC + cc];
        f1 = w[(long)(k + 1) * HC + cc];
        *(unsigned*)(wt2 + (long)c * KRED + k) =
            (unsigned)f2bf(f0) | ((unsigned)f2bf(f1) << 16);
    }
}

// K1: [xl|xr] = x @ [wl|wr] + bias via MFMA; A direct-to-reg f32->bf16,
// k=384..387 rank-4 in epilogue; bf16 output.  Counted-wait pipeline.
__global__ __launch_bounds__(256, 5) void k_node_lin(
    const float* __restrict__ x, const unsigned short* __restrict__ wt2,
    const float* __restrict__ wl, const float* __restrict__ wr,
    const float* __restrict__ bl, const float* __restrict__ br,
    unsigned short* __restrict__ xlb, unsigned short* __restrict__ xrb)
{
    __shared__ __align__(16) char W_s[2][16384];
    const int t = threadIdx.x;
    const int l = t & 63;
    const int w = t >> 6;
    const int n0 = blockIdx.x * 64;
    const int rb = (w & 1) * 32;
    const int cb = (w >> 1) * 64;
    const int lr = l & 15;
    const int lk = l >> 4;

    int wsrc[4];
#pragma unroll
    for (int i = 0; i < 4; ++i) {
        int c = w * 32 + i * 8 + (l >> 3);
        wsrc[i] = c * (KRED * 2) + ((((l & 7) * 16)) ^ ((l >> 3) << 4));
    }
    const char* wtb = (const char*)wt2;

    long rowx[2];
#pragma unroll
    for (int rg = 0; rg < 2; ++rg) {
        int n = n0 + rb + rg * 16 + lr;
        if (n >= N_NODES) n = N_NODES - 1;        // clamp loads; stores guarded
        rowx[rg] = (long)n * NODE_F;
    }

    float af[2][16];
    bf8 fa[2][2];
    f4 acc[2][4];
#pragma unroll
    for (int rg = 0; rg < 2; ++rg)
#pragma unroll
        for (int cg = 0; cg < 4; ++cg) acc[rg][cg] = (f4)(0.f);

#define STAGE_W(kt, buf)                                                         \
    {                                                                            \
        _Pragma("unroll")                                                        \
        for (int i = 0; i < 4; ++i)                                              \
            gload_lds16(wtb + wsrc[i] + (kt) * 128, &W_s[buf][w * 4096 + i * 1024]); \
    }
#define ISSUE_AX(kt)                                                             \
    {                                                                            \
        _Pragma("unroll")                                                        \
        for (int rg = 0; rg < 2; ++rg) {                                         \
            const float* rp = x + rowx[rg] + (kt) * 64 + lk * 8;                 \
            float4 a0 = *(const float4*)(rp);                                    \
            float4 a1 = *(const float4*)(rp + 4);                                \
            float4 a2 = *(const float4*)(rp + 32);                               \
            float4 a3 = *(const float4*)(rp + 36);                               \
            af[rg][0]=a0.x; af[rg][1]=a0.y; af[rg][2]=a0.z; af[rg][3]=a0.w;      \
            af[rg][4]=a1.x; af[rg][5]=a1.y; af[rg][6]=a1.z; af[rg][7]=a1.w;      \
            af[rg][8]=a2.x; af[rg][9]=a2.y; af[rg][10]=a2.z; af[rg][11]=a2.w;    \
            af[rg][12]=a3.x; af[rg][13]=a3.y; af[rg][14]=a3.z; af[rg][15]=a3.w;  \
        }                                                                        \
    }
#define CVT_A()                                                                  \
    {                                                                            \
        _Pragma("unroll")                                                        \
        for (int rg = 0; rg < 2; ++rg)                                           \
            _Pragma("unroll")                                                    \
            for (int ks = 0; ks < 2; ++ks) {                                     \
                union { bf8 v; unsigned u[4]; } tu;                              \
                _Pragma("unroll")                                                \
                for (int p = 0; p < 4; ++p)                                      \
                    tu.u[p] = cvtpk(af[rg][ks * 8 + 2 * p], af[rg][ks * 8 + 2 * p + 1]); \
                fa[rg][ks] = tu.v;                                               \
            }                                                                    \
    }

    STAGE_W(0, 0);
    ISSUE_AX(0);

    for (int kt = 0; kt < NKT; ++kt) {
        const int buf = kt & 1;
        CVT_A();                              // waits A(kt)+W(kt) (issued last iter)
        if (kt < NKT - 1) { STAGE_W(kt + 1, buf ^ 1); ISSUE_AX(kt + 1); }
        raw_barrier();                        // W(kt) visible to all waves
        __builtin_amdgcn_s_setprio(1);
#pragma unroll
        for (int ks = 0; ks < 2; ++ks) {
            const int kb = ks * 64 + lk * 16;
#pragma unroll
            for (int cg = 0; cg < 4; ++cg) {
                const int c = cb + cg * 16 + lr;
                bf8 b = *(bf8*)(&W_s[buf][c * 128 + (kb ^ ((c & 7) << 4))]);
                acc[0][cg] = __builtin_amdgcn_mfma_f32_16x16x32_bf16(fa[0][ks], b, acc[0][cg], 0, 0, 0);
                acc[1][cg] = __builtin_amdgcn_mfma_f32_16x16x32_bf16(fa[1][ks], b, acc[1][cg], 0, 0, 0);
            }
        }
        __builtin_amdgcn_s_setprio(0);
        raw_barrier();                        // all readers done before buf reuse
    }

    // epilogue: rank-4 tail (k=384..387) + bias + bf16 pack store
    const float* wsf = (cb == 0) ? wl : wr;
    const float* bsf = (cb == 0) ? bl : br;
    unsigned short* dst = (cb == 0) ? xlb : xrb;
    float wtail[4][4], bias[4];
#pragma unroll
    for (int cg = 0; cg < 4; ++cg) {
        int c = cg * 16 + lr;
        bias[cg] = bsf[c];
#pragma unroll
        for (int j = 0; j < 4; ++j)
            wtail[j][cg] = wsf[(long)(KRED + j) * HC + c];
    }
#pragma unroll
    for (int rg = 0; rg < 2; ++rg)
#pragma unroll
    for (int r = 0; r < 4; ++r) {
        const int n = n0 + rb + rg * 16 + lk * 4 + r;
        const int nc = (n < N_NODES) ? n : N_NODES - 1;
        float4 xt = *(const float4*)(x + (long)nc * NODE_F + KRED);
#pragma unroll
        for (int cg = 0; cg < 4; ++cg) {
            float v = acc[rg][cg][r] + bias[cg]
                    + xt.x * wtail[0][cg] + xt.y * wtail[1][cg]
                    + xt.z * wtail[2][cg] + xt.w * wtail[3][cg];
            float nb = __shfl_xor(v, 1);
            if (!(lr & 1) && n < N_NODES)
                *(unsigned*)&dst[(long)n * HC + cg * 16 + lr] = cvtpk(v, nb);
        }
    }
#undef STAGE_W
#undef ISSUE_AX
#undef CVT_A
}

// ---- CSR build ----
__global__ __launch_bounds__(256) void k_hist(const int* __restrict__ ei, int* __restrict__ deg)
{
    int e = blockIdx.x * 256 + threadIdx.x;
    if (e < N_EDGES) atomicAdd(&deg[ei[N_EDGES + e]], 1);
}

__global__ __launch_bounds__(256) void k_scan_bsum(const int* __restrict__ deg, int* __restrict__ bsum)
{
    __shared__ int red[4];
    int i = blockIdx.x * 256 + threadIdx.x;
    int v = (i < N_NODES) ? deg[i] : 0;
    for (int m = 1; m < 64; m <<= 1) v += __shfl_xor(v, m);
    if ((threadIdx.x & 63) == 0) red[threadIdx.x >> 6] = v;
    __syncthreads();
    if (threadIdx.x == 0) bsum[blockIdx.x] = red[0] + red[1] + red[2] + red[3];
}

__global__ __launch_bounds__(256) void k_scan_boff(int* bsum)   // 1 block, parallel
{
    __shared__ int sc[256];
    int t = threadIdx.x;
    int v = (t < NB) ? bsum[t] : 0;
    sc[t] = v; __syncthreads();
    for (int off = 1; off < 256; off <<= 1) {
        int tv = (t >= off) ? sc[t - off] : 0;
        __syncthreads();
        sc[t] += tv;
        __syncthreads();
    }
    if (t < NB) bsum[t] = sc[t] - v;   // exclusive
}

__global__ __launch_bounds__(256) void k_scan_row(const int* __restrict__ deg,
                                                  const int* __restrict__ bsum,
                                                  int* __restrict__ rowptr)
{
    __shared__ int sc[256];
    int t = threadIdx.x;
    int i = blockIdx.x * 256 + t;
    int v = (i < N_NODES) ? deg[i] : 0;
    sc[t] = v; __syncthreads();
    for (int off = 1; off < 256; off <<= 1) {
        int tv = (t >= off) ? sc[t - off] : 0;
        __syncthreads();
        sc[t] += tv;
        __syncthreads();
    }
    if (i < N_NODES) rowptr[i] = bsum[blockIdx.x] + sc[t] - v;   // exclusive
    if (i == N_NODES - 1) rowptr[N_NODES] = N_EDGES;
}

__global__ __launch_bounds__(256) void k_scatter(const int* __restrict__ ei,
                                                 const int* __restrict__ rowptr,
                                                 int* __restrict__ cursor,
                                                 int* __restrict__ csr_e, int* __restrict__ csr_s,
                                                 int* __restrict__ csr_t)
{
    int e = blockIdx.x * 256 + threadIdx.x;
    if (e >= N_EDGES) return;
    int g = ei[N_EDGES + e];
    int pos = rowptr[g] + atomicAdd(&cursor[g], 1);
    csr_e[pos] = e;
    csr_s[pos] = ei[e];
    csr_t[pos] = g;
}

// K2: 64-edge x 128-col MFMA tile over CSR-PERMUTED edges (block b: p in [64b,64b+64));
// A rows gathered via csr_e; all outputs p-indexed (sequential for k_node_agg).
__global__ __launch_bounds__(256, 5) void k_edge_main(
    const float* __restrict__ ea,
    const int* __restrict__ csr_e, const int* __restrict__ csr_s, const int* __restrict__ csr_t,
    const unsigned short* __restrict__ wt, const float* __restrict__ we,
    const unsigned short* __restrict__ xlb, const unsigned short* __restrict__ xrb,
    const float* __restrict__ att,
    unsigned short* __restrict__ eebP, float* __restrict__ exPE,
    unsigned short* __restrict__ qWP)
{
    __shared__ __align__(16) char W_s[2][16384];   // [c 0..127][64 k bf16], XOR-swizzled
    const int t = threadIdx.x;
    const int l = t & 63;
    const int w = t >> 6;
    const long pb = (long)blockIdx.x * 64;
    const int rb = (w & 1) * 32;
    const int cb = (w >> 1) * 64;
    const int lr = l & 15;
    const int lk = l >> 4;

    int wsrc[4];
#pragma unroll
    for (int i = 0; i < 4; ++i) {
        int c = w * 32 + i * 8 + (l >> 3);
        wsrc[i] = c * (KRED * 2) + ((((l & 7) * 16)) ^ ((l >> 3) << 4));
    }
    const char* wtb = (const char*)wt;

    unsigned rowb[2];
#pragma unroll
    for (int rg = 0; rg < 2; ++rg) {
        int e = csr_e[pb + rb + rg * 16 + lr];
        rowb[rg] = (unsigned)e * EDGE_F;       // e*385 < 2^32
    }

    float af[2][16];
    bf8 fa[2][2];
    f4 acc[2][4];
#pragma unroll
    for (int rg = 0; rg < 2; ++rg)
#pragma unroll
        for (int cg = 0; cg < 4; ++cg) acc[rg][cg] = (f4)(0.f);

#define STAGE_W(kt, buf)                                                         \
    {                                                                            \
        _Pragma("unroll")                                                        \
        for (int i = 0; i < 4; ++i)                                              \
            gload_lds16(wtb + wsrc[i] + (kt) * 128, &W_s[buf][w * 4096 + i * 1024]); \
    }

#define ISSUE_A(kt)                                                              \
    {                                                                            \
        _Pragma("unroll")                                                        \
        for (int rg = 0; rg < 2; ++rg) {                                         \
            const float* rp = ea + rowb[rg] + (kt) * 64 + lk * 8;                \
            _Pragma("unroll")                                                    \
            for (int q = 0; q < 16; ++q)                                         \
                af[rg][q] = rp[(q >> 3) * 32 + (q & 7)];                         \
        }                                                                        \
    }

#define CVT_A()                                                                  \
    {                                                                            \
        _Pragma("unroll")                                                        \
        for (int rg = 0; rg < 2; ++rg)                                           \
            _Pragma("unroll")                                                    \
            for (int ks = 0; ks < 2; ++ks) {                                     \
                union { bf8 v; unsigned u[4]; } tu;                              \
                _Pragma("unroll")                                                \
                for (int p = 0; p < 4; ++p)                                      \
                    tu.u[p] = cvtpk(af[rg][ks * 8 + 2 * p], af[rg][ks * 8 + 2 * p + 1]); \
                fa[rg][ks] = tu.v;                                               \
            }                                                                    \
    }

    STAGE_W(0, 0);
    ISSUE_A(0);

    for (int kt = 0; kt < NKT; ++kt) {
        const int buf = kt & 1;
        CVT_A();                              // waits A(kt)+W(kt) (issued last iter)
        if (kt < NKT - 1) { STAGE_W(kt + 1, buf ^ 1); ISSUE_A(kt + 1); }
        raw_barrier();                        // W(kt) visible to all waves
        __builtin_amdgcn_s_setprio(1);
#pragma unroll
        for (int ks = 0; ks < 2; ++ks) {
            const int kb = ks * 64 + lk * 16;
#pragma unroll
            for (int cg = 0; cg < 4; ++cg) {
                const int c = cb + cg * 16 + lr;
                bf8 b = *(bf8*)(&W_s[buf][c * 128 + (kb ^ ((c & 7) << 4))]);
                acc[0][cg] = __builtin_amdgcn_mfma_f32_16x16x32_bf16(fa[0][ks], b, acc[0][cg], 0, 0, 0);
                acc[1][cg] = __builtin_amdgcn_mfma_f32_16x16x32_bf16(fa[1][ks], b, acc[1][cg], 0, 0, 0);
            }
        }
        __builtin_amdgcn_s_setprio(0);
        raw_barrier();                        // all readers done before buf reuse
    }

    // ---- epilogue from fragments: C row = rb+rg*16+lk*4+r, col = cb+cg*16+lr ----
    if (cb == 0) {
        float attv[4], w384[4];
#pragma unroll
        for (int cg = 0; cg < 4; ++cg) {
            attv[cg] = att[cg * 16 + lr];
            w384[cg] = we[(long)(EDGE_F - 1) * HC + cg * 16 + lr];
        }
#pragma unroll
        for (int rg = 0; rg < 2; ++rg)
#pragma unroll
        for (int r = 0; r < 4; ++r) {
            const long p = pb + rb + rg * 16 + lk * 4 + r;
            const int s = csr_s[p];
            const int g = csr_t[p];
            const float a384 = ea[(long)csr_e[p] * EDGE_F + (EDGE_F - 1)];
            float eev[4];
            float sc0 = 0.f, sc1 = 0.f;
#pragma unroll
            for (int cg = 0; cg < 4; ++cg) {
                const int c = cg * 16 + lr;
                eev[cg] = fmaf(a384, w384[cg], acc[rg][cg][r]);
                float m = eev[cg] + bf2f(xlb[(long)s * HC + c]) + bf2f(xrb[(long)g * HC + c]);
                float lv = m > 0.f ? m : 0.2f * m;
                float tm = lv * attv[cg];
                if (cg < 2) sc0 += tm; else sc1 += tm;
            }
#pragma unroll
            for (int cg = 0; cg < 4; ++cg) {
                float nb = __shfl_xor(eev[cg], 1);
                if (!(lr & 1))
                    *(unsigned*)&eebP[p * HC + cg * 16 + lr] = cvtpk(eev[cg], nb);
            }
            sc0 += __shfl_xor(sc0, 1); sc0 += __shfl_xor(sc0, 2);
            sc0 += __shfl_xor(sc0, 4); sc0 += __shfl_xor(sc0, 8);
            sc1 += __shfl_xor(sc1, 1); sc1 += __shfl_xor(sc1, 2);
            sc1 += __shfl_xor(sc1, 4); sc1 += __shfl_xor(sc1, 8);
            if (lr == 0) exPE[p * 2 + 0] = __expf(sc0);   // no segment-max: shift-invariant
            else if (lr == 1) exPE[p * 2 + 1] = __expf(sc1);
        }
    } else {
#pragma unroll
        for (int rg = 0; rg < 2; ++rg)
#pragma unroll
        for (int r = 0; r < 4; ++r) {
            const long p = pb + rb + rg * 16 + lk * 4 + r;
#pragma unroll
            for (int cg = 0; cg < 4; ++cg) {
                float v = acc[rg][cg][r];
                float nb = __shfl_xor(v, 1);
                if (!(lr & 1)) {
                    unsigned pk = cvtpk(v, nb);
                    *(unsigned*)&qWP[p * HC + cg * 16 + lr] = pk;
                }
            }
        }
    }
#undef STAGE_W
#undef ISSUE_A
#undef CVT_A
}

// K3: per-node CSR aggregation; all per-edge arrays p-indexed -> sequential streams.
__global__ __launch_bounds__(256) void k_node_agg(
    const int* __restrict__ rowptr, const int* __restrict__ csr_s,
    const unsigned short* __restrict__ eebP, const float* __restrict__ exPE,
    const unsigned short* __restrict__ xlb, const unsigned short* __restrict__ xrb,
    const float* __restrict__ att, const float* __restrict__ convb,
    const float* __restrict__ w1,
    unsigned short* __restrict__ hAb, unsigned short* __restrict__ hBb)
{
    const int lane = threadIdx.x & 63;
    const int n = blockIdx.x * 4 + (threadIdx.x >> 6);
    if (n >= N_NODES) return;
    const int p0 = rowptr[n], p1 = rowptr[n + 1];
    const int h = lane >> 5;

    float eeS = 0.f, sex = 0.f;
#pragma unroll 4
    for (int p = p0; p < p1; ++p) {
        eeS += bf2f(eebP[(long)p * HC + lane]);   // sequential 128B rows
        sex += exPE[(long)p * 2 + h];             // broadcast load
    }

    int deg = p1 - p0;
    eeS /= (deg > 0 ? (float)deg : 1.f);
    float xlv = bf2f(xlb[(long)n * HC + lane]);
    float v = xlv + bf2f(xrb[(long)n * HC + lane]) + eeS;
    float lv = v > 0.f ? v : 0.2f * v;
    float partial = lv * att[lane];
    partial += __shfl_xor(partial, 1);
    partial += __shfl_xor(partial, 2);
    partial += __shfl_xor(partial, 4);
    partial += __shfl_xor(partial, 8);
    partial += __shfl_xor(partial, 16);    // each 32-lane half holds its head's score
    float exSelf = __expf(partial);
    float inv = 1.f / (sex + exSelf + 1e-16f);
    float aggr = exSelf * inv * xlv;

#pragma unroll 2
    for (int p = p0; p < p1; ++p) {
        int s = csr_s[p];                         // broadcast load
        float alpha = exPE[(long)p * 2 + h] * inv;
        aggr = fmaf(alpha, bf2f(xlb[(long)s * HC + lane]), aggr);
    }

    float hv = fmaxf(aggr + convb[lane], 0.f);
    float accA = 0.f, accB = 0.f;
    for (int k = 0; k < 64; ++k) {
        float hb = __shfl(hv, k);
        accA = fmaf(hb, w1[k * HC + lane], accA);
        accB = fmaf(hb, w1[(64 + k) * HC + lane], accB);
    }
    hAb[(long)n * HC + lane] = f2bf(accA);
    hBb[(long)n * HC + lane] = f2bf(accB);
}

// K6: trust per edge, p-order (qW coalesced, hBb[g] sorted-local); out scattered via csr_e.
__global__ __launch_bounds__(256) void k_trust(
    const int* __restrict__ csr_e, const int* __restrict__ csr_s, const int* __restrict__ csr_t,
    const unsigned short* __restrict__ hAb, const unsigned short* __restrict__ hBb,
    const unsigned short* __restrict__ qWP, const float* __restrict__ b1,
    const float* __restrict__ w2, const float* __restrict__ b2,
    float* __restrict__ out)
{
    const int lane = threadIdx.x & 63;
    const long p = (long)blockIdx.x * 4 + (threadIdx.x >> 6);
    if (p >= N_EDGES) return;
    int s = csr_s[p], g = csr_t[p];
    float m = bf2f(hAb[(long)s * HC + lane]) + bf2f(hBb[(long)g * HC + lane])
            + bf2f(qWP[p * HC + lane]) + b1[lane];
    m = fmaxf(m, 0.f);
    float p0 = m * w2[lane * 3 + 0];
    float p1 = m * w2[lane * 3 + 1];
    float p2 = m * w2[lane * 3 + 2];
    for (int msk = 1; msk < 64; msk <<= 1) {
        p0 += __shfl_xor(p0, msk);
        p1 += __shfl_xor(p1, msk);
        p2 += __shfl_xor(p2, msk);
    }
    if (lane == 0) {
        float l0 = p0 + b2[0], l1 = p1 + b2[1], l2 = p2 + b2[2];
        float mx = fmaxf(l0, fmaxf(l1, l2));
        float e0 = __expf(l0 - mx), e1 = __expf(l1 - mx), e2 = __expf(l2 - mx);
        out[csr_e[p]] = (0.5f * e1 + e2) / (e0 + e1 + e2);
    }
}

extern "C" void kernel_launch(void* const* d_in, const int* in_sizes, int n_in,
                              void* d_out, int out_size, void* d_ws, size_t ws_size,
                              hipStream_t stream)
{
    (void)in_sizes; (void)n_in; (void)out_size; (void)ws_size;
    const float* x     = (const float*)d_in[0];
    const int*   ei    = (const int*)  d_in[1];
    const float* ea    = (const float*)d_in[2];
    const float* wl    = (const float*)d_in[3];
    const float* bl    = (const float*)d_in[4];
    const float* wr    = (const float*)d_in[5];
    const float* br    = (const float*)d_in[6];
    const float* we    = (const float*)d_in[7];
    const float* att   = (const float*)d_in[8];
    const float* convb = (const float*)d_in[9];
    const float* w1    = (const float*)d_in[10];
    const float* b1    = (const float*)d_in[11];
    const float* w2    = (const float*)d_in[12];
    const float* b2    = (const float*)d_in[13];

    float* ws = (float*)d_ws;
    unsigned short* xlb = (unsigned short*)(ws + O_XLB);
    unsigned short* xrb = (unsigned short*)(ws + O_XRB);
    unsigned short* hAb = (unsigned short*)(ws + O_HAB);
    unsigned short* hBb = (unsigned short*)(ws + O_HBB);
    float* exPE   = ws + O_EXE;
    unsigned short* wt  = (unsigned short*)(ws + O_WT);
    unsigned short* wt2 = (unsigned short*)(ws + O_WT2);
    int* deg    = (int*)(ws + O_DEG);
    int* cursor = (int*)(ws + O_CURSOR);
    int* rowptr = (int*)(ws + O_ROWPTR);
    int* bsum   = (int*)(ws + O_BSUM);
    int* csr_e  = (int*)(ws + O_CSRE);
    int* csr_s  = (int*)(ws + O_CSRS);
    int* csr_t  = (int*)(ws + O_CSRT);
    unsigned short* qWP  = (unsigned short*)(ws + O_QW);
    unsigned short* eebP = (unsigned short*)(ws + O_EEB);
    float* out  = (float*)d_out;

    hipMemsetAsync(deg, 0, 100000 * sizeof(int), stream);   // deg + cursor (contiguous)

    k_prep<<<192, 256, 0, stream>>>(we, w1, wl, wr, wt, wt2);
    k_hist<<<3125, 256, 0, stream>>>(ei, deg);
    k_scan_bsum<<<NB, 256, 0, stream>>>(deg, bsum);
    k_scan_boff<<<1, 256, 0, stream>>>(bsum);
    k_scan_row<<<NB, 256, 0, stream>>>(deg, bsum, rowptr);
    k_scatter<<<3125, 256, 0, stream>>>(ei, rowptr, cursor, csr_e, csr_s, csr_t);
    k_node_lin<<<782, 256, 0, stream>>>(x, wt2, wl, wr, bl, br, xlb, xrb);
    k_edge_main<<<N_EDGES / 64, 256, 0, stream>>>(ea, csr_e, csr_s, csr_t, wt, we,
                                                  xlb, xrb, att, eebP, exPE, qWP);
    k_node_agg<<<N_NODES / 4, 256, 0, stream>>>(rowptr, csr_s, eebP, exPE,
                                                xlb, xrb, att, convb, w1, hAb, hBb);
    k_trust<<<N_EDGES / 4, 256, 0, stream>>>(csr_e, csr_s, csr_t, hAb, hBb, qWP,
                                             b1, w2, b2, out);
}

// Round 10
// 884.339 us; speedup vs baseline: 5.2717x; 1.1368x over previous
//
#include <hip/hip_runtime.h>

#define N_NODES 50000
#define N_EDGES 800000
#define NODE_F  388
#define EDGE_F  385
#define HC      64
#define KRED    384   // both GEMMs: 6 K-tiles of 64; k>=384 handled in epilogue
#define NKT     6
#define NB      196   // scan blocks: 196*256 >= 50000

// ---- workspace layout (float offsets) ----  [start, end) in floats
#define O_XLB     0L          // N*64 bf16 = 1.6M f    [0,          1,600,000)
#define O_XRB     1600000L    //                       [1.6M,       3,200,000)
#define O_HAB     3200000L    //                       [3.2M,       4,800,000)
#define O_HBB     4800000L    //                       [4.8M,       6,400,000)
#define O_EXE     6400000L    // E*2 f32 (p-indexed)   [6.4M,       8,000,000)
#define O_EESUM   8000000L    // N*64 f32 (zeroed)     [8.0M,      11,200,000)
#define O_SSUM    11200000L   // N*2 f32 (zeroed)      [11.2M,     11,300,000)
#define O_DEG     11300000L   // N int (zeroed)        [11.3M,     11,350,000)
#define O_CURSOR  11350000L   // N int (zeroed)        [11.35M,    11,400,000)
#define O_ROWPTR  11410000L   // N+1 int               [11.41M,    11,460,001)
#define O_BSUM    11470000L   // NB int                [11.47M,    11,470,196)
#define O_CSRE    11480000L   // E int                 [11.48M,    12,280,000)
#define O_CSRS    12280000L   // E int                 [12.28M,    13,080,000)
#define O_CSRT    13080000L   // E int                 [13.08M,    13,880,000)
#define O_WT      13900000L   // 128*384 bf16=24576f   [13.9M,     13,924,576)
#define O_WT2     13930000L   // 128*384 bf16=24576f   [13.93M,    13,954,576)
#define O_QW      13960000L   // E*64 bf16 = 25.6M f   [13.96M,    39,560,000) = 158 MB

typedef __attribute__((ext_vector_type(8))) short bf8;   // 8 bf16 (4 VGPRs)
typedef __attribute__((ext_vector_type(4))) float f4;

typedef __attribute__((address_space(1))) const unsigned char ga_u8;
typedef __attribute__((address_space(3))) unsigned char lds_u8;

static __device__ __forceinline__ void gload_lds16(const void* g, void* l) {
    __builtin_amdgcn_global_load_lds((ga_u8*)g, (lds_u8*)l, 16, 0, 0);
}

static __device__ __forceinline__ unsigned short f2bf(float f) {
    unsigned u = __float_as_uint(f);
    u += 0x7FFFu + ((u >> 16) & 1u);   // RNE
    return (unsigned short)(u >> 16);
}
static __device__ __forceinline__ float bf2f(unsigned short h) {
    return __uint_as_float(((unsigned)h) << 16);
}
static __device__ __forceinline__ unsigned cvtpk(float lo, float hi) {
    unsigned r;
    asm("v_cvt_pk_bf16_f32 %0, %1, %2" : "=v"(r) : "v"(lo), "v"(hi));
    return r;
}
// raw workgroup barrier, no vmcnt drain; sched_barrier pins instruction order
static __device__ __forceinline__ void raw_barrier() {
    __builtin_amdgcn_sched_barrier(0);
    __builtin_amdgcn_s_barrier();
    __builtin_amdgcn_sched_barrier(0);
}

// K0: weights. blocks 0..95: wt (edge: lin_e_w | mlp1_w[128+k]); 96..191: wt2 (lin_l|lin_r)
__global__ __launch_bounds__(256) void k_prep(
    const float* __restrict__ we, const float* __restrict__ w1,
    const float* __restrict__ wl, const float* __restrict__ wr,
    unsigned short* __restrict__ wt, unsigned short* __restrict__ wt2)
{
    int half = blockIdx.x / 96;
    int gid = (blockIdx.x - half * 96) * 256 + threadIdx.x;   // 24576 = 128 * 192
    int c  = gid / 192;
    int k  = 2 * (gid - c * 192);
    float f0, f1;
    if (half == 0) {
        if (c < HC) {
            f0 = we[(long)k * HC + c];
            f1 = we[(long)(k + 1) * HC + c];
        } else {
            f0 = w1[(long)(128 + k) * HC + (c - HC)];
            f1 = w1[(long)(128 + k + 1) * HC + (c - HC)];
        }
        *(unsigned*)(wt + (long)c * KRED + k) =
            (unsigned)f2bf(f0) | ((unsigned)f2bf(f1) << 16);
    } else {
        const float* w = (c < HC) ? wl : wr;
        int cc = (c < HC) ? c : c - HC;
        f0 = w[(long)k * HC + cc];
        f1 = w[(long)(k + 1) * HC + cc];
        *(unsigned*)(wt2 + (long)c * KRED + k) =
            (unsigned)f2bf(f0) | ((unsigned)f2bf(f1) << 16);
    }
}

// K1: [xl|xr] = x @ [wl|wr] + bias via MFMA; A direct-to-reg f32->bf16,
// k=384..387 rank-4 in epilogue; bf16 output.  Counted-wait pipeline.
__global__ __launch_bounds__(256, 5) void k_node_lin(
    const float* __restrict__ x, const unsigned short* __restrict__ wt2,
    const float* __restrict__ wl, const float* __restrict__ wr,
    const float* __restrict__ bl, const float* __restrict__ br,
    unsigned short* __restrict__ xlb, unsigned short* __restrict__ xrb)
{
    __shared__ __align__(16) char W_s[2][16384];
    const int t = threadIdx.x;
    const int l = t & 63;
    const int w = t >> 6;
    const int n0 = blockIdx.x * 64;
    const int rb = (w & 1) * 32;
    const int cb = (w >> 1) * 64;
    const int lr = l & 15;
    const int lk = l >> 4;

    int wsrc[4];
#pragma unroll
    for (int i = 0; i < 4; ++i) {
        int c = w * 32 + i * 8 + (l >> 3);
        wsrc[i] = c * (KRED * 2) + ((((l & 7) * 16)) ^ ((l >> 3) << 4));
    }
    const char* wtb = (const char*)wt2;

    long rowx[2];
#pragma unroll
    for (int rg = 0; rg < 2; ++rg) {
        int n = n0 + rb + rg * 16 + lr;
        if (n >= N_NODES) n = N_NODES - 1;        // clamp loads; stores guarded
        rowx[rg] = (long)n * NODE_F;
    }

    float af[2][16];
    bf8 fa[2][2];
    f4 acc[2][4];
#pragma unroll
    for (int rg = 0; rg < 2; ++rg)
#pragma unroll
        for (int cg = 0; cg < 4; ++cg) acc[rg][cg] = (f4)(0.f);

#define STAGE_W(kt, buf)                                                         \
    {                                                                            \
        _Pragma("unroll")                                                        \
        for (int i = 0; i < 4; ++i)                                              \
            gload_lds16(wtb + wsrc[i] + (kt) * 128, &W_s[buf][w * 4096 + i * 1024]); \
    }
#define ISSUE_AX(kt)                                                             \
    {                                                                            \
        _Pragma("unroll")                                                        \
        for (int rg = 0; rg < 2; ++rg) {                                         \
            const float* rp = x + rowx[rg] + (kt) * 64 + lk * 8;                 \
            float4 a0 = *(const float4*)(rp);                                    \
            float4 a1 = *(const float4*)(rp + 4);                                \
            float4 a2 = *(const float4*)(rp + 32);                               \
            float4 a3 = *(const float4*)(rp + 36);                               \
            af[rg][0]=a0.x; af[rg][1]=a0.y; af[rg][2]=a0.z; af[rg][3]=a0.w;      \
            af[rg][4]=a1.x; af[rg][5]=a1.y; af[rg][6]=a1.z; af[rg][7]=a1.w;      \
            af[rg][8]=a2.x; af[rg][9]=a2.y; af[rg][10]=a2.z; af[rg][11]=a2.w;    \
            af[rg][12]=a3.x; af[rg][13]=a3.y; af[rg][14]=a3.z; af[rg][15]=a3.w;  \
        }                                                                        \
    }
#define CVT_A()                                                                  \
    {                                                                            \
        _Pragma("unroll")                                                        \
        for (int rg = 0; rg < 2; ++rg)                                           \
            _Pragma("unroll")                                                    \
            for (int ks = 0; ks < 2; ++ks) {                                     \
                union { bf8 v; unsigned u[4]; } tu;                              \
                _Pragma("unroll")                                                \
                for (int p = 0; p < 4; ++p)                                      \
                    tu.u[p] = cvtpk(af[rg][ks * 8 + 2 * p], af[rg][ks * 8 + 2 * p + 1]); \
                fa[rg][ks] = tu.v;                                               \
            }                                                                    \
    }

    STAGE_W(0, 0);
    ISSUE_AX(0);

    for (int kt = 0; kt < NKT; ++kt) {
        const int buf = kt & 1;
        CVT_A();                              // waits A(kt)+W(kt) (issued last iter)
        if (kt < NKT - 1) { STAGE_W(kt + 1, buf ^ 1); ISSUE_AX(kt + 1); }
        raw_barrier();                        // W(kt) visible to all waves
        __builtin_amdgcn_s_setprio(1);
#pragma unroll
        for (int ks = 0; ks < 2; ++ks) {
            const int kb = ks * 64 + lk * 16;
#pragma unroll
            for (int cg = 0; cg < 4; ++cg) {
                const int c = cb + cg * 16 + lr;
                bf8 b = *(bf8*)(&W_s[buf][c * 128 + (kb ^ ((c & 7) << 4))]);
                acc[0][cg] = __builtin_amdgcn_mfma_f32_16x16x32_bf16(fa[0][ks], b, acc[0][cg], 0, 0, 0);
                acc[1][cg] = __builtin_amdgcn_mfma_f32_16x16x32_bf16(fa[1][ks], b, acc[1][cg], 0, 0, 0);
            }
        }
        __builtin_amdgcn_s_setprio(0);
        raw_barrier();                        // all readers done before buf reuse
    }

    // epilogue: rank-4 tail (k=384..387) + bias + bf16 pack store
    const float* wsf = (cb == 0) ? wl : wr;
    const float* bsf = (cb == 0) ? bl : br;
    unsigned short* dst = (cb == 0) ? xlb : xrb;
    float wtail[4][4], bias[4];
#pragma unroll
    for (int cg = 0; cg < 4; ++cg) {
        int c = cg * 16 + lr;
        bias[cg] = bsf[c];
#pragma unroll
        for (int j = 0; j < 4; ++j)
            wtail[j][cg] = wsf[(long)(KRED + j) * HC + c];
    }
#pragma unroll
    for (int rg = 0; rg < 2; ++rg)
#pragma unroll
    for (int r = 0; r < 4; ++r) {
        const int n = n0 + rb + rg * 16 + lk * 4 + r;
        const int nc = (n < N_NODES) ? n : N_NODES - 1;
        float4 xt = *(const float4*)(x + (long)nc * NODE_F + KRED);
#pragma unroll
        for (int cg = 0; cg < 4; ++cg) {
            float v = acc[rg][cg][r] + bias[cg]
                    + xt.x * wtail[0][cg] + xt.y * wtail[1][cg]
                    + xt.z * wtail[2][cg] + xt.w * wtail[3][cg];
            float nb = __shfl_xor(v, 1);
            if (!(lr & 1) && n < N_NODES)
                *(unsigned*)&dst[(long)n * HC + cg * 16 + lr] = cvtpk(v, nb);
        }
    }
#undef STAGE_W
#undef ISSUE_AX
#undef CVT_A
}

// ---- CSR build ----
__global__ __launch_bounds__(256) void k_hist(const int* __restrict__ ei, int* __restrict__ deg)
{
    int e = blockIdx.x * 256 + threadIdx.x;
    if (e < N_EDGES) atomicAdd(&deg[ei[N_EDGES + e]], 1);
}

__global__ __launch_bounds__(256) void k_scan_bsum(const int* __restrict__ deg, int* __restrict__ bsum)
{
    __shared__ int red[4];
    int i = blockIdx.x * 256 + threadIdx.x;
    int v = (i < N_NODES) ? deg[i] : 0;
    for (int m = 1; m < 64; m <<= 1) v += __shfl_xor(v, m);
    if ((threadIdx.x & 63) == 0) red[threadIdx.x >> 6] = v;
    __syncthreads();
    if (threadIdx.x == 0) bsum[blockIdx.x] = red[0] + red[1] + red[2] + red[3];
}

__global__ __launch_bounds__(256) void k_scan_boff(int* bsum)   // 1 block, parallel
{
    __shared__ int sc[256];
    int t = threadIdx.x;
    int v = (t < NB) ? bsum[t] : 0;
    sc[t] = v; __syncthreads();
    for (int off = 1; off < 256; off <<= 1) {
        int tv = (t >= off) ? sc[t - off] : 0;
        __syncthreads();
        sc[t] += tv;
        __syncthreads();
    }
    if (t < NB) bsum[t] = sc[t] - v;   // exclusive
}

__global__ __launch_bounds__(256) void k_scan_row(const int* __restrict__ deg,
                                                  const int* __restrict__ bsum,
                                                  int* __restrict__ rowptr)
{
    __shared__ int sc[256];
    int t = threadIdx.x;
    int i = blockIdx.x * 256 + t;
    int v = (i < N_NODES) ? deg[i] : 0;
    sc[t] = v; __syncthreads();
    for (int off = 1; off < 256; off <<= 1) {
        int tv = (t >= off) ? sc[t - off] : 0;
        __syncthreads();
        sc[t] += tv;
        __syncthreads();
    }
    if (i < N_NODES) rowptr[i] = bsum[blockIdx.x] + sc[t] - v;   // exclusive
    if (i == N_NODES - 1) rowptr[N_NODES] = N_EDGES;
}

__global__ __launch_bounds__(256) void k_scatter(const int* __restrict__ ei,
                                                 const int* __restrict__ rowptr,
                                                 int* __restrict__ cursor,
                                                 int* __restrict__ csr_e, int* __restrict__ csr_s,
                                                 int* __restrict__ csr_t)
{
    int e = blockIdx.x * 256 + threadIdx.x;
    if (e >= N_EDGES) return;
    int g = ei[N_EDGES + e];
    int pos = rowptr[g] + atomicAdd(&cursor[g], 1);
    csr_e[pos] = e;
    csr_s[pos] = ei[e];
    csr_t[pos] = g;
}

// K2: 64-edge x 128-col MFMA tile over CSR-permuted edges; fused in-LDS segmented
// reduction of ee and ex into eesum/ssum (block's edges span few consecutive nodes).
__global__ __launch_bounds__(256, 5) void k_edge_main(
    const float* __restrict__ ea,
    const int* __restrict__ csr_e, const int* __restrict__ csr_s, const int* __restrict__ csr_t,
    const unsigned short* __restrict__ wt, const float* __restrict__ we,
    const unsigned short* __restrict__ xlb, const unsigned short* __restrict__ xrb,
    const float* __restrict__ att,
    float* __restrict__ eesum, float* __restrict__ ssum,
    float* __restrict__ exPE, unsigned short* __restrict__ qWP)
{
    __shared__ __align__(16) char lds[32768];      // K-loop: 2x16KB W dbuf; epilogue: ee_s etc
    const int t = threadIdx.x;
    const int l = t & 63;
    const int w = t >> 6;
    const long pb = (long)blockIdx.x * 64;
    const int rb = (w & 1) * 32;
    const int cb = (w >> 1) * 64;
    const int lr = l & 15;
    const int lk = l >> 4;

    int wsrc[4];
#pragma unroll
    for (int i = 0; i < 4; ++i) {
        int c = w * 32 + i * 8 + (l >> 3);
        wsrc[i] = c * (KRED * 2) + ((((l & 7) * 16)) ^ ((l >> 3) << 4));
    }
    const char* wtb = (const char*)wt;

    unsigned rowb[2];
#pragma unroll
    for (int rg = 0; rg < 2; ++rg) {
        int e = csr_e[pb + rb + rg * 16 + lr];
        rowb[rg] = (unsigned)e * EDGE_F;       // e*385 < 2^32
    }

    float af[2][16];
    bf8 fa[2][2];
    f4 acc[2][4];
#pragma unroll
    for (int rg = 0; rg < 2; ++rg)
#pragma unroll
        for (int cg = 0; cg < 4; ++cg) acc[rg][cg] = (f4)(0.f);

#define STAGE_W(kt, buf)                                                         \
    {                                                                            \
        _Pragma("unroll")                                                        \
        for (int i = 0; i < 4; ++i)                                              \
            gload_lds16(wtb + wsrc[i] + (kt) * 128,                              \
                        &lds[(buf) * 16384 + w * 4096 + i * 1024]);              \
    }

// ea rows are 4B-aligned only (385 f/row): memcpy-16 lets backend emit dwordx4
// when unaligned access is supported, else falls back to dword loads (safe).
#define ISSUE_A(kt)                                                              \
    {                                                                            \
        _Pragma("unroll")                                                        \
        for (int rg = 0; rg < 2; ++rg) {                                         \
            const float* rp = ea + rowb[rg] + (kt) * 64 + lk * 8;                \
            _Pragma("unroll")                                                    \
            for (int q4 = 0; q4 < 4; ++q4)                                       \
                __builtin_memcpy(&af[rg][q4 * 4],                                \
                                 rp + (q4 >> 1) * 32 + (q4 & 1) * 4, 16);        \
        }                                                                        \
    }

#define CVT_A()                                                                  \
    {                                                                            \
        _Pragma("unroll")                                                        \
        for (int rg = 0; rg < 2; ++rg)                                           \
            _Pragma("unroll")                                                    \
            for (int ks = 0; ks < 2; ++ks) {                                     \
                union { bf8 v; unsigned u[4]; } tu;                              \
                _Pragma("unroll")                                                \
                for (int p = 0; p < 4; ++p)                                      \
                    tu.u[p] = cvtpk(af[rg][ks * 8 + 2 * p], af[rg][ks * 8 + 2 * p + 1]); \
                fa[rg][ks] = tu.v;                                               \
            }                                                                    \
    }

    STAGE_W(0, 0);
    ISSUE_A(0);

    for (int kt = 0; kt < NKT; ++kt) {
        const int buf = kt & 1;
        CVT_A();                              // waits A(kt)+W(kt) (issued last iter)
        if (kt < NKT - 1) { STAGE_W(kt + 1, buf ^ 1); ISSUE_A(kt + 1); }
        raw_barrier();                        // W(kt) visible to all waves
        __builtin_amdgcn_s_setprio(1);
#pragma unroll
        for (int ks = 0; ks < 2; ++ks) {
            const int kb = ks * 64 + lk * 16;
#pragma unroll
            for (int cg = 0; cg < 4; ++cg) {
                const int c = cb + cg * 16 + lr;
                bf8 b = *(bf8*)(&lds[buf * 16384 + c * 128 + (kb ^ ((c & 7) << 4))]);
                acc[0][cg] = __builtin_amdgcn_mfma_f32_16x16x32_bf16(fa[0][ks], b, acc[0][cg], 0, 0, 0);
                acc[1][cg] = __builtin_amdgcn_mfma_f32_16x16x32_bf16(fa[1][ks], b, acc[1][cg], 0, 0, 0);
            }
        }
        __builtin_amdgcn_s_setprio(0);
        raw_barrier();                        // all readers done before buf reuse
    }

    // ---- epilogue: fragments -> LDS; scores; segmented reduce -> eesum/ssum ----
    float (*ee_s)[65] = (float(*)[65])lds;          // 64x65 f32 = 16640 B
    int*   tgt_s      = (int*)(lds + 16640);        // 64 ints
    float (*ex_s)[2]  = (float(*)[2])(lds + 16896); // 64x2 f32

    if (cb == 0) {
        float attv[4], w384[4];
#pragma unroll
        for (int cg = 0; cg < 4; ++cg) {
            attv[cg] = att[cg * 16 + lr];
            w384[cg] = we[(long)(EDGE_F - 1) * HC + cg * 16 + lr];
        }
#pragma unroll
        for (int rg = 0; rg < 2; ++rg)
#pragma unroll
        for (int r = 0; r < 4; ++r) {
            const int row = rb + rg * 16 + lk * 4 + r;
            const long p = pb + row;
            const int s = csr_s[p];
            const int g = csr_t[p];
            const float a384 = ea[(long)csr_e[p] * EDGE_F + (EDGE_F - 1)];
            float sc0 = 0.f, sc1 = 0.f;
#pragma unroll
            for (int cg = 0; cg < 4; ++cg) {
                const int c = cg * 16 + lr;
                float eev = fmaf(a384, w384[cg], acc[rg][cg][r]);
                ee_s[row][c] = eev;
                float m = eev + bf2f(xlb[(long)s * HC + c]) + bf2f(xrb[(long)g * HC + c]);
                float lv = m > 0.f ? m : 0.2f * m;
                float tm = lv * attv[cg];
                if (cg < 2) sc0 += tm; else sc1 += tm;
            }
            sc0 += __shfl_xor(sc0, 1); sc0 += __shfl_xor(sc0, 2);
            sc0 += __shfl_xor(sc0, 4); sc0 += __shfl_xor(sc0, 8);
            sc1 += __shfl_xor(sc1, 1); sc1 += __shfl_xor(sc1, 2);
            sc1 += __shfl_xor(sc1, 4); sc1 += __shfl_xor(sc1, 8);
            if (lr == 0) {
                float ex = __expf(sc0);           // no segment-max: shift-invariant
                exPE[p * 2 + 0] = ex;
                ex_s[row][0] = ex;
                tgt_s[row] = g;
            } else if (lr == 1) {
                float ex = __expf(sc1);
                exPE[p * 2 + 1] = ex;
                ex_s[row][1] = ex;
            }
        }
    } else {
#pragma unroll
        for (int rg = 0; rg < 2; ++rg)
#pragma unroll
        for (int r = 0; r < 4; ++r) {
            const long p = pb + rb + rg * 16 + lk * 4 + r;
#pragma unroll
            for (int cg = 0; cg < 4; ++cg) {
                float v = acc[rg][cg][r];
                float nb = __shfl_xor(v, 1);
                if (!(lr & 1)) {
                    unsigned pk = cvtpk(v, nb);
                    *(unsigned*)&qWP[p * HC + cg * 16 + lr] = pk;
                }
            }
        }
    }
    __syncthreads();

    {   // segmented reduce: thread -> col c, quarter q (rows q*16..q*16+15)
        const int c = t & 63;
        const int q = t >> 6;
        const int r0 = q * 16;
        int   cur = tgt_s[r0];
        float run = ee_s[r0][c];
        for (int r = r0 + 1; r < r0 + 16; ++r) {
            int tg = tgt_s[r];
            if (tg != cur) {
                atomicAdd(&eesum[(long)cur * HC + c], run);
                run = 0.f; cur = tg;
            }
            run += ee_s[r][c];
        }
        atomicAdd(&eesum[(long)cur * HC + c], run);
        if (c < 2) {
            int   cur2 = tgt_s[r0];
            float run2 = ex_s[r0][c];
            for (int r = r0 + 1; r < r0 + 16; ++r) {
                int tg = tgt_s[r];
                if (tg != cur2) {
                    atomicAdd(&ssum[(long)cur2 * 2 + c], run2);
                    run2 = 0.f; cur2 = tg;
                }
                run2 += ex_s[r][c];
            }
            atomicAdd(&ssum[(long)cur2 * 2 + c], run2);
        }
    }
#undef STAGE_W
#undef ISSUE_A
#undef CVT_A
}

// K3: per-node finalize: eesum/ssum precomputed; alpha-weighted gather + W1 matvec.
__global__ __launch_bounds__(256) void k_node_agg(
    const int* __restrict__ rowptr, const int* __restrict__ csr_s,
    const float* __restrict__ eesum, const float* __restrict__ ssum,
    const float* __restrict__ exPE,
    const unsigned short* __restrict__ xlb, const unsigned short* __restrict__ xrb,
    const float* __restrict__ att, const float* __restrict__ convb,
    const float* __restrict__ w1,
    unsigned short* __restrict__ hAb, unsigned short* __restrict__ hBb)
{
    const int lane = threadIdx.x & 63;
    const int n = blockIdx.x * 4 + (threadIdx.x >> 6);
    if (n >= N_NODES) return;
    const int p0 = rowptr[n], p1 = rowptr[n + 1];
    const int h = lane >> 5;
    const int deg = p1 - p0;

    float eeS = eesum[(long)n * HC + lane] / (deg > 0 ? (float)deg : 1.f);
    float sex = ssum[(long)n * 2 + h];

    float xlv = bf2f(xlb[(long)n * HC + lane]);
    float v = xlv + bf2f(xrb[(long)n * HC + lane]) + eeS;
    float lv = v > 0.f ? v : 0.2f * v;
    float partial = lv * att[lane];
    partial += __shfl_xor(partial, 1);
    partial += __shfl_xor(partial, 2);
    partial += __shfl_xor(partial, 4);
    partial += __shfl_xor(partial, 8);
    partial += __shfl_xor(partial, 16);    // each 32-lane half holds its head's score
    float exSelf = __expf(partial);
    float inv = 1.f / (sex + exSelf + 1e-16f);
    float aggr = exSelf * inv * xlv;

#pragma unroll 2
    for (int p = p0; p < p1; ++p) {
        int s = csr_s[p];                         // broadcast load
        float alpha = exPE[(long)p * 2 + h] * inv;
        aggr = fmaf(alpha, bf2f(xlb[(long)s * HC + lane]), aggr);
    }

    float hv = fmaxf(aggr + convb[lane], 0.f);
    float accA = 0.f, accB = 0.f;
    for (int k = 0; k < 64; ++k) {
        float hb = __shfl(hv, k);
        accA = fmaf(hb, w1[k * HC + lane], accA);
        accB = fmaf(hb, w1[(64 + k) * HC + lane], accB);
    }
    hAb[(long)n * HC + lane] = f2bf(accA);
    hBb[(long)n * HC + lane] = f2bf(accB);
}

// K6: trust — ONE LANE PER EDGE (64 edges/wave): row-local bf16 unpack, 192 FMA/lane,
// uniform scalar w2/b1; out scattered via csr_e.
__global__ __launch_bounds__(256) void k_trust(
    const int* __restrict__ csr_e, const int* __restrict__ csr_s, const int* __restrict__ csr_t,
    const unsigned short* __restrict__ hAb, const unsigned short* __restrict__ hBb,
    const unsigned short* __restrict__ qWP, const float* __restrict__ b1,
    const float* __restrict__ w2, const float* __restrict__ b2,
    float* __restrict__ out)
{
    const long p = (long)blockIdx.x * 256 + threadIdx.x;
    const int s = csr_s[p];
    const int g = csr_t[p];
    const uint4* ha = (const uint4*)(hAb + (long)s * HC);
    const uint4* hb = (const uint4*)(hBb + (long)g * HC);
    const uint4* qw = (const uint4*)(qWP + p * HC);
    float a0 = 0.f, a1 = 0.f, a2 = 0.f;
#pragma unroll
    for (int ch = 0; ch < 8; ++ch) {              // 8 x (8 ushorts per array)
        uint4 ua = ha[ch], ub = hb[ch], uq = qw[ch];
        const unsigned* pa = (const unsigned*)&ua;
        const unsigned* pbb = (const unsigned*)&ub;
        const unsigned* pq = (const unsigned*)&uq;
#pragma unroll
        for (int j = 0; j < 4; ++j) {
            const int c = ch * 8 + j * 2;
            unsigned va = pa[j], vb = pbb[j], vq = pq[j];
            float m0 = __uint_as_float(va << 16) + __uint_as_float(vb << 16)
                     + __uint_as_float(vq << 16) + b1[c];
            float m1 = __uint_as_float(va & 0xffff0000u) + __uint_as_float(vb & 0xffff0000u)
                     + __uint_as_float(vq & 0xffff0000u) + b1[c + 1];
            m0 = fmaxf(m0, 0.f);
            m1 = fmaxf(m1, 0.f);
            a0 = fmaf(m0, w2[c * 3 + 0], a0); a0 = fmaf(m1, w2[c * 3 + 3], a0);
            a1 = fmaf(m0, w2[c * 3 + 1], a1); a1 = fmaf(m1, w2[c * 3 + 4], a1);
            a2 = fmaf(m0, w2[c * 3 + 2], a2); a2 = fmaf(m1, w2[c * 3 + 5], a2);
        }
    }
    float l0 = a0 + b2[0], l1 = a1 + b2[1], l2 = a2 + b2[2];
    float mx = fmaxf(l0, fmaxf(l1, l2));
    float e0 = __expf(l0 - mx), e1 = __expf(l1 - mx), e2 = __expf(l2 - mx);
    out[csr_e[p]] = (0.5f * e1 + e2) / (e0 + e1 + e2);
}

extern "C" void kernel_launch(void* const* d_in, const int* in_sizes, int n_in,
                              void* d_out, int out_size, void* d_ws, size_t ws_size,
                              hipStream_t stream)
{
    (void)in_sizes; (void)n_in; (void)out_size; (void)ws_size;
    const float* x     = (const float*)d_in[0];
    const int*   ei    = (const int*)  d_in[1];
    const float* ea    = (const float*)d_in[2];
    const float* wl    = (const float*)d_in[3];
    const float* bl    = (const float*)d_in[4];
    const float* wr    = (const float*)d_in[5];
    const float* br    = (const float*)d_in[6];
    const float* we    = (const float*)d_in[7];
    const float* att   = (const float*)d_in[8];
    const float* convb = (const float*)d_in[9];
    const float* w1    = (const float*)d_in[10];
    const float* b1    = (const float*)d_in[11];
    const float* w2    = (const float*)d_in[12];
    const float* b2    = (const float*)d_in[13];

    float* ws = (float*)d_ws;
    unsigned short* xlb = (unsigned short*)(ws + O_XLB);
    unsigned short* xrb = (unsigned short*)(ws + O_XRB);
    unsigned short* hAb = (unsigned short*)(ws + O_HAB);
    unsigned short* hBb = (unsigned short*)(ws + O_HBB);
    float* exPE   = ws + O_EXE;
    float* eesum  = ws + O_EESUM;
    float* ssum   = ws + O_SSUM;
    unsigned short* wt  = (unsigned short*)(ws + O_WT);
    unsigned short* wt2 = (unsigned short*)(ws + O_WT2);
    int* deg    = (int*)(ws + O_DEG);
    int* cursor = (int*)(ws + O_CURSOR);
    int* rowptr = (int*)(ws + O_ROWPTR);
    int* bsum   = (int*)(ws + O_BSUM);
    int* csr_e  = (int*)(ws + O_CSRE);
    int* csr_s  = (int*)(ws + O_CSRS);
    int* csr_t  = (int*)(ws + O_CSRT);
    unsigned short* qWP = (unsigned short*)(ws + O_QW);
    float* out  = (float*)d_out;

    // zero eesum + ssum + deg + cursor (contiguous: [O_EESUM, O_CURSOR+N))
    hipMemsetAsync(ws + O_EESUM, 0, (size_t)(11400000L - O_EESUM) * sizeof(float), stream);

    k_prep<<<192, 256, 0, stream>>>(we, w1, wl, wr, wt, wt2);
    k_hist<<<3125, 256, 0, stream>>>(ei, deg);
    k_scan_bsum<<<NB, 256, 0, stream>>>(deg, bsum);
    k_scan_boff<<<1, 256, 0, stream>>>(bsum);
    k_scan_row<<<NB, 256, 0, stream>>>(deg, bsum, rowptr);
    k_scatter<<<3125, 256, 0, stream>>>(ei, rowptr, cursor, csr_e, csr_s, csr_t);
    k_node_lin<<<782, 256, 0, stream>>>(x, wt2, wl, wr, bl, br, xlb, xrb);
    k_edge_main<<<N_EDGES / 64, 256, 0, stream>>>(ea, csr_e, csr_s, csr_t, wt, we,
                                                  xlb, xrb, att, eesum, ssum, exPE, qWP);
    k_node_agg<<<N_NODES / 4, 256, 0, stream>>>(rowptr, csr_s, eesum, ssum, exPE,
                                                xlb, xrb, att, convb, w1, hAb, hBb);
    k_trust<<<3125, 256, 0, stream>>>(csr_e, csr_s, csr_t, hAb, hBb, qWP,
                                      b1, w2, b2, out);
}

// Round 11
// 749.523 us; speedup vs baseline: 6.2199x; 1.1799x over previous
//
#include <hip/hip_runtime.h>

#define N_NODES 50000
#define N_EDGES 800000
#define NODE_F  388
#define EDGE_F  385
#define HC      64
#define KRED    384   // both GEMMs: 6 K-tiles of 64; k>=384 handled in epilogue
#define NKT     6
#define NB      196   // scan blocks: 196*256 >= 50000

// ---- workspace layout (float offsets) ----  [start, end) in floats
#define O_XLB     0L          // N*64 bf16 = 1.6M f    [0,          1,600,000)
#define O_XRB     1600000L    //                       [1.6M,       3,200,000)
#define O_HAB     3200000L    //                       [3.2M,       4,800,000)
#define O_HBB     4800000L    //                       [4.8M,       6,400,000)
#define O_EESUM   6400000L    // N*64 f32 (zeroed)     [6.4M,       9,600,000)
#define O_SSUM    9600000L    // N*2 f32 (zeroed)      [9.6M,       9,700,000)
#define O_WSUM    9700000L    // N*64 f32 (zeroed)     [9.7M,      12,900,000)
#define O_DEG     12900000L   // N int (zeroed)        [12.9M,     12,950,000)
#define O_CURSOR  12950000L   // N int (zeroed)        [12.95M,    13,000,000)
#define O_ROWPTR  13010000L   // N+1 int               [13.01M,    13,060,001)
#define O_BSUM    13070000L   // NB int                [13.07M,    13,070,196)
#define O_CSRE    13080000L   // E int                 [13.08M,    13,880,000)
#define O_CSRS    13880000L   // E int                 [13.88M,    14,680,000)
#define O_CSRT    14680000L   // E int                 [14.68M,    15,480,000)
#define O_WT      15500000L   // 128*384 bf16=24576f   [15.5M,     15,524,576)
#define O_WT2     15530000L   // 128*384 bf16=24576f   [15.53M,    15,554,576)
#define O_QW      15560000L   // E*64 bf16 = 25.6M f   [15.56M,    41,160,000) = 165 MB

typedef __attribute__((ext_vector_type(8))) short bf8;   // 8 bf16 (4 VGPRs)
typedef __attribute__((ext_vector_type(4))) float f4;

typedef __attribute__((address_space(1))) const unsigned char ga_u8;
typedef __attribute__((address_space(3))) unsigned char lds_u8;

static __device__ __forceinline__ void gload_lds16(const void* g, void* l) {
    __builtin_amdgcn_global_load_lds((ga_u8*)g, (lds_u8*)l, 16, 0, 0);
}

static __device__ __forceinline__ unsigned short f2bf(float f) {
    unsigned u = __float_as_uint(f);
    u += 0x7FFFu + ((u >> 16) & 1u);   // RNE
    return (unsigned short)(u >> 16);
}
static __device__ __forceinline__ float bf2f(unsigned short h) {
    return __uint_as_float(((unsigned)h) << 16);
}
static __device__ __forceinline__ unsigned cvtpk(float lo, float hi) {
    unsigned r;
    asm("v_cvt_pk_bf16_f32 %0, %1, %2" : "=v"(r) : "v"(lo), "v"(hi));
    return r;
}
// raw workgroup barrier, no vmcnt drain; sched_barrier pins instruction order
static __device__ __forceinline__ void raw_barrier() {
    __builtin_amdgcn_sched_barrier(0);
    __builtin_amdgcn_s_barrier();
    __builtin_amdgcn_sched_barrier(0);
}

// K0: weights. blocks 0..95: wt (edge: lin_e_w | mlp1_w[128+k]); 96..191: wt2 (lin_l|lin_r)
__global__ __launch_bounds__(256) void k_prep(
    const float* __restrict__ we, const float* __restrict__ w1,
    const float* __restrict__ wl, const float* __restrict__ wr,
    unsigned short* __restrict__ wt, unsigned short* __restrict__ wt2)
{
    int half = blockIdx.x / 96;
    int gid = (blockIdx.x - half * 96) * 256 + threadIdx.x;   // 24576 = 128 * 192
    int c  = gid / 192;
    int k  = 2 * (gid - c * 192);
    float f0, f1;
    if (half == 0) {
        if (c < HC) {
            f0 = we[(long)k * HC + c];
            f1 = we[(long)(k + 1) * HC + c];
        } else {
            f0 = w1[(long)(128 + k) * HC + (c - HC)];
            f1 = w1[(long)(128 + k + 1) * HC + (c - HC)];
        }
        *(unsigned*)(wt + (long)c * KRED + k) =
            (unsigned)f2bf(f0) | ((unsigned)f2bf(f1) << 16);
    } else {
        const float* w = (c < HC) ? wl : wr;
        int cc = (c < HC) ? c : c - HC;
        f0 = w[(long)k * HC + cc];
        f1 = w[(long)(k + 1) * HC + cc];
        *(unsigned*)(wt2 + (long)c * KRED + k) =
            (unsigned)f2bf(f0) | ((unsigned)f2bf(f1) << 16);
    }
}

// K1: [xl|xr] = x @ [wl|wr] + bias via MFMA; A direct-to-reg f32->bf16,
// k=384..387 rank-4 in epilogue; bf16 output.  Counted-wait pipeline (depth-1, proven).
__global__ __launch_bounds__(256, 5) void k_node_lin(
    const float* __restrict__ x, const unsigned short* __restrict__ wt2,
    const float* __restrict__ wl, const float* __restrict__ wr,
    const float* __restrict__ bl, const float* __restrict__ br,
    unsigned short* __restrict__ xlb, unsigned short* __restrict__ xrb)
{
    __shared__ __align__(16) char W_s[2][16384];
    const int t = threadIdx.x;
    const int l = t & 63;
    const int w = t >> 6;
    const int n0 = blockIdx.x * 64;
    const int rb = (w & 1) * 32;
    const int cb = (w >> 1) * 64;
    const int lr = l & 15;
    const int lk = l >> 4;

    int wsrc[4];
#pragma unroll
    for (int i = 0; i < 4; ++i) {
        int c = w * 32 + i * 8 + (l >> 3);
        wsrc[i] = c * (KRED * 2) + ((((l & 7) * 16)) ^ ((l >> 3) << 4));
    }
    const char* wtb = (const char*)wt2;

    long rowx[2];
#pragma unroll
    for (int rg = 0; rg < 2; ++rg) {
        int n = n0 + rb + rg * 16 + lr;
        if (n >= N_NODES) n = N_NODES - 1;        // clamp loads; stores guarded
        rowx[rg] = (long)n * NODE_F;
    }

    float af[2][16];
    bf8 fa[2][2];
    f4 acc[2][4];
#pragma unroll
    for (int rg = 0; rg < 2; ++rg)
#pragma unroll
        for (int cg = 0; cg < 4; ++cg) acc[rg][cg] = (f4)(0.f);

#define STAGE_W(kt, buf)                                                         \
    {                                                                            \
        _Pragma("unroll")                                                        \
        for (int i = 0; i < 4; ++i)                                              \
            gload_lds16(wtb + wsrc[i] + (kt) * 128, &W_s[buf][w * 4096 + i * 1024]); \
    }
#define ISSUE_AX(kt)                                                             \
    {                                                                            \
        _Pragma("unroll")                                                        \
        for (int rg = 0; rg < 2; ++rg) {                                         \
            const float* rp = x + rowx[rg] + (kt) * 64 + lk * 8;                 \
            float4 a0 = *(const float4*)(rp);                                    \
            float4 a1 = *(const float4*)(rp + 4);                                \
            float4 a2 = *(const float4*)(rp + 32);                               \
            float4 a3 = *(const float4*)(rp + 36);                               \
            af[rg][0]=a0.x; af[rg][1]=a0.y; af[rg][2]=a0.z; af[rg][3]=a0.w;      \
            af[rg][4]=a1.x; af[rg][5]=a1.y; af[rg][6]=a1.z; af[rg][7]=a1.w;      \
            af[rg][8]=a2.x; af[rg][9]=a2.y; af[rg][10]=a2.z; af[rg][11]=a2.w;    \
            af[rg][12]=a3.x; af[rg][13]=a3.y; af[rg][14]=a3.z; af[rg][15]=a3.w;  \
        }                                                                        \
    }
#define CVT_AX()                                                                 \
    {                                                                            \
        _Pragma("unroll")                                                        \
        for (int rg = 0; rg < 2; ++rg)                                           \
            _Pragma("unroll")                                                    \
            for (int ks = 0; ks < 2; ++ks) {                                     \
                union { bf8 v; unsigned u[4]; } tu;                              \
                _Pragma("unroll")                                                \
                for (int p = 0; p < 4; ++p)                                      \
                    tu.u[p] = cvtpk(af[rg][ks * 8 + 2 * p], af[rg][ks * 8 + 2 * p + 1]); \
                fa[rg][ks] = tu.v;                                               \
            }                                                                    \
    }

    STAGE_W(0, 0);
    ISSUE_AX(0);

    for (int kt = 0; kt < NKT; ++kt) {
        const int buf = kt & 1;
        CVT_AX();                             // waits A(kt)+W(kt) (issued last iter)
        if (kt < NKT - 1) { STAGE_W(kt + 1, buf ^ 1); ISSUE_AX(kt + 1); }
        raw_barrier();                        // W(kt) visible to all waves
        __builtin_amdgcn_s_setprio(1);
#pragma unroll
        for (int ks = 0; ks < 2; ++ks) {
            const int kb = ks * 64 + lk * 16;
#pragma unroll
            for (int cg = 0; cg < 4; ++cg) {
                const int c = cb + cg * 16 + lr;
                bf8 b = *(bf8*)(&W_s[buf][c * 128 + (kb ^ ((c & 7) << 4))]);
                acc[0][cg] = __builtin_amdgcn_mfma_f32_16x16x32_bf16(fa[0][ks], b, acc[0][cg], 0, 0, 0);
                acc[1][cg] = __builtin_amdgcn_mfma_f32_16x16x32_bf16(fa[1][ks], b, acc[1][cg], 0, 0, 0);
            }
        }
        __builtin_amdgcn_s_setprio(0);
        raw_barrier();                        // all readers done before buf reuse
    }

    // epilogue: rank-4 tail (k=384..387) + bias + bf16 pack store
    const float* wsf = (cb == 0) ? wl : wr;
    const float* bsf = (cb == 0) ? bl : br;
    unsigned short* dst = (cb == 0) ? xlb : xrb;
    float wtail[4][4], bias[4];
#pragma unroll
    for (int cg = 0; cg < 4; ++cg) {
        int c = cg * 16 + lr;
        bias[cg] = bsf[c];
#pragma unroll
        for (int j = 0; j < 4; ++j)
            wtail[j][cg] = wsf[(long)(KRED + j) * HC + c];
    }
#pragma unroll
    for (int rg = 0; rg < 2; ++rg)
#pragma unroll
    for (int r = 0; r < 4; ++r) {
        const int n = n0 + rb + rg * 16 + lk * 4 + r;
        const int nc = (n < N_NODES) ? n : N_NODES - 1;
        float4 xt = *(const float4*)(x + (long)nc * NODE_F + KRED);
#pragma unroll
        for (int cg = 0; cg < 4; ++cg) {
            float v = acc[rg][cg][r] + bias[cg]
                    + xt.x * wtail[0][cg] + xt.y * wtail[1][cg]
                    + xt.z * wtail[2][cg] + xt.w * wtail[3][cg];
            float nb = __shfl_xor(v, 1);
            if (!(lr & 1) && n < N_NODES)
                *(unsigned*)&dst[(long)n * HC + cg * 16 + lr] = cvtpk(v, nb);
        }
    }
#undef STAGE_W
#undef ISSUE_AX
#undef CVT_AX
}

// ---- CSR build ----
__global__ __launch_bounds__(256) void k_hist(const int* __restrict__ ei, int* __restrict__ deg)
{
    int e = blockIdx.x * 256 + threadIdx.x;
    if (e < N_EDGES) atomicAdd(&deg[ei[N_EDGES + e]], 1);
}

__global__ __launch_bounds__(256) void k_scan_bsum(const int* __restrict__ deg, int* __restrict__ bsum)
{
    __shared__ int red[4];
    int i = blockIdx.x * 256 + threadIdx.x;
    int v = (i < N_NODES) ? deg[i] : 0;
    for (int m = 1; m < 64; m <<= 1) v += __shfl_xor(v, m);
    if ((threadIdx.x & 63) == 0) red[threadIdx.x >> 6] = v;
    __syncthreads();
    if (threadIdx.x == 0) bsum[blockIdx.x] = red[0] + red[1] + red[2] + red[3];
}

__global__ __launch_bounds__(256) void k_scan_boff(int* bsum)   // 1 block, parallel
{
    __shared__ int sc[256];
    int t = threadIdx.x;
    int v = (t < NB) ? bsum[t] : 0;
    sc[t] = v; __syncthreads();
    for (int off = 1; off < 256; off <<= 1) {
        int tv = (t >= off) ? sc[t - off] : 0;
        __syncthreads();
        sc[t] += tv;
        __syncthreads();
    }
    if (t < NB) bsum[t] = sc[t] - v;   // exclusive
}

__global__ __launch_bounds__(256) void k_scan_row(const int* __restrict__ deg,
                                                  const int* __restrict__ bsum,
                                                  int* __restrict__ rowptr)
{
    __shared__ int sc[256];
    int t = threadIdx.x;
    int i = blockIdx.x * 256 + t;
    int v = (i < N_NODES) ? deg[i] : 0;
    sc[t] = v; __syncthreads();
    for (int off = 1; off < 256; off <<= 1) {
        int tv = (t >= off) ? sc[t - off] : 0;
        __syncthreads();
        sc[t] += tv;
        __syncthreads();
    }
    if (i < N_NODES) rowptr[i] = bsum[blockIdx.x] + sc[t] - v;   // exclusive
    if (i == N_NODES - 1) rowptr[N_NODES] = N_EDGES;
}

__global__ __launch_bounds__(256) void k_scatter(const int* __restrict__ ei,
                                                 const int* __restrict__ rowptr,
                                                 int* __restrict__ cursor,
                                                 int* __restrict__ csr_e, int* __restrict__ csr_s,
                                                 int* __restrict__ csr_t)
{
    int e = blockIdx.x * 256 + threadIdx.x;
    if (e >= N_EDGES) return;
    int g = ei[N_EDGES + e];
    int pos = rowptr[g] + atomicAdd(&cursor[g], 1);
    csr_e[pos] = e;
    csr_s[pos] = ei[e];
    csr_t[pos] = g;
}

// K2: CSR-ordered 64-edge x 128-col MFMA tile; depth-2 A prefetch (af dbuf);
// epilogue: fused segmented reductions -> eesum, ssum, wsum (+qW bf16 store).
__global__ __launch_bounds__(256, 4) void k_edge_main(
    const float* __restrict__ ea,
    const int* __restrict__ csr_e, const int* __restrict__ csr_s, const int* __restrict__ csr_t,
    const unsigned short* __restrict__ wt, const float* __restrict__ we,
    const unsigned short* __restrict__ xlb, const unsigned short* __restrict__ xrb,
    const float* __restrict__ att,
    float* __restrict__ eesum, float* __restrict__ ssum, float* __restrict__ wsum,
    unsigned short* __restrict__ qWP)
{
    __shared__ __align__(16) char lds[32768];      // K-loop: 2x16KB W dbuf; epilogue reuse
    const int t = threadIdx.x;
    const int l = t & 63;
    const int w = t >> 6;
    const long pb = (long)blockIdx.x * 64;
    const int rb = (w & 1) * 32;
    const int cb = (w >> 1) * 64;
    const int lr = l & 15;
    const int lk = l >> 4;

    int wsrc[4];
#pragma unroll
    for (int i = 0; i < 4; ++i) {
        int c = w * 32 + i * 8 + (l >> 3);
        wsrc[i] = c * (KRED * 2) + ((((l & 7) * 16)) ^ ((l >> 3) << 4));
    }
    const char* wtb = (const char*)wt;

    unsigned rowb[2];
#pragma unroll
    for (int rg = 0; rg < 2; ++rg) {
        int e = csr_e[pb + rb + rg * 16 + lr];
        rowb[rg] = (unsigned)e * EDGE_F;       // e*385 < 2^32
    }

    float af[2][2][16];                        // depth-2 A staging (dbuf)
    bf8 fa[2][2];
    f4 acc[2][4];
#pragma unroll
    for (int rg = 0; rg < 2; ++rg)
#pragma unroll
        for (int cg = 0; cg < 4; ++cg) acc[rg][cg] = (f4)(0.f);

#define STAGE_W(kt, buf)                                                         \
    {                                                                            \
        _Pragma("unroll")                                                        \
        for (int i = 0; i < 4; ++i)                                              \
            gload_lds16(wtb + wsrc[i] + (kt) * 128,                              \
                        &lds[(buf) * 16384 + w * 4096 + i * 1024]);              \
    }

// ea rows 4B-aligned only: memcpy-16 lets backend pick widest legal load.
#define ISSUE_A(b, kt)                                                           \
    {                                                                            \
        _Pragma("unroll")                                                        \
        for (int rg = 0; rg < 2; ++rg) {                                         \
            const float* rp = ea + rowb[rg] + (kt) * 64 + lk * 8;                \
            _Pragma("unroll")                                                    \
            for (int q4 = 0; q4 < 4; ++q4)                                       \
                __builtin_memcpy(&af[b][rg][q4 * 4],                             \
                                 rp + (q4 >> 1) * 32 + (q4 & 1) * 4, 16);        \
        }                                                                        \
    }

#define CVT_A(b)                                                                 \
    {                                                                            \
        _Pragma("unroll")                                                        \
        for (int rg = 0; rg < 2; ++rg)                                           \
            _Pragma("unroll")                                                    \
            for (int ks = 0; ks < 2; ++ks) {                                     \
                union { bf8 v; unsigned u[4]; } tu;                              \
                _Pragma("unroll")                                                \
                for (int p = 0; p < 4; ++p)                                      \
                    tu.u[p] = cvtpk(af[b][rg][ks * 8 + 2 * p],                   \
                                    af[b][rg][ks * 8 + 2 * p + 1]);              \
                fa[rg][ks] = tu.v;                                               \
            }                                                                    \
    }

    // prologue: tiles 0 and 1 in flight (A issued AFTER its W -> CVT wait implies W done)
    STAGE_W(0, 0); ISSUE_A(0, 0);
    STAGE_W(1, 1); ISSUE_A(1, 1);

    for (int kt = 0; kt < NKT; ++kt) {
        const int sl = kt & 1;
        CVT_A(sl);                            // waits A(kt) => own W(kt) gloads done
        raw_barrier();                        // every wave past its wait => W(kt) visible
        __builtin_amdgcn_s_setprio(1);
#pragma unroll
        for (int ks = 0; ks < 2; ++ks) {
            const int kb = ks * 64 + lk * 16;
#pragma unroll
            for (int cg = 0; cg < 4; ++cg) {
                const int c = cb + cg * 16 + lr;
                bf8 b = *(bf8*)(&lds[sl * 16384 + c * 128 + (kb ^ ((c & 7) << 4))]);
                acc[0][cg] = __builtin_amdgcn_mfma_f32_16x16x32_bf16(fa[0][ks], b, acc[0][cg], 0, 0, 0);
                acc[1][cg] = __builtin_amdgcn_mfma_f32_16x16x32_bf16(fa[1][ks], b, acc[1][cg], 0, 0, 0);
            }
        }
        __builtin_amdgcn_s_setprio(0);
        raw_barrier();                        // all readers done with W_s[sl]
        if (kt + 2 < NKT) {                   // stage tile kt+2 into freed slot
            STAGE_W(kt + 2, sl);
            ISSUE_A(sl, kt + 2);              // A after W: preserves the wait implication
        }
    }

    // ---- epilogue: fragments -> LDS; scores; two segmented reduces ----
    float (*ee_s)[65] = (float(*)[65])lds;          // 64x65 f32 = 16640 B
    int*   tgt_s      = (int*)(lds + 16640);        // 64 ints
    float (*ex_s)[2]  = (float(*)[2])(lds + 16896); // 64x2 f32

    if (cb == 0) {
        float attv[4], w384[4];
#pragma unroll
        for (int cg = 0; cg < 4; ++cg) {
            attv[cg] = att[cg * 16 + lr];
            w384[cg] = we[(long)(EDGE_F - 1) * HC + cg * 16 + lr];
        }
#pragma unroll
        for (int rg = 0; rg < 2; ++rg)
#pragma unroll
        for (int r = 0; r < 4; ++r) {
            const int row = rb + rg * 16 + lk * 4 + r;
            const long p = pb + row;
            const int s = csr_s[p];
            const int g = csr_t[p];
            const float a384 = ea[(long)csr_e[p] * EDGE_F + (EDGE_F - 1)];
            float sc0 = 0.f, sc1 = 0.f;
#pragma unroll
            for (int cg = 0; cg < 4; ++cg) {
                const int c = cg * 16 + lr;
                float eev = fmaf(a384, w384[cg], acc[rg][cg][r]);
                ee_s[row][c] = eev;
                float m = eev + bf2f(xlb[(long)s * HC + c]) + bf2f(xrb[(long)g * HC + c]);
                float lv = m > 0.f ? m : 0.2f * m;
                float tm = lv * attv[cg];
                if (cg < 2) sc0 += tm; else sc1 += tm;
            }
            sc0 += __shfl_xor(sc0, 1); sc0 += __shfl_xor(sc0, 2);
            sc0 += __shfl_xor(sc0, 4); sc0 += __shfl_xor(sc0, 8);
            sc1 += __shfl_xor(sc1, 1); sc1 += __shfl_xor(sc1, 2);
            sc1 += __shfl_xor(sc1, 4); sc1 += __shfl_xor(sc1, 8);
            if (lr == 0) {
                ex_s[row][0] = __expf(sc0);       // no segment-max: shift-invariant
                tgt_s[row] = g;
            } else if (lr == 1) {
                ex_s[row][1] = __expf(sc1);
            }
        }
    } else {
#pragma unroll
        for (int rg = 0; rg < 2; ++rg)
#pragma unroll
        for (int r = 0; r < 4; ++r) {
            const long p = pb + rb + rg * 16 + lk * 4 + r;
#pragma unroll
            for (int cg = 0; cg < 4; ++cg) {
                float v = acc[rg][cg][r];
                float nb = __shfl_xor(v, 1);
                if (!(lr & 1)) {
                    unsigned pk = cvtpk(v, nb);
                    *(unsigned*)&qWP[p * HC + cg * 16 + lr] = pk;
                }
            }
        }
    }
    __syncthreads();

    {   // reduce1: ee -> eesum, ex -> ssum.  thread -> col c, quarter q (16 rows)
        const int c = t & 63;
        const int q = t >> 6;
        const int r0 = q * 16;
        int   cur = tgt_s[r0];
        float run = ee_s[r0][c];
        for (int r = r0 + 1; r < r0 + 16; ++r) {
            int tg = tgt_s[r];
            if (tg != cur) {
                atomicAdd(&eesum[(long)cur * HC + c], run);
                run = 0.f; cur = tg;
            }
            run += ee_s[r][c];
        }
        atomicAdd(&eesum[(long)cur * HC + c], run);
        if (c < 2) {
            int   cur2 = tgt_s[r0];
            float run2 = ex_s[r0][c];
            for (int r = r0 + 1; r < r0 + 16; ++r) {
                int tg = tgt_s[r];
                if (tg != cur2) {
                    atomicAdd(&ssum[(long)cur2 * 2 + c], run2);
                    run2 = 0.f; cur2 = tg;
                }
                run2 += ex_s[r][c];
            }
            atomicAdd(&ssum[(long)cur2 * 2 + c], run2);
        }
    }
    __syncthreads();

    // pass2: contrib[row][c] = ex_h(row) * xl[s_row][c]  (xlb re-read, L1/L2-hot)
    if (cb == 0) {
#pragma unroll
        for (int rg = 0; rg < 2; ++rg)
#pragma unroll
        for (int r = 0; r < 4; ++r) {
            const int row = rb + rg * 16 + lk * 4 + r;
            const long p = pb + row;
            const int s = csr_s[p];
            const float ex0 = ex_s[row][0];
            const float ex1 = ex_s[row][1];
#pragma unroll
            for (int cg = 0; cg < 4; ++cg) {
                const int c = cg * 16 + lr;
                float xv = bf2f(xlb[(long)s * HC + c]);
                ee_s[row][c] = (cg < 2 ? ex0 : ex1) * xv;
            }
        }
    }
    __syncthreads();

    {   // reduce2: contrib -> wsum
        const int c = t & 63;
        const int q = t >> 6;
        const int r0 = q * 16;
        int   cur = tgt_s[r0];
        float run = ee_s[r0][c];
        for (int r = r0 + 1; r < r0 + 16; ++r) {
            int tg = tgt_s[r];
            if (tg != cur) {
                atomicAdd(&wsum[(long)cur * HC + c], run);
                run = 0.f; cur = tg;
            }
            run += ee_s[r][c];
        }
        atomicAdd(&wsum[(long)cur * HC + c], run);
    }
#undef STAGE_W
#undef ISSUE_A
#undef CVT_A
}

// K3: per-node finalize — pure streaming (eesum/ssum/wsum precomputed), W1 matvec.
__global__ __launch_bounds__(256) void k_node_agg(
    const int* __restrict__ rowptr,
    const float* __restrict__ eesum, const float* __restrict__ ssum,
    const float* __restrict__ wsum,
    const unsigned short* __restrict__ xlb, const unsigned short* __restrict__ xrb,
    const float* __restrict__ att, const float* __restrict__ convb,
    const float* __restrict__ w1,
    unsigned short* __restrict__ hAb, unsigned short* __restrict__ hBb)
{
    const int lane = threadIdx.x & 63;
    const int n = blockIdx.x * 4 + (threadIdx.x >> 6);
    if (n >= N_NODES) return;
    const int h = lane >> 5;
    const int deg = rowptr[n + 1] - rowptr[n];

    float eeS = eesum[(long)n * HC + lane] / (deg > 0 ? (float)deg : 1.f);
    float sex = ssum[(long)n * 2 + h];

    float xlv = bf2f(xlb[(long)n * HC + lane]);
    float v = xlv + bf2f(xrb[(long)n * HC + lane]) + eeS;
    float lv = v > 0.f ? v : 0.2f * v;
    float partial = lv * att[lane];
    partial += __shfl_xor(partial, 1);
    partial += __shfl_xor(partial, 2);
    partial += __shfl_xor(partial, 4);
    partial += __shfl_xor(partial, 8);
    partial += __shfl_xor(partial, 16);    // each 32-lane half holds its head's score
    float exSelf = __expf(partial);
    float inv = 1.f / (sex + exSelf + 1e-16f);
    float aggr = (exSelf * xlv + wsum[(long)n * HC + lane]) * inv;

    float hv = fmaxf(aggr + convb[lane], 0.f);
    float accA = 0.f, accB = 0.f;
    for (int k = 0; k < 64; ++k) {
        float hb = __shfl(hv, k);
        accA = fmaf(hb, w1[k * HC + lane], accA);
        accB = fmaf(hb, w1[(64 + k) * HC + lane], accB);
    }
    hAb[(long)n * HC + lane] = f2bf(accA);
    hBb[(long)n * HC + lane] = f2bf(accB);
}

// K6: trust — one lane per edge (p-order): row-local bf16 unpack, 192 FMA/lane.
__global__ __launch_bounds__(256) void k_trust(
    const int* __restrict__ csr_e, const int* __restrict__ csr_s, const int* __restrict__ csr_t,
    const unsigned short* __restrict__ hAb, const unsigned short* __restrict__ hBb,
    const unsigned short* __restrict__ qWP, const float* __restrict__ b1,
    const float* __restrict__ w2, const float* __restrict__ b2,
    float* __restrict__ out)
{
    const long p = (long)blockIdx.x * 256 + threadIdx.x;
    const int s = csr_s[p];
    const int g = csr_t[p];
    const uint4* ha = (const uint4*)(hAb + (long)s * HC);
    const uint4* hb = (const uint4*)(hBb + (long)g * HC);
    const uint4* qw = (const uint4*)(qWP + p * HC);
    float a0 = 0.f, a1 = 0.f, a2 = 0.f;
#pragma unroll
    for (int ch = 0; ch < 8; ++ch) {              // 8 x (8 ushorts per array)
        uint4 ua = ha[ch], ub = hb[ch], uq = qw[ch];
        const unsigned* pa = (const unsigned*)&ua;
        const unsigned* pbb = (const unsigned*)&ub;
        const unsigned* pq = (const unsigned*)&uq;
#pragma unroll
        for (int j = 0; j < 4; ++j) {
            const int c = ch * 8 + j * 2;
            unsigned va = pa[j], vb = pbb[j], vq = pq[j];
            float m0 = __uint_as_float(va << 16) + __uint_as_float(vb << 16)
                     + __uint_as_float(vq << 16) + b1[c];
            float m1 = __uint_as_float(va & 0xffff0000u) + __uint_as_float(vb & 0xffff0000u)
                     + __uint_as_float(vq & 0xffff0000u) + b1[c + 1];
            m0 = fmaxf(m0, 0.f);
            m1 = fmaxf(m1, 0.f);
            a0 = fmaf(m0, w2[c * 3 + 0], a0); a0 = fmaf(m1, w2[c * 3 + 3], a0);
            a1 = fmaf(m0, w2[c * 3 + 1], a1); a1 = fmaf(m1, w2[c * 3 + 4], a1);
            a2 = fmaf(m0, w2[c * 3 + 2], a2); a2 = fmaf(m1, w2[c * 3 + 5], a2);
        }
    }
    float l0 = a0 + b2[0], l1 = a1 + b2[1], l2 = a2 + b2[2];
    float mx = fmaxf(l0, fmaxf(l1, l2));
    float e0 = __expf(l0 - mx), e1 = __expf(l1 - mx), e2 = __expf(l2 - mx);
    out[csr_e[p]] = (0.5f * e1 + e2) / (e0 + e1 + e2);
}

extern "C" void kernel_launch(void* const* d_in, const int* in_sizes, int n_in,
                              void* d_out, int out_size, void* d_ws, size_t ws_size,
                              hipStream_t stream)
{
    (void)in_sizes; (void)n_in; (void)out_size; (void)ws_size;
    const float* x     = (const float*)d_in[0];
    const int*   ei    = (const int*)  d_in[1];
    const float* ea    = (const float*)d_in[2];
    const float* wl    = (const float*)d_in[3];
    const float* bl    = (const float*)d_in[4];
    const float* wr    = (const float*)d_in[5];
    const float* br    = (const float*)d_in[6];
    const float* we    = (const float*)d_in[7];
    const float* att   = (const float*)d_in[8];
    const float* convb = (const float*)d_in[9];
    const float* w1    = (const float*)d_in[10];
    const float* b1    = (const float*)d_in[11];
    const float* w2    = (const float*)d_in[12];
    const float* b2    = (const float*)d_in[13];

    float* ws = (float*)d_ws;
    unsigned short* xlb = (unsigned short*)(ws + O_XLB);
    unsigned short* xrb = (unsigned short*)(ws + O_XRB);
    unsigned short* hAb = (unsigned short*)(ws + O_HAB);
    unsigned short* hBb = (unsigned short*)(ws + O_HBB);
    float* eesum  = ws + O_EESUM;
    float* ssum   = ws + O_SSUM;
    float* wsum   = ws + O_WSUM;
    unsigned short* wt  = (unsigned short*)(ws + O_WT);
    unsigned short* wt2 = (unsigned short*)(ws + O_WT2);
    int* deg    = (int*)(ws + O_DEG);
    int* cursor = (int*)(ws + O_CURSOR);
    int* rowptr = (int*)(ws + O_ROWPTR);
    int* bsum   = (int*)(ws + O_BSUM);
    int* csr_e  = (int*)(ws + O_CSRE);
    int* csr_s  = (int*)(ws + O_CSRS);
    int* csr_t  = (int*)(ws + O_CSRT);
    unsigned short* qWP = (unsigned short*)(ws + O_QW);
    float* out  = (float*)d_out;

    // zero eesum + ssum + wsum + deg + cursor (contiguous [O_EESUM, 13,000,000))
    hipMemsetAsync(ws + O_EESUM, 0, (size_t)(13000000L - O_EESUM) * sizeof(float), stream);

    k_prep<<<192, 256, 0, stream>>>(we, w1, wl, wr, wt, wt2);
    k_hist<<<3125, 256, 0, stream>>>(ei, deg);
    k_scan_bsum<<<NB, 256, 0, stream>>>(deg, bsum);
    k_scan_boff<<<1, 256, 0, stream>>>(bsum);
    k_scan_row<<<NB, 256, 0, stream>>>(deg, bsum, rowptr);
    k_scatter<<<3125, 256, 0, stream>>>(ei, rowptr, cursor, csr_e, csr_s, csr_t);
    k_node_lin<<<782, 256, 0, stream>>>(x, wt2, wl, wr, bl, br, xlb, xrb);
    k_edge_main<<<N_EDGES / 64, 256, 0, stream>>>(ea, csr_e, csr_s, csr_t, wt, we,
                                                  xlb, xrb, att, eesum, ssum, wsum, qWP);
    k_node_agg<<<N_NODES / 4, 256, 0, stream>>>(rowptr, eesum, ssum, wsum,
                                                xlb, xrb, att, convb, w1, hAb, hBb);
    k_trust<<<3125, 256, 0, stream>>>(csr_e, csr_s, csr_t, hAb, hBb, qWP,
                                      b1, w2, b2, out);
}

// Round 12
// 725.466 us; speedup vs baseline: 6.4262x; 1.0332x over previous
//
#include <hip/hip_runtime.h>

#define N_NODES 50000
#define N_EDGES 800000
#define NODE_F  388
#define EDGE_F  385
#define HC      64
#define KRED    384   // both GEMMs: 6 K-tiles of 64; k>=384 handled in epilogue
#define NKT     6
#define NB      196   // scan blocks: 196*256 >= 50000

// ---- workspace layout (float offsets) ----  [start, end) in floats
#define O_XLB     0L          // N*64 bf16 = 1.6M f    [0,          1,600,000)
#define O_XRB     1600000L    //                       [1.6M,       3,200,000)
#define O_HAB     3200000L    //                       [3.2M,       4,800,000)
#define O_HBB     4800000L    //                       [4.8M,       6,400,000)
#define O_EESUM   6400000L    // N*64 f32 (zeroed)     [6.4M,       9,600,000)
#define O_SSUM    9600000L    // N*2 f32 (zeroed)      [9.6M,       9,700,000)
#define O_WSUM    9700000L    // N*64 f32 (zeroed)     [9.7M,      12,900,000)
#define O_DEG     12900000L   // N int (zeroed)        [12.9M,     12,950,000)
#define O_CURSOR  12950000L   // N int (zeroed)        [12.95M,    13,000,000)
#define O_ROWPTR  13010000L   // N+1 int               [13.01M,    13,060,001)
#define O_BSUM    13070000L   // NB int                [13.07M,    13,070,196)
#define O_CSREST  13080000L   // E int4 = 3.2M f       [13.08M,    16,280,000)
#define O_WT      16300000L   // 128*384 bf16=24576f   [16.3M,     16,324,576)
#define O_WT2     16330000L   // 128*384 bf16=24576f   [16.33M,    16,354,576)
#define O_QW      16360000L   // E*64 bf16 = 25.6M f   [16.36M,    41,960,000) = 168 MB

typedef __attribute__((ext_vector_type(8))) short bf8;   // 8 bf16 (4 VGPRs)
typedef __attribute__((ext_vector_type(4))) float f4;

typedef __attribute__((address_space(1))) const unsigned char ga_u8;
typedef __attribute__((address_space(3))) unsigned char lds_u8;

static __device__ __forceinline__ void gload_lds16(const void* g, void* l) {
    __builtin_amdgcn_global_load_lds((ga_u8*)g, (lds_u8*)l, 16, 0, 0);
}

static __device__ __forceinline__ unsigned short f2bf(float f) {
    unsigned u = __float_as_uint(f);
    u += 0x7FFFu + ((u >> 16) & 1u);   // RNE
    return (unsigned short)(u >> 16);
}
static __device__ __forceinline__ float bf2f(unsigned short h) {
    return __uint_as_float(((unsigned)h) << 16);
}
static __device__ __forceinline__ unsigned cvtpk(float lo, float hi) {
    unsigned r;
    asm("v_cvt_pk_bf16_f32 %0, %1, %2" : "=v"(r) : "v"(lo), "v"(hi));
    return r;
}
// raw workgroup barrier, no vmcnt drain; sched_barrier pins instruction order
static __device__ __forceinline__ void raw_barrier() {
    __builtin_amdgcn_sched_barrier(0);
    __builtin_amdgcn_s_barrier();
    __builtin_amdgcn_sched_barrier(0);
}

// K0: blocks 0..95: wt (edge weights); 96..191: wt2 (node weights); 192..3316: deg histogram
__global__ __launch_bounds__(256) void k_prep_hist(
    const float* __restrict__ we, const float* __restrict__ w1,
    const float* __restrict__ wl, const float* __restrict__ wr,
    const int* __restrict__ ei,
    unsigned short* __restrict__ wt, unsigned short* __restrict__ wt2,
    int* __restrict__ deg)
{
    if (blockIdx.x >= 192) {                  // histogram part
        int e = (blockIdx.x - 192) * 256 + threadIdx.x;
        if (e < N_EDGES) atomicAdd(&deg[ei[N_EDGES + e]], 1);
        return;
    }
    int half = blockIdx.x / 96;
    int gid = (blockIdx.x - half * 96) * 256 + threadIdx.x;   // 24576 = 128 * 192
    int c  = gid / 192;
    int k  = 2 * (gid - c * 192);
    float f0, f1;
    if (half == 0) {
        if (c < HC) {
            f0 = we[(long)k * HC + c];
            f1 = we[(long)(k + 1) * HC + c];
        } else {
            f0 = w1[(long)(128 + k) * HC + (c - HC)];
            f1 = w1[(long)(128 + k + 1) * HC + (c - HC)];
        }
        *(unsigned*)(wt + (long)c * KRED + k) =
            (unsigned)f2bf(f0) | ((unsigned)f2bf(f1) << 16);
    } else {
        const float* w = (c < HC) ? wl : wr;
        int cc = (c < HC) ? c : c - HC;
        f0 = w[(long)k * HC + cc];
        f1 = w[(long)(k + 1) * HC + cc];
        *(unsigned*)(wt2 + (long)c * KRED + k) =
            (unsigned)f2bf(f0) | ((unsigned)f2bf(f1) << 16);
    }
}

// K1: [xl|xr] = x @ [wl|wr] + bias via MFMA; A direct-to-reg f32->bf16,
// k=384..387 rank-4 in epilogue; bf16 output.  Counted-wait pipeline (depth-1, proven).
__global__ __launch_bounds__(256, 5) void k_node_lin(
    const float* __restrict__ x, const unsigned short* __restrict__ wt2,
    const float* __restrict__ wl, const float* __restrict__ wr,
    const float* __restrict__ bl, const float* __restrict__ br,
    unsigned short* __restrict__ xlb, unsigned short* __restrict__ xrb)
{
    __shared__ __align__(16) char W_s[2][16384];
    const int t = threadIdx.x;
    const int l = t & 63;
    const int w = t >> 6;
    const int n0 = blockIdx.x * 64;
    const int rb = (w & 1) * 32;
    const int cb = (w >> 1) * 64;
    const int lr = l & 15;
    const int lk = l >> 4;

    int wsrc[4];
#pragma unroll
    for (int i = 0; i < 4; ++i) {
        int c = w * 32 + i * 8 + (l >> 3);
        wsrc[i] = c * (KRED * 2) + ((((l & 7) * 16)) ^ ((l >> 3) << 4));
    }
    const char* wtb = (const char*)wt2;

    long rowx[2];
#pragma unroll
    for (int rg = 0; rg < 2; ++rg) {
        int n = n0 + rb + rg * 16 + lr;
        if (n >= N_NODES) n = N_NODES - 1;        // clamp loads; stores guarded
        rowx[rg] = (long)n * NODE_F;
    }

    float af[2][16];
    bf8 fa[2][2];
    f4 acc[2][4];
#pragma unroll
    for (int rg = 0; rg < 2; ++rg)
#pragma unroll
        for (int cg = 0; cg < 4; ++cg) acc[rg][cg] = (f4)(0.f);

#define STAGE_W(kt, buf)                                                         \
    {                                                                            \
        _Pragma("unroll")                                                        \
        for (int i = 0; i < 4; ++i)                                              \
            gload_lds16(wtb + wsrc[i] + (kt) * 128, &W_s[buf][w * 4096 + i * 1024]); \
    }
#define ISSUE_AX(kt)                                                             \
    {                                                                            \
        _Pragma("unroll")                                                        \
        for (int rg = 0; rg < 2; ++rg) {                                         \
            const float* rp = x + rowx[rg] + (kt) * 64 + lk * 8;                 \
            float4 a0 = *(const float4*)(rp);                                    \
            float4 a1 = *(const float4*)(rp + 4);                                \
            float4 a2 = *(const float4*)(rp + 32);                               \
            float4 a3 = *(const float4*)(rp + 36);                               \
            af[rg][0]=a0.x; af[rg][1]=a0.y; af[rg][2]=a0.z; af[rg][3]=a0.w;      \
            af[rg][4]=a1.x; af[rg][5]=a1.y; af[rg][6]=a1.z; af[rg][7]=a1.w;      \
            af[rg][8]=a2.x; af[rg][9]=a2.y; af[rg][10]=a2.z; af[rg][11]=a2.w;    \
            af[rg][12]=a3.x; af[rg][13]=a3.y; af[rg][14]=a3.z; af[rg][15]=a3.w;  \
        }                                                                        \
    }
#define CVT_AX()                                                                 \
    {                                                                            \
        _Pragma("unroll")                                                        \
        for (int rg = 0; rg < 2; ++rg)                                           \
            _Pragma("unroll")                                                    \
            for (int ks = 0; ks < 2; ++ks) {                                     \
                union { bf8 v; unsigned u[4]; } tu;                              \
                _Pragma("unroll")                                                \
                for (int p = 0; p < 4; ++p)                                      \
                    tu.u[p] = cvtpk(af[rg][ks * 8 + 2 * p], af[rg][ks * 8 + 2 * p + 1]); \
                fa[rg][ks] = tu.v;                                               \
            }                                                                    \
    }

    STAGE_W(0, 0);
    ISSUE_AX(0);

    for (int kt = 0; kt < NKT; ++kt) {
        const int buf = kt & 1;
        CVT_AX();                             // waits A(kt)+W(kt) (issued last iter)
        if (kt < NKT - 1) { STAGE_W(kt + 1, buf ^ 1); ISSUE_AX(kt + 1); }
        raw_barrier();                        // W(kt) visible to all waves
        __builtin_amdgcn_s_setprio(1);
#pragma unroll
        for (int ks = 0; ks < 2; ++ks) {
            const int kb = ks * 64 + lk * 16;
#pragma unroll
            for (int cg = 0; cg < 4; ++cg) {
                const int c = cb + cg * 16 + lr;
                bf8 b = *(bf8*)(&W_s[buf][c * 128 + (kb ^ ((c & 7) << 4))]);
                acc[0][cg] = __builtin_amdgcn_mfma_f32_16x16x32_bf16(fa[0][ks], b, acc[0][cg], 0, 0, 0);
                acc[1][cg] = __builtin_amdgcn_mfma_f32_16x16x32_bf16(fa[1][ks], b, acc[1][cg], 0, 0, 0);
            }
        }
        __builtin_amdgcn_s_setprio(0);
        raw_barrier();                        // all readers done before buf reuse
    }

    // epilogue: rank-4 tail (k=384..387) + bias + bf16 pack store
    const float* wsf = (cb == 0) ? wl : wr;
    const float* bsf = (cb == 0) ? bl : br;
    unsigned short* dst = (cb == 0) ? xlb : xrb;
    float wtail[4][4], bias[4];
#pragma unroll
    for (int cg = 0; cg < 4; ++cg) {
        int c = cg * 16 + lr;
        bias[cg] = bsf[c];
#pragma unroll
        for (int j = 0; j < 4; ++j)
            wtail[j][cg] = wsf[(long)(KRED + j) * HC + c];
    }
#pragma unroll
    for (int rg = 0; rg < 2; ++rg)
#pragma unroll
    for (int r = 0; r < 4; ++r) {
        const int n = n0 + rb + rg * 16 + lk * 4 + r;
        const int nc = (n < N_NODES) ? n : N_NODES - 1;
        float4 xt = *(const float4*)(x + (long)nc * NODE_F + KRED);
#pragma unroll
        for (int cg = 0; cg < 4; ++cg) {
            float v = acc[rg][cg][r] + bias[cg]
                    + xt.x * wtail[0][cg] + xt.y * wtail[1][cg]
                    + xt.z * wtail[2][cg] + xt.w * wtail[3][cg];
            float nb = __shfl_xor(v, 1);
            if (!(lr & 1) && n < N_NODES)
                *(unsigned*)&dst[(long)n * HC + cg * 16 + lr] = cvtpk(v, nb);
        }
    }
#undef STAGE_W
#undef ISSUE_AX
#undef CVT_AX
}

// ---- CSR build ----
__global__ __launch_bounds__(256) void k_scan_bsum(const int* __restrict__ deg, int* __restrict__ bsum)
{
    __shared__ int red[4];
    int i = blockIdx.x * 256 + threadIdx.x;
    int v = (i < N_NODES) ? deg[i] : 0;
    for (int m = 1; m < 64; m <<= 1) v += __shfl_xor(v, m);
    if ((threadIdx.x & 63) == 0) red[threadIdx.x >> 6] = v;
    __syncthreads();
    if (threadIdx.x == 0) bsum[blockIdx.x] = red[0] + red[1] + red[2] + red[3];
}

// scan_row with inlined block-offset: each block sums bsum[0..blockIdx) itself
__global__ __launch_bounds__(256) void k_scan_row(const int* __restrict__ deg,
                                                  const int* __restrict__ bsum,
                                                  int* __restrict__ rowptr)
{
    __shared__ int sc[256];
    __shared__ int red[4];
    int t = threadIdx.x;
    // base = sum of bsum[j] for j < blockIdx.x
    int bv = (t < NB && t < (int)blockIdx.x) ? bsum[t] : 0;
    for (int m = 1; m < 64; m <<= 1) bv += __shfl_xor(bv, m);
    if ((t & 63) == 0) red[t >> 6] = bv;
    int i = blockIdx.x * 256 + t;
    int v = (i < N_NODES) ? deg[i] : 0;
    sc[t] = v; __syncthreads();
    int base = red[0] + red[1] + red[2] + red[3];
    for (int off = 1; off < 256; off <<= 1) {
        int tv = (t >= off) ? sc[t - off] : 0;
        __syncthreads();
        sc[t] += tv;
        __syncthreads();
    }
    if (i < N_NODES) rowptr[i] = base + sc[t] - v;   // exclusive
    if (i == N_NODES - 1) rowptr[N_NODES] = N_EDGES;
}

__global__ __launch_bounds__(256) void k_scatter(const int* __restrict__ ei,
                                                 const int* __restrict__ rowptr,
                                                 int* __restrict__ cursor,
                                                 int4* __restrict__ csr_est)
{
    int e = blockIdx.x * 256 + threadIdx.x;
    if (e >= N_EDGES) return;
    int g = ei[N_EDGES + e];
    int pos = rowptr[g] + atomicAdd(&cursor[g], 1);
    int4 v; v.x = e; v.y = ei[e]; v.z = g; v.w = 0;
    csr_est[pos] = v;                          // one 16B store (1 sector vs 3)
}

// K2: CSR-ordered 64-edge x 128-col MFMA tile; depth-2 A prefetch (af dbuf);
// epilogue: fused segmented reductions -> eesum, ssum, wsum (+qW bf16 store).
__global__ __launch_bounds__(256, 4) void k_edge_main(
    const float* __restrict__ ea, const int4* __restrict__ csr_est,
    const unsigned short* __restrict__ wt, const float* __restrict__ we,
    const unsigned short* __restrict__ xlb, const unsigned short* __restrict__ xrb,
    const float* __restrict__ att,
    float* __restrict__ eesum, float* __restrict__ ssum, float* __restrict__ wsum,
    unsigned short* __restrict__ qWP)
{
    __shared__ __align__(16) char lds[32768];      // K-loop: 2x16KB W dbuf; epilogue reuse
    const int t = threadIdx.x;
    const int l = t & 63;
    const int w = t >> 6;
    const long pb = (long)blockIdx.x * 64;
    const int rb = (w & 1) * 32;
    const int cb = (w >> 1) * 64;
    const int lr = l & 15;
    const int lk = l >> 4;

    int wsrc[4];
#pragma unroll
    for (int i = 0; i < 4; ++i) {
        int c = w * 32 + i * 8 + (l >> 3);
        wsrc[i] = c * (KRED * 2) + ((((l & 7) * 16)) ^ ((l >> 3) << 4));
    }
    const char* wtb = (const char*)wt;

    unsigned rowb[2];
#pragma unroll
    for (int rg = 0; rg < 2; ++rg) {
        int e = csr_est[pb + rb + rg * 16 + lr].x;
        rowb[rg] = (unsigned)e * EDGE_F;       // e*385 < 2^32
    }

    float af[2][2][16];                        // depth-2 A staging (dbuf)
    bf8 fa[2][2];
    f4 acc[2][4];
#pragma unroll
    for (int rg = 0; rg < 2; ++rg)
#pragma unroll
        for (int cg = 0; cg < 4; ++cg) acc[rg][cg] = (f4)(0.f);

#define STAGE_W(kt, buf)                                                         \
    {                                                                            \
        _Pragma("unroll")                                                        \
        for (int i = 0; i < 4; ++i)                                              \
            gload_lds16(wtb + wsrc[i] + (kt) * 128,                              \
                        &lds[(buf) * 16384 + w * 4096 + i * 1024]);              \
    }

// ea rows 4B-aligned only: memcpy-16 lets backend pick widest legal load.
#define ISSUE_A(b, kt)                                                           \
    {                                                                            \
        _Pragma("unroll")                                                        \
        for (int rg = 0; rg < 2; ++rg) {                                         \
            const float* rp = ea + rowb[rg] + (kt) * 64 + lk * 8;                \
            _Pragma("unroll")                                                    \
            for (int q4 = 0; q4 < 4; ++q4)                                       \
                __builtin_memcpy(&af[b][rg][q4 * 4],                             \
                                 rp + (q4 >> 1) * 32 + (q4 & 1) * 4, 16);        \
        }                                                                        \
    }

#define CVT_A(b)                                                                 \
    {                                                                            \
        _Pragma("unroll")                                                        \
        for (int rg = 0; rg < 2; ++rg)                                           \
            _Pragma("unroll")                                                    \
            for (int ks = 0; ks < 2; ++ks) {                                     \
                union { bf8 v; unsigned u[4]; } tu;                              \
                _Pragma("unroll")                                                \
                for (int p = 0; p < 4; ++p)                                      \
                    tu.u[p] = cvtpk(af[b][rg][ks * 8 + 2 * p],                   \
                                    af[b][rg][ks * 8 + 2 * p + 1]);              \
                fa[rg][ks] = tu.v;                                               \
            }                                                                    \
    }

    // prologue: tiles 0 and 1 in flight (A issued AFTER its W -> CVT wait implies W done)
    STAGE_W(0, 0); ISSUE_A(0, 0);
    STAGE_W(1, 1); ISSUE_A(1, 1);

    for (int kt = 0; kt < NKT; ++kt) {
        const int sl = kt & 1;
        CVT_A(sl);                            // waits A(kt) => own W(kt) gloads done
        raw_barrier();                        // every wave past its wait => W(kt) visible
        __builtin_amdgcn_s_setprio(1);
#pragma unroll
        for (int ks = 0; ks < 2; ++ks) {
            const int kb = ks * 64 + lk * 16;
#pragma unroll
            for (int cg = 0; cg < 4; ++cg) {
                const int c = cb + cg * 16 + lr;
                bf8 b = *(bf8*)(&lds[sl * 16384 + c * 128 + (kb ^ ((c & 7) << 4))]);
                acc[0][cg] = __builtin_amdgcn_mfma_f32_16x16x32_bf16(fa[0][ks], b, acc[0][cg], 0, 0, 0);
                acc[1][cg] = __builtin_amdgcn_mfma_f32_16x16x32_bf16(fa[1][ks], b, acc[1][cg], 0, 0, 0);
            }
        }
        __builtin_amdgcn_s_setprio(0);
        raw_barrier();                        // all readers done with W_s[sl]
        if (kt + 2 < NKT) {                   // stage tile kt+2 into freed slot
            STAGE_W(kt + 2, sl);
            ISSUE_A(sl, kt + 2);              // A after W: preserves the wait implication
        }
    }

    // ---- epilogue: fragments -> LDS; scores; two segmented reduces ----
    float (*ee_s)[65] = (float(*)[65])lds;          // 64x65 f32 = 16640 B
    int*   tgt_s      = (int*)(lds + 16640);        // 64 ints
    float (*ex_s)[2]  = (float(*)[2])(lds + 16896); // 64x2 f32

    if (cb == 0) {
        float attv[4], w384[4];
#pragma unroll
        for (int cg = 0; cg < 4; ++cg) {
            attv[cg] = att[cg * 16 + lr];
            w384[cg] = we[(long)(EDGE_F - 1) * HC + cg * 16 + lr];
        }
#pragma unroll
        for (int rg = 0; rg < 2; ++rg)
#pragma unroll
        for (int r = 0; r < 4; ++r) {
            const int row = rb + rg * 16 + lk * 4 + r;
            const long p = pb + row;
            const int4 est = csr_est[p];            // broadcast across 16 lanes
            const int s = est.y;
            const int g = est.z;
            const float a384 = ea[(long)est.x * EDGE_F + (EDGE_F - 1)];
            float sc0 = 0.f, sc1 = 0.f;
#pragma unroll
            for (int cg = 0; cg < 4; ++cg) {
                const int c = cg * 16 + lr;
                float eev = fmaf(a384, w384[cg], acc[rg][cg][r]);
                ee_s[row][c] = eev;
                float m = eev + bf2f(xlb[(long)s * HC + c]) + bf2f(xrb[(long)g * HC + c]);
                float lv = m > 0.f ? m : 0.2f * m;
                float tm = lv * attv[cg];
                if (cg < 2) sc0 += tm; else sc1 += tm;
            }
            sc0 += __shfl_xor(sc0, 1); sc0 += __shfl_xor(sc0, 2);
            sc0 += __shfl_xor(sc0, 4); sc0 += __shfl_xor(sc0, 8);
            sc1 += __shfl_xor(sc1, 1); sc1 += __shfl_xor(sc1, 2);
            sc1 += __shfl_xor(sc1, 4); sc1 += __shfl_xor(sc1, 8);
            if (lr == 0) {
                ex_s[row][0] = __expf(sc0);       // no segment-max: shift-invariant
                tgt_s[row] = g;
            } else if (lr == 1) {
                ex_s[row][1] = __expf(sc1);
            }
        }
    } else {
#pragma unroll
        for (int rg = 0; rg < 2; ++rg)
#pragma unroll
        for (int r = 0; r < 4; ++r) {
            const long p = pb + rb + rg * 16 + lk * 4 + r;
#pragma unroll
            for (int cg = 0; cg < 4; ++cg) {
                float v = acc[rg][cg][r];
                float nb = __shfl_xor(v, 1);
                if (!(lr & 1)) {
                    unsigned pk = cvtpk(v, nb);
                    *(unsigned*)&qWP[p * HC + cg * 16 + lr] = pk;
                }
            }
        }
    }
    __syncthreads();

    {   // reduce1: ee -> eesum, ex -> ssum.  thread -> col c, quarter q (16 rows)
        const int c = t & 63;
        const int q = t >> 6;
        const int r0 = q * 16;
        int   cur = tgt_s[r0];
        float run = ee_s[r0][c];
        for (int r = r0 + 1; r < r0 + 16; ++r) {
            int tg = tgt_s[r];
            if (tg != cur) {
                atomicAdd(&eesum[(long)cur * HC + c], run);
                run = 0.f; cur = tg;
            }
            run += ee_s[r][c];
        }
        atomicAdd(&eesum[(long)cur * HC + c], run);
        if (c < 2) {
            int   cur2 = tgt_s[r0];
            float run2 = ex_s[r0][c];
            for (int r = r0 + 1; r < r0 + 16; ++r) {
                int tg = tgt_s[r];
                if (tg != cur2) {
                    atomicAdd(&ssum[(long)cur2 * 2 + c], run2);
                    run2 = 0.f; cur2 = tg;
                }
                run2 += ex_s[r][c];
            }
            atomicAdd(&ssum[(long)cur2 * 2 + c], run2);
        }
    }
    __syncthreads();

    // pass2: contrib[row][c] = ex_h(row) * xl[s_row][c]  (xlb re-read, L1/L2-hot)
    if (cb == 0) {
#pragma unroll
        for (int rg = 0; rg < 2; ++rg)
#pragma unroll
        for (int r = 0; r < 4; ++r) {
            const int row = rb + rg * 16 + lk * 4 + r;
            const long p = pb + row;
            const int s = csr_est[p].y;
            const float ex0 = ex_s[row][0];
            const float ex1 = ex_s[row][1];
#pragma unroll
            for (int cg = 0; cg < 4; ++cg) {
                const int c = cg * 16 + lr;
                float xv = bf2f(xlb[(long)s * HC + c]);
                ee_s[row][c] = (cg < 2 ? ex0 : ex1) * xv;
            }
        }
    }
    __syncthreads();

    {   // reduce2: contrib -> wsum
        const int c = t & 63;
        const int q = t >> 6;
        const int r0 = q * 16;
        int   cur = tgt_s[r0];
        float run = ee_s[r0][c];
        for (int r = r0 + 1; r < r0 + 16; ++r) {
            int tg = tgt_s[r];
            if (tg != cur) {
                atomicAdd(&wsum[(long)cur * HC + c], run);
                run = 0.f; cur = tg;
            }
            run += ee_s[r][c];
        }
        atomicAdd(&wsum[(long)cur * HC + c], run);
    }
#undef STAGE_W
#undef ISSUE_A
#undef CVT_A
}

// K3: per-node finalize — pure streaming (eesum/ssum/wsum precomputed), W1 matvec.
__global__ __launch_bounds__(256) void k_node_agg(
    const int* __restrict__ rowptr,
    const float* __restrict__ eesum, const float* __restrict__ ssum,
    const float* __restrict__ wsum,
    const unsigned short* __restrict__ xlb, const unsigned short* __restrict__ xrb,
    const float* __restrict__ att, const float* __restrict__ convb,
    const float* __restrict__ w1,
    unsigned short* __restrict__ hAb, unsigned short* __restrict__ hBb)
{
    const int lane = threadIdx.x & 63;
    const int n = blockIdx.x * 4 + (threadIdx.x >> 6);
    if (n >= N_NODES) return;
    const int h = lane >> 5;
    const int deg = rowptr[n + 1] - rowptr[n];

    float eeS = eesum[(long)n * HC + lane] / (deg > 0 ? (float)deg : 1.f);
    float sex = ssum[(long)n * 2 + h];

    float xlv = bf2f(xlb[(long)n * HC + lane]);
    float v = xlv + bf2f(xrb[(long)n * HC + lane]) + eeS;
    float lv = v > 0.f ? v : 0.2f * v;
    float partial = lv * att[lane];
    partial += __shfl_xor(partial, 1);
    partial += __shfl_xor(partial, 2);
    partial += __shfl_xor(partial, 4);
    partial += __shfl_xor(partial, 8);
    partial += __shfl_xor(partial, 16);    // each 32-lane half holds its head's score
    float exSelf = __expf(partial);
    float inv = 1.f / (sex + exSelf + 1e-16f);
    float aggr = (exSelf * xlv + wsum[(long)n * HC + lane]) * inv;

    float hv = fmaxf(aggr + convb[lane], 0.f);
    float accA = 0.f, accB = 0.f;
    for (int k = 0; k < 64; ++k) {
        float hb = __shfl(hv, k);
        accA = fmaf(hb, w1[k * HC + lane], accA);
        accB = fmaf(hb, w1[(64 + k) * HC + lane], accB);
    }
    hAb[(long)n * HC + lane] = f2bf(accA);
    hBb[(long)n * HC + lane] = f2bf(accB);
}

// K6: trust — one lane per edge (p-order): row-local bf16 unpack, 192 FMA/lane.
__global__ __launch_bounds__(256) void k_trust(
    const int4* __restrict__ csr_est,
    const unsigned short* __restrict__ hAb, const unsigned short* __restrict__ hBb,
    const unsigned short* __restrict__ qWP, const float* __restrict__ b1,
    const float* __restrict__ w2, const float* __restrict__ b2,
    float* __restrict__ out)
{
    const long p = (long)blockIdx.x * 256 + threadIdx.x;
    const int4 est = csr_est[p];               // one coalesced 16B load
    const int s = est.y;
    const int g = est.z;
    const uint4* ha = (const uint4*)(hAb + (long)s * HC);
    const uint4* hb = (const uint4*)(hBb + (long)g * HC);
    const uint4* qw = (const uint4*)(qWP + p * HC);
    float a0 = 0.f, a1 = 0.f, a2 = 0.f;
#pragma unroll
    for (int ch = 0; ch < 8; ++ch) {              // 8 x (8 ushorts per array)
        uint4 ua = ha[ch], ub = hb[ch], uq = qw[ch];
        const unsigned* pa = (const unsigned*)&ua;
        const unsigned* pbb = (const unsigned*)&ub;
        const unsigned* pq = (const unsigned*)&uq;
#pragma unroll
        for (int j = 0; j < 4; ++j) {
            const int c = ch * 8 + j * 2;
            unsigned va = pa[j], vb = pbb[j], vq = pq[j];
            float m0 = __uint_as_float(va << 16) + __uint_as_float(vb << 16)
                     + __uint_as_float(vq << 16) + b1[c];
            float m1 = __uint_as_float(va & 0xffff0000u) + __uint_as_float(vb & 0xffff0000u)
                     + __uint_as_float(vq & 0xffff0000u) + b1[c + 1];
            m0 = fmaxf(m0, 0.f);
            m1 = fmaxf(m1, 0.f);
            a0 = fmaf(m0, w2[c * 3 + 0], a0); a0 = fmaf(m1, w2[c * 3 + 3], a0);
            a1 = fmaf(m0, w2[c * 3 + 1], a1); a1 = fmaf(m1, w2[c * 3 + 4], a1);
            a2 = fmaf(m0, w2[c * 3 + 2], a2); a2 = fmaf(m1, w2[c * 3 + 5], a2);
        }
    }
    float l0 = a0 + b2[0], l1 = a1 + b2[1], l2 = a2 + b2[2];
    float mx = fmaxf(l0, fmaxf(l1, l2));
    float e0 = __expf(l0 - mx), e1 = __expf(l1 - mx), e2 = __expf(l2 - mx);
    out[est.x] = (0.5f * e1 + e2) / (e0 + e1 + e2);
}

extern "C" void kernel_launch(void* const* d_in, const int* in_sizes, int n_in,
                              void* d_out, int out_size, void* d_ws, size_t ws_size,
                              hipStream_t stream)
{
    (void)in_sizes; (void)n_in; (void)out_size; (void)ws_size;
    const float* x     = (const float*)d_in[0];
    const int*   ei    = (const int*)  d_in[1];
    const float* ea    = (const float*)d_in[2];
    const float* wl    = (const float*)d_in[3];
    const float* bl    = (const float*)d_in[4];
    const float* wr    = (const float*)d_in[5];
    const float* br    = (const float*)d_in[6];
    const float* we    = (const float*)d_in[7];
    const float* att   = (const float*)d_in[8];
    const float* convb = (const float*)d_in[9];
    const float* w1    = (const float*)d_in[10];
    const float* b1    = (const float*)d_in[11];
    const float* w2    = (const float*)d_in[12];
    const float* b2    = (const float*)d_in[13];

    float* ws = (float*)d_ws;
    unsigned short* xlb = (unsigned short*)(ws + O_XLB);
    unsigned short* xrb = (unsigned short*)(ws + O_XRB);
    unsigned short* hAb = (unsigned short*)(ws + O_HAB);
    unsigned short* hBb = (unsigned short*)(ws + O_HBB);
    float* eesum  = ws + O_EESUM;
    float* ssum   = ws + O_SSUM;
    float* wsum   = ws + O_WSUM;
    unsigned short* wt  = (unsigned short*)(ws + O_WT);
    unsigned short* wt2 = (unsigned short*)(ws + O_WT2);
    int* deg    = (int*)(ws + O_DEG);
    int* cursor = (int*)(ws + O_CURSOR);
    int* rowptr = (int*)(ws + O_ROWPTR);
    int* bsum   = (int*)(ws + O_BSUM);
    int4* csr_est = (int4*)(ws + O_CSREST);
    unsigned short* qWP = (unsigned short*)(ws + O_QW);
    float* out  = (float*)d_out;

    // zero eesum + ssum + wsum + deg + cursor (contiguous [O_EESUM, 13,000,000))
    hipMemsetAsync(ws + O_EESUM, 0, (size_t)(13000000L - O_EESUM) * sizeof(float), stream);

    k_prep_hist<<<3317, 256, 0, stream>>>(we, w1, wl, wr, ei, wt, wt2, deg);
    k_scan_bsum<<<NB, 256, 0, stream>>>(deg, bsum);
    k_scan_row<<<NB, 256, 0, stream>>>(deg, bsum, rowptr);
    k_scatter<<<3125, 256, 0, stream>>>(ei, rowptr, cursor, csr_est);
    k_node_lin<<<782, 256, 0, stream>>>(x, wt2, wl, wr, bl, br, xlb, xrb);
    k_edge_main<<<N_EDGES / 64, 256, 0, stream>>>(ea, csr_est, wt, we,
                                                  xlb, xrb, att, eesum, ssum, wsum, qWP);
    k_node_agg<<<N_NODES / 4, 256, 0, stream>>>(rowptr, eesum, ssum, wsum,
                                                xlb, xrb, att, convb, w1, hAb, hBb);
    k_trust<<<3125, 256, 0, stream>>>(csr_est, hAb, hBb, qWP, b1, w2, b2, out);
}

// Round 13
// 711.758 us; speedup vs baseline: 6.5499x; 1.0193x over previous
//
#include <hip/hip_runtime.h>

#define N_NODES 50000
#define N_EDGES 800000
#define NODE_F  388
#define EDGE_F  385
#define HC      64
#define KRED    384   // both GEMMs: 6 K-tiles of 64; k>=384 handled in epilogue
#define NKT     6
#define NB      196   // scan blocks: 196*256 >= 50000
#define SCAT_BLKS 3125

// ---- workspace layout (float offsets) ----  [start, end) in floats
#define O_XLB     0L          // N*64 bf16 = 1.6M f    [0,          1,600,000)
#define O_XRB     1600000L    //                       [1.6M,       3,200,000)
#define O_HAB     3200000L    //                       [3.2M,       4,800,000)
#define O_HBB     4800000L    //                       [4.8M,       6,400,000)
#define O_EESUM   6400000L    // N*64 f32 (zeroed)     [6.4M,       9,600,000)
#define O_SSUM    9600000L    // N*2 f32 (zeroed)      [9.6M,       9,700,000)
#define O_WSUM    9700000L    // N*64 f32 (zeroed)     [9.7M,      12,900,000)
#define O_DEG     12900000L   // N int (zeroed)        [12.9M,     12,950,000)
#define O_CURSOR  12950000L   // N int (zeroed)        [12.95M,    13,000,000)
#define O_ROWPTR  13010000L   // N+1 int               [13.01M,    13,060,001)
#define O_BSUM    13070000L   // NB int                [13.07M,    13,070,196)
#define O_CSREST  13080000L   // E int4 = 3.2M f       [13.08M,    16,280,000)
#define O_WT      16300000L   // 128*384 bf16=24576f   [16.3M,     16,324,576)
#define O_WT2     16330000L   // 128*384 bf16=24576f   [16.33M,    16,354,576)
#define O_QW      16360000L   // E*64 bf16 = 25.6M f   [16.36M,    41,960,000) = 168 MB

typedef __attribute__((ext_vector_type(8))) short bf8;   // 8 bf16 (4 VGPRs)
typedef __attribute__((ext_vector_type(4))) float f4;

typedef __attribute__((address_space(1))) const unsigned char ga_u8;
typedef __attribute__((address_space(3))) unsigned char lds_u8;

static __device__ __forceinline__ void gload_lds16(const void* g, void* l) {
    __builtin_amdgcn_global_load_lds((ga_u8*)g, (lds_u8*)l, 16, 0, 0);
}

static __device__ __forceinline__ unsigned short f2bf(float f) {
    unsigned u = __float_as_uint(f);
    u += 0x7FFFu + ((u >> 16) & 1u);   // RNE
    return (unsigned short)(u >> 16);
}
static __device__ __forceinline__ float bf2f(unsigned short h) {
    return __uint_as_float(((unsigned)h) << 16);
}
static __device__ __forceinline__ unsigned cvtpk(float lo, float hi) {
    unsigned r;
    asm("v_cvt_pk_bf16_f32 %0, %1, %2" : "=v"(r) : "v"(lo), "v"(hi));
    return r;
}
// raw workgroup barrier, no vmcnt drain; sched_barrier pins instruction order
static __device__ __forceinline__ void raw_barrier() {
    __builtin_amdgcn_sched_barrier(0);
    __builtin_amdgcn_s_barrier();
    __builtin_amdgcn_sched_barrier(0);
}

// K0: blocks 0..95: wt (edge weights); 96..191: wt2 (node weights); 192..3316: deg histogram
__global__ __launch_bounds__(256) void k_prep_hist(
    const float* __restrict__ we, const float* __restrict__ w1,
    const float* __restrict__ wl, const float* __restrict__ wr,
    const int* __restrict__ ei,
    unsigned short* __restrict__ wt, unsigned short* __restrict__ wt2,
    int* __restrict__ deg)
{
    if (blockIdx.x >= 192) {                  // histogram part
        int e = (blockIdx.x - 192) * 256 + threadIdx.x;
        if (e < N_EDGES) atomicAdd(&deg[ei[N_EDGES + e]], 1);
        return;
    }
    int half = blockIdx.x / 96;
    int gid = (blockIdx.x - half * 96) * 256 + threadIdx.x;   // 24576 = 128 * 192
    int c  = gid / 192;
    int k  = 2 * (gid - c * 192);
    float f0, f1;
    if (half == 0) {
        if (c < HC) {
            f0 = we[(long)k * HC + c];
            f1 = we[(long)(k + 1) * HC + c];
        } else {
            f0 = w1[(long)(128 + k) * HC + (c - HC)];
            f1 = w1[(long)(128 + k + 1) * HC + (c - HC)];
        }
        *(unsigned*)(wt + (long)c * KRED + k) =
            (unsigned)f2bf(f0) | ((unsigned)f2bf(f1) << 16);
    } else {
        const float* w = (c < HC) ? wl : wr;
        int cc = (c < HC) ? c : c - HC;
        f0 = w[(long)k * HC + cc];
        f1 = w[(long)(k + 1) * HC + cc];
        *(unsigned*)(wt2 + (long)c * KRED + k) =
            (unsigned)f2bf(f0) | ((unsigned)f2bf(f1) << 16);
    }
}

// ---- CSR scan ----
__global__ __launch_bounds__(256) void k_scan_bsum(const int* __restrict__ deg, int* __restrict__ bsum)
{
    __shared__ int red[4];
    int i = blockIdx.x * 256 + threadIdx.x;
    int v = (i < N_NODES) ? deg[i] : 0;
    for (int m = 1; m < 64; m <<= 1) v += __shfl_xor(v, m);
    if ((threadIdx.x & 63) == 0) red[threadIdx.x >> 6] = v;
    __syncthreads();
    if (threadIdx.x == 0) bsum[blockIdx.x] = red[0] + red[1] + red[2] + red[3];
}

// scan_row with inlined block-offset: each block sums bsum[0..blockIdx) itself
__global__ __launch_bounds__(256) void k_scan_row(const int* __restrict__ deg,
                                                  const int* __restrict__ bsum,
                                                  int* __restrict__ rowptr)
{
    __shared__ int sc[256];
    __shared__ int red[4];
    int t = threadIdx.x;
    // base = sum of bsum[j] for j < blockIdx.x
    int bv = (t < NB && t < (int)blockIdx.x) ? bsum[t] : 0;
    for (int m = 1; m < 64; m <<= 1) bv += __shfl_xor(bv, m);
    if ((t & 63) == 0) red[t >> 6] = bv;
    int i = blockIdx.x * 256 + t;
    int v = (i < N_NODES) ? deg[i] : 0;
    sc[t] = v; __syncthreads();
    int base = red[0] + red[1] + red[2] + red[3];
    for (int off = 1; off < 256; off <<= 1) {
        int tv = (t >= off) ? sc[t - off] : 0;
        __syncthreads();
        sc[t] += tv;
        __syncthreads();
    }
    if (i < N_NODES) rowptr[i] = base + sc[t] - v;   // exclusive
    if (i == N_NODES - 1) rowptr[N_NODES] = N_EDGES;
}

// K1: MERGED launch. Blocks [0,3125): CSR scatter (int4 pack).  Blocks [3125,3907):
// node-linear MFMA [xl|xr] = x @ [wl|wr] + bias (depth-1 counted-wait pipeline).
// Independent workloads (scatter: latency/atomic-bound; node_lin: MFMA-bound) co-reside.
__global__ __launch_bounds__(256, 4) void k_nl_scatter(
    const int* __restrict__ ei, const int* __restrict__ rowptr, int* __restrict__ cursor,
    int4* __restrict__ csr_est,
    const float* __restrict__ x, const unsigned short* __restrict__ wt2,
    const float* __restrict__ wl, const float* __restrict__ wr,
    const float* __restrict__ bl, const float* __restrict__ br,
    unsigned short* __restrict__ xlb, unsigned short* __restrict__ xrb)
{
    __shared__ __align__(16) char W_s[2][16384];
    if (blockIdx.x < SCAT_BLKS) {             // ---- scatter path ----
        int e = blockIdx.x * 256 + threadIdx.x;
        if (e >= N_EDGES) return;
        int g = ei[N_EDGES + e];
        int pos = rowptr[g] + atomicAdd(&cursor[g], 1);
        int4 v; v.x = e; v.y = ei[e]; v.z = g; v.w = 0;
        csr_est[pos] = v;                     // one 16B store (1 sector vs 3)
        return;
    }
    // ---- node_lin path ----
    const int bid = blockIdx.x - SCAT_BLKS;
    const int t = threadIdx.x;
    const int l = t & 63;
    const int w = t >> 6;
    const int n0 = bid * 64;
    const int rb = (w & 1) * 32;
    const int cb = (w >> 1) * 64;
    const int lr = l & 15;
    const int lk = l >> 4;

    int wsrc[4];
#pragma unroll
    for (int i = 0; i < 4; ++i) {
        int c = w * 32 + i * 8 + (l >> 3);
        wsrc[i] = c * (KRED * 2) + ((((l & 7) * 16)) ^ ((l >> 3) << 4));
    }
    const char* wtb = (const char*)wt2;

    long rowx[2];
#pragma unroll
    for (int rg = 0; rg < 2; ++rg) {
        int n = n0 + rb + rg * 16 + lr;
        if (n >= N_NODES) n = N_NODES - 1;        // clamp loads; stores guarded
        rowx[rg] = (long)n * NODE_F;
    }

    float af[2][16];
    bf8 fa[2][2];
    f4 acc[2][4];
#pragma unroll
    for (int rg = 0; rg < 2; ++rg)
#pragma unroll
        for (int cg = 0; cg < 4; ++cg) acc[rg][cg] = (f4)(0.f);

#define STAGE_W(kt, buf)                                                         \
    {                                                                            \
        _Pragma("unroll")                                                        \
        for (int i = 0; i < 4; ++i)                                              \
            gload_lds16(wtb + wsrc[i] + (kt) * 128, &W_s[buf][w * 4096 + i * 1024]); \
    }
#define ISSUE_AX(kt)                                                             \
    {                                                                            \
        _Pragma("unroll")                                                        \
        for (int rg = 0; rg < 2; ++rg) {                                         \
            const float* rp = x + rowx[rg] + (kt) * 64 + lk * 8;                 \
            float4 a0 = *(const float4*)(rp);                                    \
            float4 a1 = *(const float4*)(rp + 4);                                \
            float4 a2 = *(const float4*)(rp + 32);                               \
            float4 a3 = *(const float4*)(rp + 36);                               \
            af[rg][0]=a0.x; af[rg][1]=a0.y; af[rg][2]=a0.z; af[rg][3]=a0.w;      \
            af[rg][4]=a1.x; af[rg][5]=a1.y; af[rg][6]=a1.z; af[rg][7]=a1.w;      \
            af[rg][8]=a2.x; af[rg][9]=a2.y; af[rg][10]=a2.z; af[rg][11]=a2.w;    \
            af[rg][12]=a3.x; af[rg][13]=a3.y; af[rg][14]=a3.z; af[rg][15]=a3.w;  \
        }                                                                        \
    }
#define CVT_AX()                                                                 \
    {                                                                            \
        _Pragma("unroll")                                                        \
        for (int rg = 0; rg < 2; ++rg)                                           \
            _Pragma("unroll")                                                    \
            for (int ks = 0; ks < 2; ++ks) {                                     \
                union { bf8 v; unsigned u[4]; } tu;                              \
                _Pragma("unroll")                                                \
                for (int p = 0; p < 4; ++p)                                      \
                    tu.u[p] = cvtpk(af[rg][ks * 8 + 2 * p], af[rg][ks * 8 + 2 * p + 1]); \
                fa[rg][ks] = tu.v;                                               \
            }                                                                    \
    }

    STAGE_W(0, 0);
    ISSUE_AX(0);

    for (int kt = 0; kt < NKT; ++kt) {
        const int buf = kt & 1;
        CVT_AX();                             // waits A(kt)+W(kt) (issued last iter)
        if (kt < NKT - 1) { STAGE_W(kt + 1, buf ^ 1); ISSUE_AX(kt + 1); }
        raw_barrier();                        // W(kt) visible to all waves
        __builtin_amdgcn_s_setprio(1);
#pragma unroll
        for (int ks = 0; ks < 2; ++ks) {
            const int kb = ks * 64 + lk * 16;
#pragma unroll
            for (int cg = 0; cg < 4; ++cg) {
                const int c = cb + cg * 16 + lr;
                bf8 b = *(bf8*)(&W_s[buf][c * 128 + (kb ^ ((c & 7) << 4))]);
                acc[0][cg] = __builtin_amdgcn_mfma_f32_16x16x32_bf16(fa[0][ks], b, acc[0][cg], 0, 0, 0);
                acc[1][cg] = __builtin_amdgcn_mfma_f32_16x16x32_bf16(fa[1][ks], b, acc[1][cg], 0, 0, 0);
            }
        }
        __builtin_amdgcn_s_setprio(0);
        raw_barrier();                        // all readers done before buf reuse
    }

    // epilogue: rank-4 tail (k=384..387) + bias + bf16 pack store
    const float* wsf = (cb == 0) ? wl : wr;
    const float* bsf = (cb == 0) ? bl : br;
    unsigned short* dst = (cb == 0) ? xlb : xrb;
    float wtail[4][4], bias[4];
#pragma unroll
    for (int cg = 0; cg < 4; ++cg) {
        int c = cg * 16 + lr;
        bias[cg] = bsf[c];
#pragma unroll
        for (int j = 0; j < 4; ++j)
            wtail[j][cg] = wsf[(long)(KRED + j) * HC + c];
    }
#pragma unroll
    for (int rg = 0; rg < 2; ++rg)
#pragma unroll
    for (int r = 0; r < 4; ++r) {
        const int n = n0 + rb + rg * 16 + lk * 4 + r;
        const int nc = (n < N_NODES) ? n : N_NODES - 1;
        float4 xt = *(const float4*)(x + (long)nc * NODE_F + KRED);
#pragma unroll
        for (int cg = 0; cg < 4; ++cg) {
            float v = acc[rg][cg][r] + bias[cg]
                    + xt.x * wtail[0][cg] + xt.y * wtail[1][cg]
                    + xt.z * wtail[2][cg] + xt.w * wtail[3][cg];
            float nb = __shfl_xor(v, 1);
            if (!(lr & 1) && n < N_NODES)
                *(unsigned*)&dst[(long)n * HC + cg * 16 + lr] = cvtpk(v, nb);
        }
    }
#undef STAGE_W
#undef ISSUE_AX
#undef CVT_AX
}

// K2: CSR-ordered 64-edge x 128-col MFMA tile; depth-2 A prefetch (af dbuf);
// epilogue: fused segmented reductions -> eesum, ssum, wsum (+qW bf16 store).
__global__ __launch_bounds__(256, 4) void k_edge_main(
    const float* __restrict__ ea, const int4* __restrict__ csr_est,
    const unsigned short* __restrict__ wt, const float* __restrict__ we,
    const unsigned short* __restrict__ xlb, const unsigned short* __restrict__ xrb,
    const float* __restrict__ att,
    float* __restrict__ eesum, float* __restrict__ ssum, float* __restrict__ wsum,
    unsigned short* __restrict__ qWP)
{
    __shared__ __align__(16) char lds[32768];      // K-loop: 2x16KB W dbuf; epilogue reuse
    const int t = threadIdx.x;
    const int l = t & 63;
    const int w = t >> 6;
    const long pb = (long)blockIdx.x * 64;
    const int rb = (w & 1) * 32;
    const int cb = (w >> 1) * 64;
    const int lr = l & 15;
    const int lk = l >> 4;

    int wsrc[4];
#pragma unroll
    for (int i = 0; i < 4; ++i) {
        int c = w * 32 + i * 8 + (l >> 3);
        wsrc[i] = c * (KRED * 2) + ((((l & 7) * 16)) ^ ((l >> 3) << 4));
    }
    const char* wtb = (const char*)wt;

    unsigned rowb[2];
#pragma unroll
    for (int rg = 0; rg < 2; ++rg) {
        int e = csr_est[pb + rb + rg * 16 + lr].x;
        rowb[rg] = (unsigned)e * EDGE_F;       // e*385 < 2^32
    }

    float af[2][2][16];                        // depth-2 A staging (dbuf)
    bf8 fa[2][2];
    f4 acc[2][4];
#pragma unroll
    for (int rg = 0; rg < 2; ++rg)
#pragma unroll
        for (int cg = 0; cg < 4; ++cg) acc[rg][cg] = (f4)(0.f);

#define STAGE_W(kt, buf)                                                         \
    {                                                                            \
        _Pragma("unroll")                                                        \
        for (int i = 0; i < 4; ++i)                                              \
            gload_lds16(wtb + wsrc[i] + (kt) * 128,                              \
                        &lds[(buf) * 16384 + w * 4096 + i * 1024]);              \
    }

// ea rows 4B-aligned only: memcpy-16 lets backend pick widest legal load.
#define ISSUE_A(b, kt)                                                           \
    {                                                                            \
        _Pragma("unroll")                                                        \
        for (int rg = 0; rg < 2; ++rg) {                                         \
            const float* rp = ea + rowb[rg] + (kt) * 64 + lk * 8;                \
            _Pragma("unroll")                                                    \
            for (int q4 = 0; q4 < 4; ++q4)                                       \
                __builtin_memcpy(&af[b][rg][q4 * 4],                             \
                                 rp + (q4 >> 1) * 32 + (q4 & 1) * 4, 16);        \
        }                                                                        \
    }

#define CVT_A(b)                                                                 \
    {                                                                            \
        _Pragma("unroll")                                                        \
        for (int rg = 0; rg < 2; ++rg)                                           \
            _Pragma("unroll")                                                    \
            for (int ks = 0; ks < 2; ++ks) {                                     \
                union { bf8 v; unsigned u[4]; } tu;                              \
                _Pragma("unroll")                                                \
                for (int p = 0; p < 4; ++p)                                      \
                    tu.u[p] = cvtpk(af[b][rg][ks * 8 + 2 * p],                   \
                                    af[b][rg][ks * 8 + 2 * p + 1]);              \
                fa[rg][ks] = tu.v;                                               \
            }                                                                    \
    }

    // prologue: tiles 0 and 1 in flight (A issued AFTER its W -> CVT wait implies W done)
    STAGE_W(0, 0); ISSUE_A(0, 0);
    STAGE_W(1, 1); ISSUE_A(1, 1);

    for (int kt = 0; kt < NKT; ++kt) {
        const int sl = kt & 1;
        CVT_A(sl);                            // waits A(kt) => own W(kt) gloads done
        raw_barrier();                        // every wave past its wait => W(kt) visible
        __builtin_amdgcn_s_setprio(1);
#pragma unroll
        for (int ks = 0; ks < 2; ++ks) {
            const int kb = ks * 64 + lk * 16;
#pragma unroll
            for (int cg = 0; cg < 4; ++cg) {
                const int c = cb + cg * 16 + lr;
                bf8 b = *(bf8*)(&lds[sl * 16384 + c * 128 + (kb ^ ((c & 7) << 4))]);
                acc[0][cg] = __builtin_amdgcn_mfma_f32_16x16x32_bf16(fa[0][ks], b, acc[0][cg], 0, 0, 0);
                acc[1][cg] = __builtin_amdgcn_mfma_f32_16x16x32_bf16(fa[1][ks], b, acc[1][cg], 0, 0, 0);
            }
        }
        __builtin_amdgcn_s_setprio(0);
        raw_barrier();                        // all readers done with W_s[sl]
        if (kt + 2 < NKT) {                   // stage tile kt+2 into freed slot
            STAGE_W(kt + 2, sl);
            ISSUE_A(sl, kt + 2);              // A after W: preserves the wait implication
        }
    }

    // ---- epilogue: fragments -> LDS; scores; two segmented reduces ----
    float (*ee_s)[65] = (float(*)[65])lds;          // 64x65 f32 = 16640 B
    int*   tgt_s      = (int*)(lds + 16640);        // 64 ints
    float (*ex_s)[2]  = (float(*)[2])(lds + 16896); // 64x2 f32

    if (cb == 0) {
        float attv[4], w384[4];
#pragma unroll
        for (int cg = 0; cg < 4; ++cg) {
            attv[cg] = att[cg * 16 + lr];
            w384[cg] = we[(long)(EDGE_F - 1) * HC + cg * 16 + lr];
        }
#pragma unroll
        for (int rg = 0; rg < 2; ++rg)
#pragma unroll
        for (int r = 0; r < 4; ++r) {
            const int row = rb + rg * 16 + lk * 4 + r;
            const long p = pb + row;
            const int4 est = csr_est[p];            // broadcast across 16 lanes
            const int s = est.y;
            const int g = est.z;
            const float a384 = ea[(long)est.x * EDGE_F + (EDGE_F - 1)];
            float sc0 = 0.f, sc1 = 0.f;
#pragma unroll
            for (int cg = 0; cg < 4; ++cg) {
                const int c = cg * 16 + lr;
                float eev = fmaf(a384, w384[cg], acc[rg][cg][r]);
                ee_s[row][c] = eev;
                float m = eev + bf2f(xlb[(long)s * HC + c]) + bf2f(xrb[(long)g * HC + c]);
                float lv = m > 0.f ? m : 0.2f * m;
                float tm = lv * attv[cg];
                if (cg < 2) sc0 += tm; else sc1 += tm;
            }
            sc0 += __shfl_xor(sc0, 1); sc0 += __shfl_xor(sc0, 2);
            sc0 += __shfl_xor(sc0, 4); sc0 += __shfl_xor(sc0, 8);
            sc1 += __shfl_xor(sc1, 1); sc1 += __shfl_xor(sc1, 2);
            sc1 += __shfl_xor(sc1, 4); sc1 += __shfl_xor(sc1, 8);
            if (lr == 0) {
                ex_s[row][0] = __expf(sc0);       // no segment-max: shift-invariant
                tgt_s[row] = g;
            } else if (lr == 1) {
                ex_s[row][1] = __expf(sc1);
            }
        }
    } else {
#pragma unroll
        for (int rg = 0; rg < 2; ++rg)
#pragma unroll
        for (int r = 0; r < 4; ++r) {
            const long p = pb + rb + rg * 16 + lk * 4 + r;
#pragma unroll
            for (int cg = 0; cg < 4; ++cg) {
                float v = acc[rg][cg][r];
                float nb = __shfl_xor(v, 1);
                if (!(lr & 1)) {
                    unsigned pk = cvtpk(v, nb);
                    *(unsigned*)&qWP[p * HC + cg * 16 + lr] = pk;
                }
            }
        }
    }
    __syncthreads();

    {   // reduce1: ee -> eesum, ex -> ssum.  thread -> col c, quarter q (16 rows)
        const int c = t & 63;
        const int q = t >> 6;
        const int r0 = q * 16;
        int   cur = tgt_s[r0];
        float run = ee_s[r0][c];
        for (int r = r0 + 1; r < r0 + 16; ++r) {
            int tg = tgt_s[r];
            if (tg != cur) {
                atomicAdd(&eesum[(long)cur * HC + c], run);
                run = 0.f; cur = tg;
            }
            run += ee_s[r][c];
        }
        atomicAdd(&eesum[(long)cur * HC + c], run);
        if (c < 2) {
            int   cur2 = tgt_s[r0];
            float run2 = ex_s[r0][c];
            for (int r = r0 + 1; r < r0 + 16; ++r) {
                int tg = tgt_s[r];
                if (tg != cur2) {
                    atomicAdd(&ssum[(long)cur2 * 2 + c], run2);
                    run2 = 0.f; cur2 = tg;
                }
                run2 += ex_s[r][c];
            }
            atomicAdd(&ssum[(long)cur2 * 2 + c], run2);
        }
    }
    __syncthreads();

    // pass2: contrib[row][c] = ex_h(row) * xl[s_row][c]  (xlb re-read, L1/L2-hot)
    if (cb == 0) {
#pragma unroll
        for (int rg = 0; rg < 2; ++rg)
#pragma unroll
        for (int r = 0; r < 4; ++r) {
            const int row = rb + rg * 16 + lk * 4 + r;
            const long p = pb + row;
            const int s = csr_est[p].y;
            const float ex0 = ex_s[row][0];
            const float ex1 = ex_s[row][1];
#pragma unroll
            for (int cg = 0; cg < 4; ++cg) {
                const int c = cg * 16 + lr;
                float xv = bf2f(xlb[(long)s * HC + c]);
                ee_s[row][c] = (cg < 2 ? ex0 : ex1) * xv;
            }
        }
    }
    __syncthreads();

    {   // reduce2: contrib -> wsum
        const int c = t & 63;
        const int q = t >> 6;
        const int r0 = q * 16;
        int   cur = tgt_s[r0];
        float run = ee_s[r0][c];
        for (int r = r0 + 1; r < r0 + 16; ++r) {
            int tg = tgt_s[r];
            if (tg != cur) {
                atomicAdd(&wsum[(long)cur * HC + c], run);
                run = 0.f; cur = tg;
            }
            run += ee_s[r][c];
        }
        atomicAdd(&wsum[(long)cur * HC + c], run);
    }
#undef STAGE_W
#undef ISSUE_A
#undef CVT_A
}

// K3: per-node finalize — pure streaming (eesum/ssum/wsum precomputed), W1 matvec.
__global__ __launch_bounds__(256) void k_node_agg(
    const int* __restrict__ rowptr,
    const float* __restrict__ eesum, const float* __restrict__ ssum,
    const float* __restrict__ wsum,
    const unsigned short* __restrict__ xlb, const unsigned short* __restrict__ xrb,
    const float* __restrict__ att, const float* __restrict__ convb,
    const float* __restrict__ w1,
    unsigned short* __restrict__ hAb, unsigned short* __restrict__ hBb)
{
    const int lane = threadIdx.x & 63;
    const int n = blockIdx.x * 4 + (threadIdx.x >> 6);
    if (n >= N_NODES) return;
    const int h = lane >> 5;
    const int deg = rowptr[n + 1] - rowptr[n];

    float eeS = eesum[(long)n * HC + lane] / (deg > 0 ? (float)deg : 1.f);
    float sex = ssum[(long)n * 2 + h];

    float xlv = bf2f(xlb[(long)n * HC + lane]);
    float v = xlv + bf2f(xrb[(long)n * HC + lane]) + eeS;
    float lv = v > 0.f ? v : 0.2f * v;
    float partial = lv * att[lane];
    partial += __shfl_xor(partial, 1);
    partial += __shfl_xor(partial, 2);
    partial += __shfl_xor(partial, 4);
    partial += __shfl_xor(partial, 8);
    partial += __shfl_xor(partial, 16);    // each 32-lane half holds its head's score
    float exSelf = __expf(partial);
    float inv = 1.f / (sex + exSelf + 1e-16f);
    float aggr = (exSelf * xlv + wsum[(long)n * HC + lane]) * inv;

    float hv = fmaxf(aggr + convb[lane], 0.f);
    float accA = 0.f, accB = 0.f;
    for (int k = 0; k < 64; ++k) {
        float hb = __shfl(hv, k);
        accA = fmaf(hb, w1[k * HC + lane], accA);
        accB = fmaf(hb, w1[(64 + k) * HC + lane], accB);
    }
    hAb[(long)n * HC + lane] = f2bf(accA);
    hBb[(long)n * HC + lane] = f2bf(accB);
}

// K6: trust — one lane per edge (p-order): row-local bf16 unpack, 192 FMA/lane.
__global__ __launch_bounds__(256) void k_trust(
    const int4* __restrict__ csr_est,
    const unsigned short* __restrict__ hAb, const unsigned short* __restrict__ hBb,
    const unsigned short* __restrict__ qWP, const float* __restrict__ b1,
    const float* __restrict__ w2, const float* __restrict__ b2,
    float* __restrict__ out)
{
    const long p = (long)blockIdx.x * 256 + threadIdx.x;
    const int4 est = csr_est[p];               // one coalesced 16B load
    const int s = est.y;
    const int g = est.z;
    const uint4* ha = (const uint4*)(hAb + (long)s * HC);
    const uint4* hb = (const uint4*)(hBb + (long)g * HC);
    const uint4* qw = (const uint4*)(qWP + p * HC);
    float a0 = 0.f, a1 = 0.f, a2 = 0.f;
#pragma unroll
    for (int ch = 0; ch < 8; ++ch) {              // 8 x (8 ushorts per array)
        uint4 ua = ha[ch], ub = hb[ch], uq = qw[ch];
        const unsigned* pa = (const unsigned*)&ua;
        const unsigned* pbb = (const unsigned*)&ub;
        const unsigned* pq = (const unsigned*)&uq;
#pragma unroll
        for (int j = 0; j < 4; ++j) {
            const int c = ch * 8 + j * 2;
            unsigned va = pa[j], vb = pbb[j], vq = pq[j];
            float m0 = __uint_as_float(va << 16) + __uint_as_float(vb << 16)
                     + __uint_as_float(vq << 16) + b1[c];
            float m1 = __uint_as_float(va & 0xffff0000u) + __uint_as_float(vb & 0xffff0000u)
                     + __uint_as_float(vq & 0xffff0000u) + b1[c + 1];
            m0 = fmaxf(m0, 0.f);
            m1 = fmaxf(m1, 0.f);
            a0 = fmaf(m0, w2[c * 3 + 0], a0); a0 = fmaf(m1, w2[c * 3 + 3], a0);
            a1 = fmaf(m0, w2[c * 3 + 1], a1); a1 = fmaf(m1, w2[c * 3 + 4], a1);
            a2 = fmaf(m0, w2[c * 3 + 2], a2); a2 = fmaf(m1, w2[c * 3 + 5], a2);
        }
    }
    float l0 = a0 + b2[0], l1 = a1 + b2[1], l2 = a2 + b2[2];
    float mx = fmaxf(l0, fmaxf(l1, l2));
    float e0 = __expf(l0 - mx), e1 = __expf(l1 - mx), e2 = __expf(l2 - mx);
    out[est.x] = (0.5f * e1 + e2) / (e0 + e1 + e2);
}

extern "C" void kernel_launch(void* const* d_in, const int* in_sizes, int n_in,
                              void* d_out, int out_size, void* d_ws, size_t ws_size,
                              hipStream_t stream)
{
    (void)in_sizes; (void)n_in; (void)out_size; (void)ws_size;
    const float* x     = (const float*)d_in[0];
    const int*   ei    = (const int*)  d_in[1];
    const float* ea    = (const float*)d_in[2];
    const float* wl    = (const float*)d_in[3];
    const float* bl    = (const float*)d_in[4];
    const float* wr    = (const float*)d_in[5];
    const float* br    = (const float*)d_in[6];
    const float* we    = (const float*)d_in[7];
    const float* att   = (const float*)d_in[8];
    const float* convb = (const float*)d_in[9];
    const float* w1    = (const float*)d_in[10];
    const float* b1    = (const float*)d_in[11];
    const float* w2    = (const float*)d_in[12];
    const float* b2    = (const float*)d_in[13];

    float* ws = (float*)d_ws;
    unsigned short* xlb = (unsigned short*)(ws + O_XLB);
    unsigned short* xrb = (unsigned short*)(ws + O_XRB);
    unsigned short* hAb = (unsigned short*)(ws + O_HAB);
    unsigned short* hBb = (unsigned short*)(ws + O_HBB);
    float* eesum  = ws + O_EESUM;
    float* ssum   = ws + O_SSUM;
    float* wsum   = ws + O_WSUM;
    unsigned short* wt  = (unsigned short*)(ws + O_WT);
    unsigned short* wt2 = (unsigned short*)(ws + O_WT2);
    int* deg    = (int*)(ws + O_DEG);
    int* cursor = (int*)(ws + O_CURSOR);
    int* rowptr = (int*)(ws + O_ROWPTR);
    int* bsum   = (int*)(ws + O_BSUM);
    int4* csr_est = (int4*)(ws + O_CSREST);
    unsigned short* qWP = (unsigned short*)(ws + O_QW);
    float* out  = (float*)d_out;

    // zero eesum + ssum + wsum + deg + cursor (contiguous [O_EESUM, 13,000,000))
    hipMemsetAsync(ws + O_EESUM, 0, (size_t)(13000000L - O_EESUM) * sizeof(float), stream);

    k_prep_hist<<<3317, 256, 0, stream>>>(we, w1, wl, wr, ei, wt, wt2, deg);
    k_scan_bsum<<<NB, 256, 0, stream>>>(deg, bsum);
    k_scan_row<<<NB, 256, 0, stream>>>(deg, bsum, rowptr);
    k_nl_scatter<<<SCAT_BLKS + 782, 256, 0, stream>>>(ei, rowptr, cursor, csr_est,
                                                      x, wt2, wl, wr, bl, br, xlb, xrb);
    k_edge_main<<<N_EDGES / 64, 256, 0, stream>>>(ea, csr_est, wt, we,
                                                  xlb, xrb, att, eesum, ssum, wsum, qWP);
    k_node_agg<<<N_NODES / 4, 256, 0, stream>>>(rowptr, eesum, ssum, wsum,
                                                xlb, xrb, att, convb, w1, hAb, hBb);
    k_trust<<<3125, 256, 0, stream>>>(csr_est, hAb, hBb, qWP, b1, w2, b2, out);
}